// Round 12
// baseline (5567.734 us; speedup 1.0000x reference)
//
#include <hip/hip_runtime.h>
#include <hip/hip_bf16.h>

// ---------------- problem constants ----------------
// B=32, S=512, D=512, K=2048, NHEADS=8, NHASH=4, HLEN=16; N = B*S = 16384.
// d_out is FLOAT32. Intermediates f32-stored.
// Inner products: f32 FMA over 16-elem chunks (k ascending), f64 chunk
// combine — per-element rounding sequence IDENTICAL to r10/r11 (bit-identical
// outputs). r12 changes only the parallel decomposition: 128x64 tile,
// 8x4 per-thread register block, BK=16.

#define GF_BIAS 1
#define GF_RELU 2
#define GF_ADD  4
#define GF_POS  8
#define GF_ACC  16

// output layout (f32 elements), return order — total 43,008,001
static constexpr long long O_QUANT = 0LL;        // 8388608
static constexpr long long O_LOSS  = 8388608LL;  // 1
static constexpr long long O_IDX   = 8388609LL;  // 16384
static constexpr long long O_HASH  = 8404993LL;  // 1048576
static constexpr long long O_REG   = 9453569LL;  // 33554432
static constexpr long long O_END   = 43008001LL;

// workspace layout (f32 element offsets) — total 34,402,304 f32 = 131.2 MiB
static constexpr long long W_XP    = 0LL;
static constexpr long long W_CT    = 8388608LL;
static constexpr long long W_PROJ  = 16777216LL;
static constexpr long long W_VW    = 25165824LL;
static constexpr long long W_HREG  = 33554432LL;
static constexpr long long W_T     = 34078720LL;
static constexpr long long W_IDX   = 34209792LL;
static constexpr long long W_ASUM  = 34226176LL;  // 16384 f64
static constexpr long long W_CBB   = 34258944LL;  // 2048 f64
static constexpr long long W_LPART = 34263040LL;  // 4096 f64
static constexpr long long W_PBV   = 34271232LL;  // 4*16384 f32 partial best val
static constexpr long long W_PBI   = 34336768LL;  // 4*16384 int partial best idx
static constexpr long long W_END   = 34402304LL;

// ---------------- generic GEMM: 128x64 tile, 8x4/thread, BK=16 ---------------
template<int FLAGS>
__global__ __launch_bounds__(256)
void gemm_bt_r12(const float* __restrict__ A, const float* __restrict__ Bm,
                 const float* __restrict__ bias, const float* __restrict__ pos,
                 const float* __restrict__ addsrc, float* __restrict__ C,
                 int Kdim, int lda, int ldb, int ldc)
{
    __shared__ float As[16][132];   // [k][row], 128 rows + pad
    __shared__ float Bs[16][68];    // [k][col], 64 cols + pad
    const int tid = threadIdx.x;
    const int tx = tid & 15, ty = tid >> 4;
    const int bm = blockIdx.x * 128, bn = blockIdx.y * 64;
    // A staging slots: 512 float4 = 128 rows x 4 kgroups; thread t -> t, t+256
    const int ar0 = tid >> 2,        akg0 = (tid & 3) << 2;
    const int ar1 = (tid + 256) >> 2, akg1 = akg0;   // (t+256)&3 == t&3
    // B staging: 256 float4 = 64 rows x 4 kgroups
    const int br = tid >> 2, bkg = (tid & 3) << 2;
    const float* Arow0 = A + (long long)(bm + ar0) * lda + akg0;
    const float* Arow1 = A + (long long)(bm + ar1) * lda + akg1;
    const float* Brow  = Bm + (long long)(bn + br) * ldb + bkg;

    double acc[8][4] = {};
    for (int k0 = 0; k0 < Kdim; k0 += 16) {
        float4 a0 = *(const float4*)(Arow0 + k0);
        float4 a1 = *(const float4*)(Arow1 + k0);
        float4 b0 = *(const float4*)(Brow + k0);
        __syncthreads();
        As[akg0+0][ar0]=a0.x; As[akg0+1][ar0]=a0.y; As[akg0+2][ar0]=a0.z; As[akg0+3][ar0]=a0.w;
        As[akg1+0][ar1]=a1.x; As[akg1+1][ar1]=a1.y; As[akg1+2][ar1]=a1.z; As[akg1+3][ar1]=a1.w;
        Bs[bkg+0][br]=b0.x; Bs[bkg+1][br]=b0.y; Bs[bkg+2][br]=b0.z; Bs[bkg+3][br]=b0.w;
        __syncthreads();
        float cacc[8][4] = {};
        #pragma unroll
        for (int kk = 0; kk < 16; ++kk) {
            float a[8], b[4];
            #pragma unroll
            for (int i=0;i<8;i++) a[i] = As[kk][ty*8+i];
            #pragma unroll
            for (int j=0;j<4;j++) b[j] = Bs[kk][tx*4+j];
            #pragma unroll
            for (int i=0;i<8;i++)
                #pragma unroll
                for (int j=0;j<4;j++)
                    cacc[i][j] = fmaf(a[i], b[j], cacc[i][j]);
        }
        #pragma unroll
        for (int i=0;i<8;i++)
            #pragma unroll
            for (int j=0;j<4;j++)
                acc[i][j] += (double)cacc[i][j];
    }
    #pragma unroll
    for (int i=0;i<8;i++){
        const int row = bm + ty*8 + i;
        #pragma unroll
        for (int j=0;j<4;j++){
            const int col = bn + tx*4 + j;
            double v = acc[i][j];
            if constexpr (FLAGS & GF_BIAS) v += (double)bias[col];
            if constexpr (FLAGS & GF_POS)  v += (double)pos[(long long)(row & 511)*512 + col];
            if constexpr (FLAGS & GF_ADD)  v += (double)addsrc[(long long)row*ldc + col];
            if constexpr (FLAGS & GF_ACC)  v += (double)C[(long long)row*ldc + col];
            if constexpr (FLAGS & GF_RELU) v = (v > 0.0) ? v : 0.0;
            C[(long long)row*ldc + col] = (float)v;
        }
    }
}

// ---------------- conv1d as implicit GEMM: 128x64 tile, 8x4, BK=16 -----------
template<int KT>
__global__ __launch_bounds__(256)
void conv_relu_r12(const float* __restrict__ xp, const float* __restrict__ wt,
                   const float* __restrict__ bias, float* __restrict__ outp)
{
    constexpr int PAD = KT / 2;
    constexpr int KD  = KT * 512;
    __shared__ float As[16][132];
    __shared__ float Bs[16][68];
    const int tid = threadIdx.x;
    const int tx = tid & 15, ty = tid >> 4;
    const int bm = blockIdx.x * 128, bn = blockIdx.y * 64;
    const int ar0 = tid >> 2,         akg0 = (tid & 3) << 2;
    const int ar1 = (tid + 256) >> 2, akg1 = akg0;
    const int br = tid >> 2, bkg = (tid & 3) << 2;
    const int n0 = bm + ar0, s0 = n0 & 511;
    const int n1 = bm + ar1, s1 = n1 & 511;
    const float* Brow = wt + (long long)(bn + br) * KD + bkg;

    double acc[8][4] = {};
    for (int k0 = 0; k0 < KD; k0 += 16) {
        const int t  = k0 >> 9;
        const int ib = (k0 & 511);
        const int sp0 = s0 + t - PAD;
        const int sp1 = s1 + t - PAD;
        float4 a0 = make_float4(0.f,0.f,0.f,0.f);
        float4 a1 = make_float4(0.f,0.f,0.f,0.f);
        if (sp0 >= 0 && sp0 < 512)
            a0 = *(const float4*)(xp + (long long)(n0 + t - PAD)*512 + ib + akg0);
        if (sp1 >= 0 && sp1 < 512)
            a1 = *(const float4*)(xp + (long long)(n1 + t - PAD)*512 + ib + akg1);
        float4 b0 = *(const float4*)(Brow + k0);
        __syncthreads();
        As[akg0+0][ar0]=a0.x; As[akg0+1][ar0]=a0.y; As[akg0+2][ar0]=a0.z; As[akg0+3][ar0]=a0.w;
        As[akg1+0][ar1]=a1.x; As[akg1+1][ar1]=a1.y; As[akg1+2][ar1]=a1.z; As[akg1+3][ar1]=a1.w;
        Bs[bkg+0][br]=b0.x; Bs[bkg+1][br]=b0.y; Bs[bkg+2][br]=b0.z; Bs[bkg+3][br]=b0.w;
        __syncthreads();
        float cacc[8][4] = {};
        #pragma unroll
        for (int kk = 0; kk < 16; ++kk) {
            float a[8], b[4];
            #pragma unroll
            for (int i=0;i<8;i++) a[i] = As[kk][ty*8+i];
            #pragma unroll
            for (int j=0;j<4;j++) b[j] = Bs[kk][tx*4+j];
            #pragma unroll
            for (int i=0;i<8;i++)
                #pragma unroll
                for (int j=0;j<4;j++)
                    cacc[i][j] = fmaf(a[i], b[j], cacc[i][j]);
        }
        #pragma unroll
        for (int i=0;i<8;i++)
            #pragma unroll
            for (int j=0;j<4;j++)
                acc[i][j] += (double)cacc[i][j];
    }
    #pragma unroll
    for (int i=0;i<8;i++){
        const int row = bm + ty*8 + i;
        #pragma unroll
        for (int j=0;j<4;j++){
            const int col = bn + tx*4 + j;
            double v = acc[i][j] + (double)bias[col];
            outp[(long long)row*512 + col] = (float)((v > 0.0) ? v : 0.0);
        }
    }
}

// conv weight transpose: w[o][i][t] -> wt[o][t][i]
template<int KT>
__global__ __launch_bounds__(256)
void conv_w_tr_r12(const float* __restrict__ w, float* __restrict__ wt)
{
    long long i = (long long)blockIdx.x*256 + threadIdx.x;
    int o  = (int)(i / (512*KT));
    int rem= (int)(i % (512*KT));
    int t  = rem >> 9;
    int ii = rem & 511;
    wt[i] = w[(long long)o*512*KT + (long long)ii*KT + t];
}

// ---------------- fused attention (unchanged) --------------------------------
__global__ __launch_bounds__(256)
void attn_fused_r12(const float* __restrict__ proj, const float* __restrict__ inw,
                    const float* __restrict__ inb, const float* __restrict__ Kbuf,
                    const float* __restrict__ Vbuf, float* __restrict__ att)
{
    __shared__ float Qs[64][65];
    __shared__ float Kt[64][65];   // K tile, then P tile
    __shared__ float Vt[64][65];
    const int tid = threadIdx.x;
    const int tx = tid & 15, ty = tid >> 4;
    const int bid = blockIdx.x;
    const int qt = bid & 7, h = (bid >> 3) & 7, b = bid >> 6;
    const int row0 = b*512 + qt*64;
    const int lr = tid >> 2, lk = (tid & 3) << 2;

    { // Q = (proj @ Wq^T + bq) * 0.125, chunked accumulate
        double qa[4][4] = {};
        const float* Arow = proj + (long long)(row0 + lr)*512 + lk;
        const float* Brow = inw  + (long long)(h*64 + lr)*512 + lk;
        for (int k0 = 0; k0 < 512; k0 += 16) {
            float4 av = *(const float4*)(Arow + k0);
            float4 bv = *(const float4*)(Brow + k0);
            __syncthreads();
            Kt[lk+0][lr]=av.x; Kt[lk+1][lr]=av.y; Kt[lk+2][lr]=av.z; Kt[lk+3][lr]=av.w;
            Vt[lk+0][lr]=bv.x; Vt[lk+1][lr]=bv.y; Vt[lk+2][lr]=bv.z; Vt[lk+3][lr]=bv.w;
            __syncthreads();
            float c[4][4] = {};
            #pragma unroll
            for (int kk = 0; kk < 16; ++kk) {
                float a[4], bb[4];
                #pragma unroll
                for (int i=0;i<4;i++) a[i] = Kt[kk][ty*4+i];
                #pragma unroll
                for (int j=0;j<4;j++) bb[j] = Vt[kk][tx*4+j];
                #pragma unroll
                for (int i=0;i<4;i++)
                    #pragma unroll
                    for (int j=0;j<4;j++)
                        c[i][j] = fmaf(a[i], bb[j], c[i][j]);
            }
            #pragma unroll
            for (int i=0;i<4;i++)
                #pragma unroll
                for (int j=0;j<4;j++)
                    qa[i][j] += (double)c[i][j];
        }
        __syncthreads();
        #pragma unroll
        for (int i=0;i<4;i++)
            #pragma unroll
            for (int j=0;j<4;j++)
                Qs[ty*4+i][tx*4+j] = (float)((qa[i][j] + (double)inb[h*64 + tx*4+j]) * 0.125);
    }

    float m[4];
    double l[4], acc[4][4] = {};
    #pragma unroll
    for (int i=0;i<4;i++){ m[i] = -1e30f; l[i] = 0.0; }

    for (int kv = 0; kv < 512; kv += 64) {
        __syncthreads();
        #pragma unroll
        for (int u = 0; u < 16; ++u) {
            int e = u*256 + tid;
            int r = e >> 6, c = e & 63;
            Kt[r][c] = Kbuf[(long long)(b*512 + kv + r)*512 + h*64 + c];
            Vt[r][c] = Vbuf[(long long)(b*512 + kv + r)*512 + h*64 + c];
        }
        __syncthreads();
        // scores: chunked f32 FMA, f64 combine
        double scd[4][4] = {};
        for (int d0 = 0; d0 < 64; d0 += 16) {
            float c[4][4] = {};
            #pragma unroll
            for (int dd = 0; dd < 16; ++dd) {
                float a[4], bb[4];
                #pragma unroll
                for (int i=0;i<4;i++) a[i] = Qs[ty*4+i][d0+dd];
                #pragma unroll
                for (int j=0;j<4;j++) bb[j] = Kt[tx*4+j][d0+dd];
                #pragma unroll
                for (int i=0;i<4;i++)
                    #pragma unroll
                    for (int j=0;j<4;j++)
                        c[i][j] = fmaf(a[i], bb[j], c[i][j]);
            }
            #pragma unroll
            for (int i=0;i<4;i++)
                #pragma unroll
                for (int j=0;j<4;j++)
                    scd[i][j] += (double)c[i][j];
        }
        float sc[4][4];
        #pragma unroll
        for (int i=0;i<4;i++)
            #pragma unroll
            for (int j=0;j<4;j++)
                sc[i][j] = (float)scd[i][j];
        // online softmax: f32 max/exp, f64 sums
        #pragma unroll
        for (int i=0;i<4;i++){
            float tm = fmaxf(fmaxf(sc[i][0],sc[i][1]), fmaxf(sc[i][2],sc[i][3]));
            #pragma unroll
            for (int msk=1; msk<16; msk<<=1) tm = fmaxf(tm, __shfl_xor(tm, msk, 64));
            float mn = fmaxf(m[i], tm);
            float scale = expf(m[i] - mn);
            double rs = 0.0;
            #pragma unroll
            for (int j=0;j<4;j++){ float p = expf(sc[i][j]-mn); sc[i][j]=p; rs += (double)p; }
            #pragma unroll
            for (int msk=1; msk<16; msk<<=1) rs += __shfl_xor(rs, msk, 64);
            l[i] = l[i]*(double)scale + rs;
            m[i] = mn;
            #pragma unroll
            for (int j=0;j<4;j++) acc[i][j] *= (double)scale;
        }
        __syncthreads();   // all sc reads of Kt done; reuse Kt as P tile (f32)
        #pragma unroll
        for (int i=0;i<4;i++)
            #pragma unroll
            for (int j=0;j<4;j++)
                Kt[ty*4+i][tx*4+j] = sc[i][j];
        __syncthreads();
        // PV: chunked f32 FMA, f64 combine
        for (int d0 = 0; d0 < 64; d0 += 16) {
            float c[4][4] = {};
            #pragma unroll
            for (int dd = 0; dd < 16; ++dd) {
                float p[4], v[4];
                #pragma unroll
                for (int i=0;i<4;i++) p[i] = Kt[ty*4+i][d0+dd];
                #pragma unroll
                for (int j=0;j<4;j++) v[j] = Vt[d0+dd][tx*4+j];
                #pragma unroll
                for (int i=0;i<4;i++)
                    #pragma unroll
                    for (int j=0;j<4;j++)
                        c[i][j] = fmaf(p[i], v[j], c[i][j]);
            }
            #pragma unroll
            for (int i=0;i<4;i++)
                #pragma unroll
                for (int j=0;j<4;j++)
                    acc[i][j] += (double)c[i][j];
        }
    }
    #pragma unroll
    for (int i=0;i<4;i++)
        #pragma unroll
        for (int j=0;j<4;j++)
            att[(long long)(row0 + ty*4+i)*512 + h*64 + tx*4+j] = (float)(acc[i][j] / l[i]);
}

// ---------------- row sum of squares (f64), 512-col rows ---------------------
__global__ __launch_bounds__(256)
void row_sumsq_r12(const float* __restrict__ X, double* __restrict__ outp)
{
    const int row  = blockIdx.x*4 + (threadIdx.x >> 6);
    const int lane = threadIdx.x & 63;
    double s = 0.0;
    #pragma unroll
    for (int u = 0; u < 8; ++u) {
        float v = X[(long long)row*512 + lane + u*64];
        s += (double)v * (double)v;
    }
    #pragma unroll
    for (int msk = 32; msk; msk >>= 1) s += __shfl_xor(s, msk, 64);
    if (lane == 0) outp[row] = s;
}

// ---------------- VQ argmin: ct-split x4, BK=32, chunk-16 dots (r11 verbatim) -
__global__ __launch_bounds__(256)
void vq_argmin_r12(const float* __restrict__ enc, const float* __restrict__ cb,
                   const double* __restrict__ Asum, const double* __restrict__ cbB,
                   float* __restrict__ pbv, int* __restrict__ pbi)
{
    __shared__ float Es[32][68];
    __shared__ float Cs[32][68];
    __shared__ float bv_s[64][17];
    __shared__ int   bi_s[64][17];
    const int tid = threadIdx.x;
    const int tx = tid & 15, ty = tid >> 4;
    const int lr = tid >> 2, lk = (tid & 3) << 2;
    const int bm  = blockIdx.x * 64;
    const int ct0 = blockIdx.y * 512;
    float bestv[4]; int besti[4];
    #pragma unroll
    for (int i=0;i<4;i++){ bestv[i] = 3.0e38f; besti[i] = 2048; }

    for (int ct = ct0; ct < ct0 + 512; ct += 64) {
        double macc[4][4] = {};
        for (int k0 = 0; k0 < 512; k0 += 32) {
            float4 av0 = *(const float4*)(enc + (long long)(bm + lr)*512 + k0 + lk);
            float4 av1 = *(const float4*)(enc + (long long)(bm + lr)*512 + k0 + 16 + lk);
            float4 bv0 = *(const float4*)(cb  + (long long)(ct + lr)*512 + k0 + lk);
            float4 bv1 = *(const float4*)(cb  + (long long)(ct + lr)*512 + k0 + 16 + lk);
            __syncthreads();
            Es[lk+0][lr]=av0.x; Es[lk+1][lr]=av0.y; Es[lk+2][lr]=av0.z; Es[lk+3][lr]=av0.w;
            Es[lk+16][lr]=av1.x; Es[lk+17][lr]=av1.y; Es[lk+18][lr]=av1.z; Es[lk+19][lr]=av1.w;
            Cs[lk+0][lr]=bv0.x; Cs[lk+1][lr]=bv0.y; Cs[lk+2][lr]=bv0.z; Cs[lk+3][lr]=bv0.w;
            Cs[lk+16][lr]=bv1.x; Cs[lk+17][lr]=bv1.y; Cs[lk+18][lr]=bv1.z; Cs[lk+19][lr]=bv1.w;
            __syncthreads();
            {
                float cacc[4][4] = {};
                #pragma unroll
                for (int kk = 0; kk < 16; ++kk) {
                    float a[4], b[4];
                    #pragma unroll
                    for (int i=0;i<4;i++) a[i] = Es[kk][ty*4+i];
                    #pragma unroll
                    for (int j=0;j<4;j++) b[j] = Cs[kk][tx*4+j];
                    #pragma unroll
                    for (int i=0;i<4;i++)
                        #pragma unroll
                        for (int j=0;j<4;j++)
                            cacc[i][j] = fmaf(a[i], b[j], cacc[i][j]);
                }
                #pragma unroll
                for (int i=0;i<4;i++)
                    #pragma unroll
                    for (int j=0;j<4;j++)
                        macc[i][j] += (double)cacc[i][j];
            }
            {
                float cacc[4][4] = {};
                #pragma unroll
                for (int kk = 16; kk < 32; ++kk) {
                    float a[4], b[4];
                    #pragma unroll
                    for (int i=0;i<4;i++) a[i] = Es[kk][ty*4+i];
                    #pragma unroll
                    for (int j=0;j<4;j++) b[j] = Cs[kk][tx*4+j];
                    #pragma unroll
                    for (int i=0;i<4;i++)
                        #pragma unroll
                        for (int j=0;j<4;j++)
                            cacc[i][j] = fmaf(a[i], b[j], cacc[i][j]);
                }
                #pragma unroll
                for (int i=0;i<4;i++)
                    #pragma unroll
                    for (int j=0;j<4;j++)
                        macc[i][j] += (double)cacc[i][j];
            }
        }
        #pragma unroll
        for (int i=0;i<4;i++){
            const float anf = (float)Asum[bm + ty*4 + i];
            #pragma unroll
            for (int j=0;j<4;j++){
                const int ci = ct + tx*4 + j;
                const float bf  = (float)cbB[ci];
                const float s1  = anf + bf;                  // fl32(A+B)
                const float df  = (float)(2.0 * macc[i][j]); // fl32(2*dot)
                const float qd  = s1 - df;                   // fl32 combine
                if (qd < bestv[i] || (qd == bestv[i] && ci < besti[i])) {
                    bestv[i] = qd; besti[i] = ci;
                }
            }
        }
    }
    #pragma unroll
    for (int i=0;i<4;i++){ bv_s[ty*4+i][tx] = bestv[i]; bi_s[ty*4+i][tx] = besti[i]; }
    __syncthreads();
    if (tid < 64) {
        float bv = bv_s[tid][0]; int bi = bi_s[tid][0];
        #pragma unroll
        for (int x = 1; x < 16; ++x) {
            float v = bv_s[tid][x]; int ii = bi_s[tid][x];
            if (v < bv || (v == bv && ii < bi)) { bv = v; bi = ii; }
        }
        pbv[(long long)blockIdx.y*16384 + bm + tid] = bv;
        pbi[(long long)blockIdx.y*16384 + bm + tid] = bi;
    }
}

__global__ __launch_bounds__(256)
void vq_reduce_r12(const float* __restrict__ pbv, const int* __restrict__ pbi,
                   int* __restrict__ idxout)
{
    int n = blockIdx.x*256 + threadIdx.x;
    if (n >= 16384) return;
    float bv = pbv[n]; int bi = pbi[n];
    #pragma unroll
    for (int q = 1; q < 4; ++q) {
        float v = pbv[q*16384 + n]; int ii = pbi[q*16384 + n];
        if (v < bv || (v == bv && ii < bi)) { bv = v; bi = ii; }
    }
    idxout[n] = bi & 2047;
}

// ---------------- vq loss: two-stage, atomic-free ----------------------------
__global__ __launch_bounds__(256)
void vq_loss_partial_r12(const float* __restrict__ enc, const float* __restrict__ cb,
                         const int* __restrict__ idxp, double* __restrict__ part)
{
    __shared__ double red[4];
    const int row  = blockIdx.x*4 + (threadIdx.x >> 6);
    const int lane = threadIdx.x & 63;
    const int ci = idxp[row] & 2047;
    double s = 0.0;
    #pragma unroll
    for (int u = 0; u < 8; ++u) {
        int d = lane + u*64;
        double dv = (double)cb[(long long)ci*512 + d] - (double)enc[(long long)row*512 + d];
        s += dv * dv;
    }
    #pragma unroll
    for (int msk = 32; msk; msk >>= 1) s += __shfl_xor(s, msk, 64);
    if (lane == 0) red[threadIdx.x >> 6] = s;
    __syncthreads();
    if (threadIdx.x == 0)
        part[blockIdx.x] = red[0] + red[1] + red[2] + red[3];
}

// ---------------- regime softmax rows (in place) -----------------------------
__global__ __launch_bounds__(256)
void softmax_rows_r12(float* __restrict__ R)
{
    const int row = blockIdx.x;
    const int tid = threadIdx.x;
    __shared__ float  redf[256];
    __shared__ double redd[256];
    float* p = R + (long long)row * 2048;
    float mx = -1e30f;
    for (int c = tid; c < 2048; c += 256) mx = fmaxf(mx, p[c]);
    redf[tid] = mx; __syncthreads();
    for (int s2 = 128; s2; s2 >>= 1) { if (tid < s2) redf[tid] = fmaxf(redf[tid], redf[tid+s2]); __syncthreads(); }
    mx = redf[0];
    double sum = 0.0;
    for (int c = tid; c < 2048; c += 256) { float e = expf(p[c] - mx); p[c] = e; sum += e; }
    redd[tid] = sum; __syncthreads();
    for (int s2 = 128; s2; s2 >>= 1) { if (tid < s2) redd[tid] += redd[tid+s2]; __syncthreads(); }
    double tot = redd[0];
    for (int c = tid; c < 2048; c += 256) p[c] = (float)((double)p[c] / tot);
}

// ---------------- hash table per codebook entry ------------------------------
__global__ __launch_bounds__(256)
void hash_table_r12(const float* __restrict__ cb, const float* __restrict__ hw,
                    float* __restrict__ T)
{
    const int k = blockIdx.x*4 + (threadIdx.x >> 6);
    const int j = threadIdx.x & 63;
    double s = 0.0;
    for (int d = 0; d < 512; ++d)
        s += (double)cb[(long long)k*512 + d] * (double)hw[(long long)j*512 + d];
    T[(long long)k*64 + j] = (s > 0.0) ? 1.0f : 0.0f;
}

// ---------------- output writers (f32 d_out) ---------------------------------
__global__ void write_loss_r12(const double* __restrict__ part,
                               float* __restrict__ out)
{
    __shared__ double red[256];
    double s = 0.0;
    for (int i = threadIdx.x; i < 4096; i += 256) s += part[i];
    red[threadIdx.x] = s; __syncthreads();
    for (int s2 = 128; s2; s2 >>= 1) {
        if (threadIdx.x < s2) red[threadIdx.x] += red[threadIdx.x + s2];
        __syncthreads();
    }
    if (threadIdx.x == 0)
        out[O_LOSS] = (float)(1.25 * red[0] / 8388608.0);
}

__global__ __launch_bounds__(256)
void write_regime_r12(const float* __restrict__ R, const int* __restrict__ idxp,
                      float* __restrict__ out)
{
    long long i = (long long)blockIdx.x*256 + threadIdx.x;
    if (i >= 33554432LL) return;
    int n = (int)(i >> 11), c = (int)(i & 2047);
    int ci = idxp[n] & 2047;
    out[O_REG + i] = R[(long long)ci*2048 + c];
}

__global__ __launch_bounds__(256)
void write_hash_r12(const float* __restrict__ T, const int* __restrict__ idxp,
                    float* __restrict__ out)
{
    long long i = (long long)blockIdx.x*256 + threadIdx.x;
    if (i >= 1048576LL) return;
    int n = (int)(i >> 6), j = (int)(i & 63);
    int ci = idxp[n] & 2047;
    out[O_HASH + i] = T[(long long)ci*64 + j];
}

__global__ __launch_bounds__(256)
void write_idx_r12(const int* __restrict__ idxp, float* __restrict__ out)
{
    int n = blockIdx.x*256 + threadIdx.x;
    if (n >= 16384) return;
    out[O_IDX + n] = (float)(idxp[n] & 2047);
}

__global__ __launch_bounds__(256)
void write_quant_r12(const float* __restrict__ cb, const int* __restrict__ idxp,
                     float* __restrict__ out)
{
    long long i = (long long)blockIdx.x*256 + threadIdx.x;
    if (i >= 8388608LL) return;
    int n = (int)(i >> 9), d = (int)(i & 511);
    int ci = idxp[n] & 2047;
    out[O_QUANT + i] = cb[(long long)ci*512 + d];
}

// ---------------- launcher ----------------------------------------------------
extern "C" void kernel_launch(void* const* d_in, const int* in_sizes, int n_in,
                              void* d_out, int out_size, void* d_ws, size_t ws_size,
                              hipStream_t stream)
{
    (void)in_sizes; (void)n_in; (void)out_size;
    const float* market = (const float*)d_in[0];
    const float* W_in   = (const float*)d_in[1];
    const float* b_in   = (const float*)d_in[2];
    const float* pos    = (const float*)d_in[3];
    const float* c3w = (const float*)d_in[4];  const float* c3b = (const float*)d_in[5];
    const float* c5w = (const float*)d_in[6];  const float* c5b = (const float*)d_in[7];
    const float* c7w = (const float*)d_in[8];  const float* c7b = (const float*)d_in[9];
    const float* c9w = (const float*)d_in[10]; const float* c9b = (const float*)d_in[11];
    const float* msw = (const float*)d_in[12]; const float* msb = (const float*)d_in[13];
    const float* inw = (const float*)d_in[14]; const float* inb = (const float*)d_in[15];
    const float* aow = (const float*)d_in[16]; const float* aob = (const float*)d_in[17];
    const float* cb  = (const float*)d_in[18]; const float* hw  = (const float*)d_in[19];
    const float* r1w = (const float*)d_in[20]; const float* r1b = (const float*)d_in[21];
    const float* r2w = (const float*)d_in[22]; const float* r2b = (const float*)d_in[23];

    if (ws_size < (size_t)W_END * sizeof(float)) return; // insufficient scratch

    float* ws    = (float*)d_ws;
    float* xp    = ws + W_XP;
    float* convt = ws + W_CT;
    float* projp = ws + W_PROJ;
    float* wt3   = ws + W_VW;        // conv weights time-share the V region
    float* wt5   = wt3 + 512*512*3;
    float* wt7   = wt5 + 512*512*5;
    float* wt9   = wt7 + 512*512*7;
    float* Vbufp = ws + W_VW;
    float* hregp = ws + W_HREG;
    float* Tp    = ws + W_T;
    int*    idxp  = (int*)(ws + W_IDX);
    double* asump = (double*)(ws + W_ASUM);
    double* cbbp  = (double*)(ws + W_CBB);
    double* lpart = (double*)(ws + W_LPART);
    float*  pbvp  = ws + W_PBV;
    int*    pbip  = (int*)(ws + W_PBI);

    float* out = (float*)d_out;   // f32 output buffer

    float* attp  = xp;      // xp dead after conv9
    float* Kbufp = convt;   // conv_tmp dead after last ms gemm
    float* encp  = convt;   // K dead after attn
    float* Rp    = projp;   // proj dead after enc gemm

    // conv weight transposes
    conv_w_tr_r12<3><<<3072, 256, 0, stream>>>(c3w, wt3);
    conv_w_tr_r12<5><<<5120, 256, 0, stream>>>(c5w, wt5);
    conv_w_tr_r12<7><<<7168, 256, 0, stream>>>(c7w, wt7);
    conv_w_tr_r12<9><<<9216, 256, 0, stream>>>(c9w, wt9);

    const dim3 gN512(128, 8);     // 128-row tiles x 64-col tiles

    // xp = market @ W_in^T + b_in + pos_enc
    gemm_bt_r12<GF_BIAS|GF_POS><<<gN512, 256, 0, stream>>>(market, W_in, b_in, pos, nullptr, xp, 512, 512, 512, 512);

    // proj = sum_c relu(conv_c(xp)) @ msW_c^T (+ bias on first)
    conv_relu_r12<3><<<gN512, 256, 0, stream>>>(xp, wt3, c3b, convt);
    gemm_bt_r12<GF_BIAS><<<gN512, 256, 0, stream>>>(convt, msw + 0*512, msb, nullptr, nullptr, projp, 512, 512, 2048, 512);
    conv_relu_r12<5><<<gN512, 256, 0, stream>>>(xp, wt5, c5b, convt);
    gemm_bt_r12<GF_ACC><<<gN512, 256, 0, stream>>>(convt, msw + 1*512, nullptr, nullptr, nullptr, projp, 512, 512, 2048, 512);
    conv_relu_r12<7><<<gN512, 256, 0, stream>>>(xp, wt7, c7b, convt);
    gemm_bt_r12<GF_ACC><<<gN512, 256, 0, stream>>>(convt, msw + 2*512, nullptr, nullptr, nullptr, projp, 512, 512, 2048, 512);
    conv_relu_r12<9><<<gN512, 256, 0, stream>>>(xp, wt9, c9b, convt);
    gemm_bt_r12<GF_ACC><<<gN512, 256, 0, stream>>>(convt, msw + 3*512, nullptr, nullptr, nullptr, projp, 512, 512, 2048, 512);

    // K, V projections (Q fused into attention). V overwrites wt (dead).
    gemm_bt_r12<GF_BIAS><<<gN512, 256, 0, stream>>>(projp, inw + 512*512,  inb + 512,  nullptr, nullptr, Kbufp, 512, 512, 512, 512);
    gemm_bt_r12<GF_BIAS><<<gN512, 256, 0, stream>>>(projp, inw + 1024*512, inb + 1024, nullptr, nullptr, Vbufp, 512, 512, 512, 512);

    attn_fused_r12<<<2048, 256, 0, stream>>>(projp, inw, inb, Kbufp, Vbufp, attp);

    // enc = proj + att @ attn_out_w^T + attn_out_b   (enc overwrites K region)
    gemm_bt_r12<GF_BIAS|GF_ADD><<<gN512, 256, 0, stream>>>(attp, aow, aob, nullptr, projp, encp, 512, 512, 512, 512);

    // VQ
    row_sumsq_r12<<<4096, 256, 0, stream>>>(encp, asump);
    row_sumsq_r12<<<512,  256, 0, stream>>>(cb, cbbp);
    vq_argmin_r12<<<dim3(256, 4), 256, 0, stream>>>(encp, cb, asump, cbbp, pbvp, pbip);
    vq_reduce_r12<<<64, 256, 0, stream>>>(pbvp, pbip, idxp);
    vq_loss_partial_r12<<<4096, 256, 0, stream>>>(encp, cb, idxp, lpart);

    // regime tables per codebook entry (R overwrites proj region, now dead)
    gemm_bt_r12<GF_BIAS|GF_RELU><<<dim3(16, 4),  256, 0, stream>>>(cb, r1w, r1b, nullptr, nullptr, hregp, 512, 512, 512, 256);
    gemm_bt_r12<GF_BIAS><<<dim3(16, 32), 256, 0, stream>>>(hregp, r2w, r2b, nullptr, nullptr, Rp, 256, 256, 256, 2048);
    softmax_rows_r12<<<2048, 256, 0, stream>>>(Rp);
    hash_table_r12<<<512, 256, 0, stream>>>(cb, hw, Tp);

    // ---- output writes (f32), every chunk fully covered each call ----
    write_loss_r12<<<1, 256, 0, stream>>>(lpart, out);
    write_regime_r12<<<131072, 256, 0, stream>>>(Rp, idxp, out);
    write_hash_r12<<<4096, 256, 0, stream>>>(Tp, idxp, out);
    write_idx_r12<<<64, 256, 0, stream>>>(idxp, out);
    write_quant_r12<<<32768, 256, 0, stream>>>(cb, idxp, out);
}

// Round 13
// 4865.595 us; speedup vs baseline: 1.1443x; 1.1443x over previous
//
#include <hip/hip_runtime.h>
#include <hip/hip_bf16.h>

// ---------------- problem constants ----------------
// B=32, S=512, D=512, K=2048, NHEADS=8, NHASH=4, HLEN=16; N = B*S = 16384.
// d_out is FLOAT32.
// r13: conv/GEMM accumulate in PLAIN f32 (np-sgemm-class rounding; justified
// by jax-f32 == np-f32 argmin agreement for this seed). VQ argmin keeps the
// verified f64-dot + f32-absorbed compare + first-index ties verbatim.
// Tile: 128x128, 8x8 per thread, BK=16.

#define GF_BIAS 1
#define GF_RELU 2
#define GF_ADD  4
#define GF_POS  8
#define GF_ACC  16

// output layout (f32 elements), return order — total 43,008,001
static constexpr long long O_QUANT = 0LL;        // 8388608
static constexpr long long O_LOSS  = 8388608LL;  // 1
static constexpr long long O_IDX   = 8388609LL;  // 16384
static constexpr long long O_HASH  = 8404993LL;  // 1048576
static constexpr long long O_REG   = 9453569LL;  // 33554432
static constexpr long long O_END   = 43008001LL;

// workspace layout (f32 element offsets) — total 34,402,304 f32 = 131.2 MiB
static constexpr long long W_XP    = 0LL;
static constexpr long long W_CT    = 8388608LL;
static constexpr long long W_PROJ  = 16777216LL;
static constexpr long long W_VW    = 25165824LL;
static constexpr long long W_HREG  = 33554432LL;
static constexpr long long W_T     = 34078720LL;
static constexpr long long W_IDX   = 34209792LL;
static constexpr long long W_ASUM  = 34226176LL;  // 16384 f64
static constexpr long long W_CBB   = 34258944LL;  // 2048 f64
static constexpr long long W_LPART = 34263040LL;  // 4096 f64
static constexpr long long W_PBV   = 34271232LL;  // 4*16384 f32 partial best val
static constexpr long long W_PBI   = 34336768LL;  // 4*16384 int partial best idx
static constexpr long long W_END   = 34402304LL;

// ---------------- generic GEMM: 128x128 tile, 8x8/thread, BK=16, f32 acc -----
template<int FLAGS>
__global__ __launch_bounds__(256)
void gemm_bt_r13(const float* __restrict__ A, const float* __restrict__ Bm,
                 const float* __restrict__ bias, const float* __restrict__ pos,
                 const float* __restrict__ addsrc, float* __restrict__ C,
                 int Kdim, int lda, int ldb, int ldc)
{
    __shared__ float As[16][132];   // [k][row]
    __shared__ float Bs[16][132];   // [k][col]
    const int tid = threadIdx.x;
    const int tx = tid & 15, ty = tid >> 4;
    const int bm = blockIdx.x * 128, bn = blockIdx.y * 128;
    const int r0 = tid >> 2;            // 0..63
    const int kg = (tid & 3) << 2;      // 0,4,8,12
    const float* Arow0 = A  + (long long)(bm + r0) * lda + kg;
    const float* Arow1 = A  + (long long)(bm + r0 + 64) * lda + kg;
    const float* Brow0 = Bm + (long long)(bn + r0) * ldb + kg;
    const float* Brow1 = Bm + (long long)(bn + r0 + 64) * ldb + kg;

    float acc[8][8] = {};
    for (int k0 = 0; k0 < Kdim; k0 += 16) {
        float4 a0 = *(const float4*)(Arow0 + k0);
        float4 a1 = *(const float4*)(Arow1 + k0);
        float4 b0 = *(const float4*)(Brow0 + k0);
        float4 b1 = *(const float4*)(Brow1 + k0);
        __syncthreads();
        As[kg+0][r0]=a0.x; As[kg+1][r0]=a0.y; As[kg+2][r0]=a0.z; As[kg+3][r0]=a0.w;
        As[kg+0][r0+64]=a1.x; As[kg+1][r0+64]=a1.y; As[kg+2][r0+64]=a1.z; As[kg+3][r0+64]=a1.w;
        Bs[kg+0][r0]=b0.x; Bs[kg+1][r0]=b0.y; Bs[kg+2][r0]=b0.z; Bs[kg+3][r0]=b0.w;
        Bs[kg+0][r0+64]=b1.x; Bs[kg+1][r0+64]=b1.y; Bs[kg+2][r0+64]=b1.z; Bs[kg+3][r0+64]=b1.w;
        __syncthreads();
        #pragma unroll
        for (int kk = 0; kk < 16; ++kk) {
            float a[8], b[8];
            #pragma unroll
            for (int i=0;i<8;i++) a[i] = As[kk][ty*8+i];
            #pragma unroll
            for (int j=0;j<8;j++) b[j] = Bs[kk][tx*8+j];
            #pragma unroll
            for (int i=0;i<8;i++)
                #pragma unroll
                for (int j=0;j<8;j++)
                    acc[i][j] = fmaf(a[i], b[j], acc[i][j]);
        }
    }
    #pragma unroll
    for (int i=0;i<8;i++){
        const int row = bm + ty*8 + i;
        #pragma unroll
        for (int j=0;j<8;j++){
            const int col = bn + tx*8 + j;
            float v = acc[i][j];
            if constexpr (FLAGS & GF_BIAS) v += bias[col];
            if constexpr (FLAGS & GF_POS)  v += pos[(long long)(row & 511)*512 + col];
            if constexpr (FLAGS & GF_ADD)  v += addsrc[(long long)row*ldc + col];
            if constexpr (FLAGS & GF_ACC)  v += C[(long long)row*ldc + col];
            if constexpr (FLAGS & GF_RELU) v = fmaxf(v, 0.0f);
            C[(long long)row*ldc + col] = v;
        }
    }
}

// ---------------- conv1d as implicit GEMM: 128x128, 8x8, BK=16, f32 acc ------
template<int KT>
__global__ __launch_bounds__(256)
void conv_relu_r13(const float* __restrict__ xp, const float* __restrict__ wt,
                   const float* __restrict__ bias, float* __restrict__ outp)
{
    constexpr int PAD = KT / 2;
    constexpr int KD  = KT * 512;
    __shared__ float As[16][132];
    __shared__ float Bs[16][132];
    const int tid = threadIdx.x;
    const int tx = tid & 15, ty = tid >> 4;
    const int bm = blockIdx.x * 128, bn = blockIdx.y * 128;
    const int r0 = tid >> 2;
    const int kg = (tid & 3) << 2;
    const int n0 = bm + r0,      s0 = n0 & 511;
    const int n1 = bm + r0 + 64, s1 = n1 & 511;
    const float* Brow0 = wt + (long long)(bn + r0) * KD + kg;
    const float* Brow1 = wt + (long long)(bn + r0 + 64) * KD + kg;

    float acc[8][8] = {};
    for (int k0 = 0; k0 < KD; k0 += 16) {
        const int t  = k0 >> 9;
        const int ib = (k0 & 511) + kg;
        const int sp0 = s0 + t - PAD;
        const int sp1 = s1 + t - PAD;
        float4 a0 = make_float4(0.f,0.f,0.f,0.f);
        float4 a1 = make_float4(0.f,0.f,0.f,0.f);
        if (sp0 >= 0 && sp0 < 512)
            a0 = *(const float4*)(xp + (long long)(n0 + t - PAD)*512 + ib);
        if (sp1 >= 0 && sp1 < 512)
            a1 = *(const float4*)(xp + (long long)(n1 + t - PAD)*512 + ib);
        float4 b0 = *(const float4*)(Brow0 + k0);
        float4 b1 = *(const float4*)(Brow1 + k0);
        __syncthreads();
        As[kg+0][r0]=a0.x; As[kg+1][r0]=a0.y; As[kg+2][r0]=a0.z; As[kg+3][r0]=a0.w;
        As[kg+0][r0+64]=a1.x; As[kg+1][r0+64]=a1.y; As[kg+2][r0+64]=a1.z; As[kg+3][r0+64]=a1.w;
        Bs[kg+0][r0]=b0.x; Bs[kg+1][r0]=b0.y; Bs[kg+2][r0]=b0.z; Bs[kg+3][r0]=b0.w;
        Bs[kg+0][r0+64]=b1.x; Bs[kg+1][r0+64]=b1.y; Bs[kg+2][r0+64]=b1.z; Bs[kg+3][r0+64]=b1.w;
        __syncthreads();
        #pragma unroll
        for (int kk = 0; kk < 16; ++kk) {
            float a[8], b[8];
            #pragma unroll
            for (int i=0;i<8;i++) a[i] = As[kk][ty*8+i];
            #pragma unroll
            for (int j=0;j<8;j++) b[j] = Bs[kk][tx*8+j];
            #pragma unroll
            for (int i=0;i<8;i++)
                #pragma unroll
                for (int j=0;j<8;j++)
                    acc[i][j] = fmaf(a[i], b[j], acc[i][j]);
        }
    }
    #pragma unroll
    for (int i=0;i<8;i++){
        const int row = bm + ty*8 + i;
        #pragma unroll
        for (int j=0;j<8;j++){
            const int col = bn + tx*8 + j;
            float v = acc[i][j] + bias[col];
            outp[(long long)row*512 + col] = fmaxf(v, 0.0f);
        }
    }
}

// conv weight transpose: w[o][i][t] -> wt[o][t][i]
template<int KT>
__global__ __launch_bounds__(256)
void conv_w_tr_r13(const float* __restrict__ w, float* __restrict__ wt)
{
    long long i = (long long)blockIdx.x*256 + threadIdx.x;
    int o  = (int)(i / (512*KT));
    int rem= (int)(i % (512*KT));
    int t  = rem >> 9;
    int ii = rem & 511;
    wt[i] = w[(long long)o*512*KT + (long long)ii*KT + t];
}

// ---------------- fused attention (r12 verbatim) -----------------------------
__global__ __launch_bounds__(256)
void attn_fused_r13(const float* __restrict__ proj, const float* __restrict__ inw,
                    const float* __restrict__ inb, const float* __restrict__ Kbuf,
                    const float* __restrict__ Vbuf, float* __restrict__ att)
{
    __shared__ float Qs[64][65];
    __shared__ float Kt[64][65];
    __shared__ float Vt[64][65];
    const int tid = threadIdx.x;
    const int tx = tid & 15, ty = tid >> 4;
    const int bid = blockIdx.x;
    const int qt = bid & 7, h = (bid >> 3) & 7, b = bid >> 6;
    const int row0 = b*512 + qt*64;
    const int lr = tid >> 2, lk = (tid & 3) << 2;

    { // Q = (proj @ Wq^T + bq) * 0.125, chunked accumulate
        double qa[4][4] = {};
        const float* Arow = proj + (long long)(row0 + lr)*512 + lk;
        const float* Brow = inw  + (long long)(h*64 + lr)*512 + lk;
        for (int k0 = 0; k0 < 512; k0 += 16) {
            float4 av = *(const float4*)(Arow + k0);
            float4 bv = *(const float4*)(Brow + k0);
            __syncthreads();
            Kt[lk+0][lr]=av.x; Kt[lk+1][lr]=av.y; Kt[lk+2][lr]=av.z; Kt[lk+3][lr]=av.w;
            Vt[lk+0][lr]=bv.x; Vt[lk+1][lr]=bv.y; Vt[lk+2][lr]=bv.z; Vt[lk+3][lr]=bv.w;
            __syncthreads();
            float c[4][4] = {};
            #pragma unroll
            for (int kk = 0; kk < 16; ++kk) {
                float a[4], bb[4];
                #pragma unroll
                for (int i=0;i<4;i++) a[i] = Kt[kk][ty*4+i];
                #pragma unroll
                for (int j=0;j<4;j++) bb[j] = Vt[kk][tx*4+j];
                #pragma unroll
                for (int i=0;i<4;i++)
                    #pragma unroll
                    for (int j=0;j<4;j++)
                        c[i][j] = fmaf(a[i], bb[j], c[i][j]);
            }
            #pragma unroll
            for (int i=0;i<4;i++)
                #pragma unroll
                for (int j=0;j<4;j++)
                    qa[i][j] += (double)c[i][j];
        }
        __syncthreads();
        #pragma unroll
        for (int i=0;i<4;i++)
            #pragma unroll
            for (int j=0;j<4;j++)
                Qs[ty*4+i][tx*4+j] = (float)((qa[i][j] + (double)inb[h*64 + tx*4+j]) * 0.125);
    }

    float m[4];
    double l[4], acc[4][4] = {};
    #pragma unroll
    for (int i=0;i<4;i++){ m[i] = -1e30f; l[i] = 0.0; }

    for (int kv = 0; kv < 512; kv += 64) {
        __syncthreads();
        #pragma unroll
        for (int u = 0; u < 16; ++u) {
            int e = u*256 + tid;
            int r = e >> 6, c = e & 63;
            Kt[r][c] = Kbuf[(long long)(b*512 + kv + r)*512 + h*64 + c];
            Vt[r][c] = Vbuf[(long long)(b*512 + kv + r)*512 + h*64 + c];
        }
        __syncthreads();
        double scd[4][4] = {};
        for (int d0 = 0; d0 < 64; d0 += 16) {
            float c[4][4] = {};
            #pragma unroll
            for (int dd = 0; dd < 16; ++dd) {
                float a[4], bb[4];
                #pragma unroll
                for (int i=0;i<4;i++) a[i] = Qs[ty*4+i][d0+dd];
                #pragma unroll
                for (int j=0;j<4;j++) bb[j] = Kt[tx*4+j][d0+dd];
                #pragma unroll
                for (int i=0;i<4;i++)
                    #pragma unroll
                    for (int j=0;j<4;j++)
                        c[i][j] = fmaf(a[i], bb[j], c[i][j]);
            }
            #pragma unroll
            for (int i=0;i<4;i++)
                #pragma unroll
                for (int j=0;j<4;j++)
                    scd[i][j] += (double)c[i][j];
        }
        float sc[4][4];
        #pragma unroll
        for (int i=0;i<4;i++)
            #pragma unroll
            for (int j=0;j<4;j++)
                sc[i][j] = (float)scd[i][j];
        #pragma unroll
        for (int i=0;i<4;i++){
            float tm = fmaxf(fmaxf(sc[i][0],sc[i][1]), fmaxf(sc[i][2],sc[i][3]));
            #pragma unroll
            for (int msk=1; msk<16; msk<<=1) tm = fmaxf(tm, __shfl_xor(tm, msk, 64));
            float mn = fmaxf(m[i], tm);
            float scale = expf(m[i] - mn);
            double rs = 0.0;
            #pragma unroll
            for (int j=0;j<4;j++){ float p = expf(sc[i][j]-mn); sc[i][j]=p; rs += (double)p; }
            #pragma unroll
            for (int msk=1; msk<16; msk<<=1) rs += __shfl_xor(rs, msk, 64);
            l[i] = l[i]*(double)scale + rs;
            m[i] = mn;
            #pragma unroll
            for (int j=0;j<4;j++) acc[i][j] *= (double)scale;
        }
        __syncthreads();
        #pragma unroll
        for (int i=0;i<4;i++)
            #pragma unroll
            for (int j=0;j<4;j++)
                Kt[ty*4+i][tx*4+j] = sc[i][j];
        __syncthreads();
        for (int d0 = 0; d0 < 64; d0 += 16) {
            float c[4][4] = {};
            #pragma unroll
            for (int dd = 0; dd < 16; ++dd) {
                float p[4], v[4];
                #pragma unroll
                for (int i=0;i<4;i++) p[i] = Kt[ty*4+i][d0+dd];
                #pragma unroll
                for (int j=0;j<4;j++) v[j] = Vt[d0+dd][tx*4+j];
                #pragma unroll
                for (int i=0;i<4;i++)
                    #pragma unroll
                    for (int j=0;j<4;j++)
                        c[i][j] = fmaf(p[i], v[j], c[i][j]);
            }
            #pragma unroll
            for (int i=0;i<4;i++)
                #pragma unroll
                for (int j=0;j<4;j++)
                    acc[i][j] += (double)c[i][j];
        }
    }
    #pragma unroll
    for (int i=0;i<4;i++)
        #pragma unroll
        for (int j=0;j<4;j++)
            att[(long long)(row0 + ty*4+i)*512 + h*64 + tx*4+j] = (float)(acc[i][j] / l[i]);
}

// ---------------- row sum of squares (f64), 512-col rows ---------------------
__global__ __launch_bounds__(256)
void row_sumsq_r13(const float* __restrict__ X, double* __restrict__ outp)
{
    const int row  = blockIdx.x*4 + (threadIdx.x >> 6);
    const int lane = threadIdx.x & 63;
    double s = 0.0;
    #pragma unroll
    for (int u = 0; u < 8; ++u) {
        float v = X[(long long)row*512 + lane + u*64];
        s += (double)v * (double)v;
    }
    #pragma unroll
    for (int msk = 32; msk; msk >>= 1) s += __shfl_xor(s, msk, 64);
    if (lane == 0) outp[row] = s;
}

// ---------------- VQ argmin (r12 verbatim): f64 dots, absorbed compare -------
__global__ __launch_bounds__(256)
void vq_argmin_r13(const float* __restrict__ enc, const float* __restrict__ cb,
                   const double* __restrict__ Asum, const double* __restrict__ cbB,
                   float* __restrict__ pbv, int* __restrict__ pbi)
{
    __shared__ float Es[32][68];
    __shared__ float Cs[32][68];
    __shared__ float bv_s[64][17];
    __shared__ int   bi_s[64][17];
    const int tid = threadIdx.x;
    const int tx = tid & 15, ty = tid >> 4;
    const int lr = tid >> 2, lk = (tid & 3) << 2;
    const int bm  = blockIdx.x * 64;
    const int ct0 = blockIdx.y * 512;
    float bestv[4]; int besti[4];
    #pragma unroll
    for (int i=0;i<4;i++){ bestv[i] = 3.0e38f; besti[i] = 2048; }

    for (int ct = ct0; ct < ct0 + 512; ct += 64) {
        double macc[4][4] = {};
        for (int k0 = 0; k0 < 512; k0 += 32) {
            float4 av0 = *(const float4*)(enc + (long long)(bm + lr)*512 + k0 + lk);
            float4 av1 = *(const float4*)(enc + (long long)(bm + lr)*512 + k0 + 16 + lk);
            float4 bv0 = *(const float4*)(cb  + (long long)(ct + lr)*512 + k0 + lk);
            float4 bv1 = *(const float4*)(cb  + (long long)(ct + lr)*512 + k0 + 16 + lk);
            __syncthreads();
            Es[lk+0][lr]=av0.x; Es[lk+1][lr]=av0.y; Es[lk+2][lr]=av0.z; Es[lk+3][lr]=av0.w;
            Es[lk+16][lr]=av1.x; Es[lk+17][lr]=av1.y; Es[lk+18][lr]=av1.z; Es[lk+19][lr]=av1.w;
            Cs[lk+0][lr]=bv0.x; Cs[lk+1][lr]=bv0.y; Cs[lk+2][lr]=bv0.z; Cs[lk+3][lr]=bv0.w;
            Cs[lk+16][lr]=bv1.x; Cs[lk+17][lr]=bv1.y; Cs[lk+18][lr]=bv1.z; Cs[lk+19][lr]=bv1.w;
            __syncthreads();
            #pragma unroll
            for (int half = 0; half < 2; ++half) {
                float cacc[4][4] = {};
                #pragma unroll
                for (int kk2 = 0; kk2 < 16; ++kk2) {
                    const int kk = half*16 + kk2;
                    float a[4], b[4];
                    #pragma unroll
                    for (int i=0;i<4;i++) a[i] = Es[kk][ty*4+i];
                    #pragma unroll
                    for (int j=0;j<4;j++) b[j] = Cs[kk][tx*4+j];
                    #pragma unroll
                    for (int i=0;i<4;i++)
                        #pragma unroll
                        for (int j=0;j<4;j++)
                            cacc[i][j] = fmaf(a[i], b[j], cacc[i][j]);
                }
                #pragma unroll
                for (int i=0;i<4;i++)
                    #pragma unroll
                    for (int j=0;j<4;j++)
                        macc[i][j] += (double)cacc[i][j];
            }
        }
        #pragma unroll
        for (int i=0;i<4;i++){
            const float anf = (float)Asum[bm + ty*4 + i];
            #pragma unroll
            for (int j=0;j<4;j++){
                const int ci = ct + tx*4 + j;
                const float bf  = (float)cbB[ci];
                const float s1  = anf + bf;                  // fl32(A+B)
                const float df  = (float)(2.0 * macc[i][j]); // fl32(2*dot)
                const float qd  = s1 - df;                   // fl32 combine
                if (qd < bestv[i] || (qd == bestv[i] && ci < besti[i])) {
                    bestv[i] = qd; besti[i] = ci;
                }
            }
        }
    }
    #pragma unroll
    for (int i=0;i<4;i++){ bv_s[ty*4+i][tx] = bestv[i]; bi_s[ty*4+i][tx] = besti[i]; }
    __syncthreads();
    if (tid < 64) {
        float bv = bv_s[tid][0]; int bi = bi_s[tid][0];
        #pragma unroll
        for (int x = 1; x < 16; ++x) {
            float v = bv_s[tid][x]; int ii = bi_s[tid][x];
            if (v < bv || (v == bv && ii < bi)) { bv = v; bi = ii; }
        }
        pbv[(long long)blockIdx.y*16384 + bm + tid] = bv;
        pbi[(long long)blockIdx.y*16384 + bm + tid] = bi;
    }
}

__global__ __launch_bounds__(256)
void vq_reduce_r13(const float* __restrict__ pbv, const int* __restrict__ pbi,
                   int* __restrict__ idxout)
{
    int n = blockIdx.x*256 + threadIdx.x;
    if (n >= 16384) return;
    float bv = pbv[n]; int bi = pbi[n];
    #pragma unroll
    for (int q = 1; q < 4; ++q) {
        float v = pbv[q*16384 + n]; int ii = pbi[q*16384 + n];
        if (v < bv || (v == bv && ii < bi)) { bv = v; bi = ii; }
    }
    idxout[n] = bi & 2047;
}

// ---------------- vq loss: two-stage, atomic-free ----------------------------
__global__ __launch_bounds__(256)
void vq_loss_partial_r13(const float* __restrict__ enc, const float* __restrict__ cb,
                         const int* __restrict__ idxp, double* __restrict__ part)
{
    __shared__ double red[4];
    const int row  = blockIdx.x*4 + (threadIdx.x >> 6);
    const int lane = threadIdx.x & 63;
    const int ci = idxp[row] & 2047;
    double s = 0.0;
    #pragma unroll
    for (int u = 0; u < 8; ++u) {
        int d = lane + u*64;
        double dv = (double)cb[(long long)ci*512 + d] - (double)enc[(long long)row*512 + d];
        s += dv * dv;
    }
    #pragma unroll
    for (int msk = 32; msk; msk >>= 1) s += __shfl_xor(s, msk, 64);
    if (lane == 0) red[threadIdx.x >> 6] = s;
    __syncthreads();
    if (threadIdx.x == 0)
        part[blockIdx.x] = red[0] + red[1] + red[2] + red[3];
}

// ---------------- regime softmax rows (in place) -----------------------------
__global__ __launch_bounds__(256)
void softmax_rows_r13(float* __restrict__ R)
{
    const int row = blockIdx.x;
    const int tid = threadIdx.x;
    __shared__ float  redf[256];
    __shared__ double redd[256];
    float* p = R + (long long)row * 2048;
    float mx = -1e30f;
    for (int c = tid; c < 2048; c += 256) mx = fmaxf(mx, p[c]);
    redf[tid] = mx; __syncthreads();
    for (int s2 = 128; s2; s2 >>= 1) { if (tid < s2) redf[tid] = fmaxf(redf[tid], redf[tid+s2]); __syncthreads(); }
    mx = redf[0];
    double sum = 0.0;
    for (int c = tid; c < 2048; c += 256) { float e = expf(p[c] - mx); p[c] = e; sum += e; }
    redd[tid] = sum; __syncthreads();
    for (int s2 = 128; s2; s2 >>= 1) { if (tid < s2) redd[tid] += redd[tid+s2]; __syncthreads(); }
    double tot = redd[0];
    for (int c = tid; c < 2048; c += 256) p[c] = (float)((double)p[c] / tot);
}

// ---------------- hash table per codebook entry ------------------------------
__global__ __launch_bounds__(256)
void hash_table_r13(const float* __restrict__ cb, const float* __restrict__ hw,
                    float* __restrict__ T)
{
    const int k = blockIdx.x*4 + (threadIdx.x >> 6);
    const int j = threadIdx.x & 63;
    double s = 0.0;
    for (int d = 0; d < 512; ++d)
        s += (double)cb[(long long)k*512 + d] * (double)hw[(long long)j*512 + d];
    T[(long long)k*64 + j] = (s > 0.0) ? 1.0f : 0.0f;
}

// ---------------- output writers (f32 d_out) ---------------------------------
__global__ void write_loss_r13(const double* __restrict__ part,
                               float* __restrict__ out)
{
    __shared__ double red[256];
    double s = 0.0;
    for (int i = threadIdx.x; i < 4096; i += 256) s += part[i];
    red[threadIdx.x] = s; __syncthreads();
    for (int s2 = 128; s2; s2 >>= 1) {
        if (threadIdx.x < s2) red[threadIdx.x] += red[threadIdx.x + s2];
        __syncthreads();
    }
    if (threadIdx.x == 0)
        out[O_LOSS] = (float)(1.25 * red[0] / 8388608.0);
}

__global__ __launch_bounds__(256)
void write_regime_r13(const float* __restrict__ R, const int* __restrict__ idxp,
                      float* __restrict__ out)
{
    long long i = (long long)blockIdx.x*256 + threadIdx.x;
    if (i >= 33554432LL) return;
    int n = (int)(i >> 11), c = (int)(i & 2047);
    int ci = idxp[n] & 2047;
    out[O_REG + i] = R[(long long)ci*2048 + c];
}

__global__ __launch_bounds__(256)
void write_hash_r13(const float* __restrict__ T, const int* __restrict__ idxp,
                    float* __restrict__ out)
{
    long long i = (long long)blockIdx.x*256 + threadIdx.x;
    if (i >= 1048576LL) return;
    int n = (int)(i >> 6), j = (int)(i & 63);
    int ci = idxp[n] & 2047;
    out[O_HASH + i] = T[(long long)ci*64 + j];
}

__global__ __launch_bounds__(256)
void write_idx_r13(const int* __restrict__ idxp, float* __restrict__ out)
{
    int n = blockIdx.x*256 + threadIdx.x;
    if (n >= 16384) return;
    out[O_IDX + n] = (float)(idxp[n] & 2047);
}

__global__ __launch_bounds__(256)
void write_quant_r13(const float* __restrict__ cb, const int* __restrict__ idxp,
                     float* __restrict__ out)
{
    long long i = (long long)blockIdx.x*256 + threadIdx.x;
    if (i >= 8388608LL) return;
    int n = (int)(i >> 9), d = (int)(i & 511);
    int ci = idxp[n] & 2047;
    out[O_QUANT + i] = cb[(long long)ci*512 + d];
}

// ---------------- launcher ----------------------------------------------------
extern "C" void kernel_launch(void* const* d_in, const int* in_sizes, int n_in,
                              void* d_out, int out_size, void* d_ws, size_t ws_size,
                              hipStream_t stream)
{
    (void)in_sizes; (void)n_in; (void)out_size;
    const float* market = (const float*)d_in[0];
    const float* W_in   = (const float*)d_in[1];
    const float* b_in   = (const float*)d_in[2];
    const float* pos    = (const float*)d_in[3];
    const float* c3w = (const float*)d_in[4];  const float* c3b = (const float*)d_in[5];
    const float* c5w = (const float*)d_in[6];  const float* c5b = (const float*)d_in[7];
    const float* c7w = (const float*)d_in[8];  const float* c7b = (const float*)d_in[9];
    const float* c9w = (const float*)d_in[10]; const float* c9b = (const float*)d_in[11];
    const float* msw = (const float*)d_in[12]; const float* msb = (const float*)d_in[13];
    const float* inw = (const float*)d_in[14]; const float* inb = (const float*)d_in[15];
    const float* aow = (const float*)d_in[16]; const float* aob = (const float*)d_in[17];
    const float* cb  = (const float*)d_in[18]; const float* hw  = (const float*)d_in[19];
    const float* r1w = (const float*)d_in[20]; const float* r1b = (const float*)d_in[21];
    const float* r2w = (const float*)d_in[22]; const float* r2b = (const float*)d_in[23];

    if (ws_size < (size_t)W_END * sizeof(float)) return; // insufficient scratch

    float* ws    = (float*)d_ws;
    float* xp    = ws + W_XP;
    float* convt = ws + W_CT;
    float* projp = ws + W_PROJ;
    float* wt3   = ws + W_VW;        // conv weights time-share the V region
    float* wt5   = wt3 + 512*512*3;
    float* wt7   = wt5 + 512*512*5;
    float* wt9   = wt7 + 512*512*7;
    float* Vbufp = ws + W_VW;
    float* hregp = ws + W_HREG;
    float* Tp    = ws + W_T;
    int*    idxp  = (int*)(ws + W_IDX);
    double* asump = (double*)(ws + W_ASUM);
    double* cbbp  = (double*)(ws + W_CBB);
    double* lpart = (double*)(ws + W_LPART);
    float*  pbvp  = ws + W_PBV;
    int*    pbip  = (int*)(ws + W_PBI);

    float* out = (float*)d_out;   // f32 output buffer

    float* attp  = xp;      // xp dead after conv9
    float* Kbufp = convt;   // conv_tmp dead after last ms gemm
    float* encp  = convt;   // K dead after attn
    float* Rp    = projp;   // proj dead after enc gemm

    // conv weight transposes
    conv_w_tr_r13<3><<<3072, 256, 0, stream>>>(c3w, wt3);
    conv_w_tr_r13<5><<<5120, 256, 0, stream>>>(c5w, wt5);
    conv_w_tr_r13<7><<<7168, 256, 0, stream>>>(c7w, wt7);
    conv_w_tr_r13<9><<<9216, 256, 0, stream>>>(c9w, wt9);

    const dim3 gN512(128, 4);     // 128-row x 128-col tiles, N=16384 x 512

    // xp = market @ W_in^T + b_in + pos_enc
    gemm_bt_r13<GF_BIAS|GF_POS><<<gN512, 256, 0, stream>>>(market, W_in, b_in, pos, nullptr, xp, 512, 512, 512, 512);

    // proj = sum_c relu(conv_c(xp)) @ msW_c^T (+ bias on first)
    conv_relu_r13<3><<<gN512, 256, 0, stream>>>(xp, wt3, c3b, convt);
    gemm_bt_r13<GF_BIAS><<<gN512, 256, 0, stream>>>(convt, msw + 0*512, msb, nullptr, nullptr, projp, 512, 512, 2048, 512);
    conv_relu_r13<5><<<gN512, 256, 0, stream>>>(xp, wt5, c5b, convt);
    gemm_bt_r13<GF_ACC><<<gN512, 256, 0, stream>>>(convt, msw + 1*512, nullptr, nullptr, nullptr, projp, 512, 512, 2048, 512);
    conv_relu_r13<7><<<gN512, 256, 0, stream>>>(xp, wt7, c7b, convt);
    gemm_bt_r13<GF_ACC><<<gN512, 256, 0, stream>>>(convt, msw + 2*512, nullptr, nullptr, nullptr, projp, 512, 512, 2048, 512);
    conv_relu_r13<9><<<gN512, 256, 0, stream>>>(xp, wt9, c9b, convt);
    gemm_bt_r13<GF_ACC><<<gN512, 256, 0, stream>>>(convt, msw + 3*512, nullptr, nullptr, nullptr, projp, 512, 512, 2048, 512);

    // K, V projections (Q fused into attention). V overwrites wt (dead).
    gemm_bt_r13<GF_BIAS><<<gN512, 256, 0, stream>>>(projp, inw + 512*512,  inb + 512,  nullptr, nullptr, Kbufp, 512, 512, 512, 512);
    gemm_bt_r13<GF_BIAS><<<gN512, 256, 0, stream>>>(projp, inw + 1024*512, inb + 1024, nullptr, nullptr, Vbufp, 512, 512, 512, 512);

    attn_fused_r13<<<2048, 256, 0, stream>>>(projp, inw, inb, Kbufp, Vbufp, attp);

    // enc = proj + att @ attn_out_w^T + attn_out_b   (enc overwrites K region)
    gemm_bt_r13<GF_BIAS|GF_ADD><<<gN512, 256, 0, stream>>>(attp, aow, aob, nullptr, projp, encp, 512, 512, 512, 512);

    // VQ
    row_sumsq_r13<<<4096, 256, 0, stream>>>(encp, asump);
    row_sumsq_r13<<<512,  256, 0, stream>>>(cb, cbbp);
    vq_argmin_r13<<<dim3(256, 4), 256, 0, stream>>>(encp, cb, asump, cbbp, pbvp, pbip);
    vq_reduce_r13<<<64, 256, 0, stream>>>(pbvp, pbip, idxp);
    vq_loss_partial_r13<<<4096, 256, 0, stream>>>(encp, cb, idxp, lpart);

    // regime tables per codebook entry (R overwrites proj region, now dead)
    gemm_bt_r13<GF_BIAS|GF_RELU><<<dim3(16, 2),  256, 0, stream>>>(cb, r1w, r1b, nullptr, nullptr, hregp, 512, 512, 512, 256);
    gemm_bt_r13<GF_BIAS><<<dim3(16, 16), 256, 0, stream>>>(hregp, r2w, r2b, nullptr, nullptr, Rp, 256, 256, 256, 2048);
    softmax_rows_r13<<<2048, 256, 0, stream>>>(Rp);
    hash_table_r13<<<512, 256, 0, stream>>>(cb, hw, Tp);

    // ---- output writes (f32), every chunk fully covered each call ----
    write_loss_r13<<<1, 256, 0, stream>>>(lpart, out);
    write_regime_r13<<<131072, 256, 0, stream>>>(Rp, idxp, out);
    write_hash_r13<<<4096, 256, 0, stream>>>(Tp, idxp, out);
    write_idx_r13<<<64, 256, 0, stream>>>(idxp, out);
    write_quant_r13<<<32768, 256, 0, stream>>>(cb, idxp, out);
}

// Round 14
// 4818.634 us; speedup vs baseline: 1.1555x; 1.0097x over previous
//
#include <hip/hip_runtime.h>
#include <hip/hip_bf16.h>

// ---------------- problem constants ----------------
// B=32, S=512, D=512, K=2048, NHEADS=8, NHASH=4, HLEN=16; N = B*S = 16384.
// d_out is FLOAT32.
// r14 = r13 with the B-fragment column mapping split into two 4-blocks
// (tx*4+j, 64+tx*4+j) so b128 LDS reads are 2-way (free) instead of 4-way.
// Per-output-element accumulation order unchanged -> bit-identical outputs.

#define GF_BIAS 1
#define GF_RELU 2
#define GF_ADD  4
#define GF_POS  8
#define GF_ACC  16

// output layout (f32 elements), return order — total 43,008,001
static constexpr long long O_QUANT = 0LL;        // 8388608
static constexpr long long O_LOSS  = 8388608LL;  // 1
static constexpr long long O_IDX   = 8388609LL;  // 16384
static constexpr long long O_HASH  = 8404993LL;  // 1048576
static constexpr long long O_REG   = 9453569LL;  // 33554432
static constexpr long long O_END   = 43008001LL;

// workspace layout (f32 element offsets)
static constexpr long long W_XP    = 0LL;
static constexpr long long W_CT    = 8388608LL;
static constexpr long long W_PROJ  = 16777216LL;
static constexpr long long W_VW    = 25165824LL;
static constexpr long long W_HREG  = 33554432LL;
static constexpr long long W_T     = 34078720LL;
static constexpr long long W_IDX   = 34209792LL;
static constexpr long long W_ASUM  = 34226176LL;  // 16384 f64
static constexpr long long W_CBB   = 34258944LL;  // 2048 f64
static constexpr long long W_LPART = 34263040LL;  // 4096 f64
static constexpr long long W_PBV   = 34271232LL;  // 4*16384 f32
static constexpr long long W_PBI   = 34336768LL;  // 4*16384 int
static constexpr long long W_END   = 34402304LL;

// ---------------- generic GEMM: 128x128 tile, 8x8/thread, BK=16, f32 acc -----
template<int FLAGS>
__global__ __launch_bounds__(256)
void gemm_bt_r14(const float* __restrict__ A, const float* __restrict__ Bm,
                 const float* __restrict__ bias, const float* __restrict__ pos,
                 const float* __restrict__ addsrc, float* __restrict__ C,
                 int Kdim, int lda, int ldb, int ldc)
{
    __shared__ float As[16][132];   // [k][row]
    __shared__ float Bs[16][132];   // [k][col]
    const int tid = threadIdx.x;
    const int tx = tid & 15, ty = tid >> 4;
    const int bm = blockIdx.x * 128, bn = blockIdx.y * 128;
    const int r0 = tid >> 2;            // 0..63
    const int kg = (tid & 3) << 2;      // 0,4,8,12
    const float* Arow0 = A  + (long long)(bm + r0) * lda + kg;
    const float* Arow1 = A  + (long long)(bm + r0 + 64) * lda + kg;
    const float* Brow0 = Bm + (long long)(bn + r0) * ldb + kg;
    const float* Brow1 = Bm + (long long)(bn + r0 + 64) * ldb + kg;

    float acc[8][8] = {};
    for (int k0 = 0; k0 < Kdim; k0 += 16) {
        float4 a0 = *(const float4*)(Arow0 + k0);
        float4 a1 = *(const float4*)(Arow1 + k0);
        float4 b0 = *(const float4*)(Brow0 + k0);
        float4 b1 = *(const float4*)(Brow1 + k0);
        __syncthreads();
        As[kg+0][r0]=a0.x; As[kg+1][r0]=a0.y; As[kg+2][r0]=a0.z; As[kg+3][r0]=a0.w;
        As[kg+0][r0+64]=a1.x; As[kg+1][r0+64]=a1.y; As[kg+2][r0+64]=a1.z; As[kg+3][r0+64]=a1.w;
        Bs[kg+0][r0]=b0.x; Bs[kg+1][r0]=b0.y; Bs[kg+2][r0]=b0.z; Bs[kg+3][r0]=b0.w;
        Bs[kg+0][r0+64]=b1.x; Bs[kg+1][r0+64]=b1.y; Bs[kg+2][r0+64]=b1.z; Bs[kg+3][r0+64]=b1.w;
        __syncthreads();
        #pragma unroll
        for (int kk = 0; kk < 16; ++kk) {
            float a[8], b[8];
            #pragma unroll
            for (int i=0;i<8;i++) a[i] = As[kk][ty*8+i];
            #pragma unroll
            for (int j=0;j<4;j++) b[j]   = Bs[kk][tx*4+j];
            #pragma unroll
            for (int j=0;j<4;j++) b[4+j] = Bs[kk][64+tx*4+j];
            #pragma unroll
            for (int i=0;i<8;i++)
                #pragma unroll
                for (int j=0;j<8;j++)
                    acc[i][j] = fmaf(a[i], b[j], acc[i][j]);
        }
    }
    #pragma unroll
    for (int i=0;i<8;i++){
        const int row = bm + ty*8 + i;
        #pragma unroll
        for (int j=0;j<8;j++){
            const int col = bn + ((j < 4) ? (tx*4 + j) : (64 + tx*4 + (j-4)));
            float v = acc[i][j];
            if constexpr (FLAGS & GF_BIAS) v += bias[col];
            if constexpr (FLAGS & GF_POS)  v += pos[(long long)(row & 511)*512 + col];
            if constexpr (FLAGS & GF_ADD)  v += addsrc[(long long)row*ldc + col];
            if constexpr (FLAGS & GF_ACC)  v += C[(long long)row*ldc + col];
            if constexpr (FLAGS & GF_RELU) v = fmaxf(v, 0.0f);
            C[(long long)row*ldc + col] = v;
        }
    }
}

// ---------------- conv1d as implicit GEMM: 128x128, 8x8, BK=16, f32 acc ------
template<int KT>
__global__ __launch_bounds__(256)
void conv_relu_r14(const float* __restrict__ xp, const float* __restrict__ wt,
                   const float* __restrict__ bias, float* __restrict__ outp)
{
    constexpr int PAD = KT / 2;
    constexpr int KD  = KT * 512;
    __shared__ float As[16][132];
    __shared__ float Bs[16][132];
    const int tid = threadIdx.x;
    const int tx = tid & 15, ty = tid >> 4;
    const int bm = blockIdx.x * 128, bn = blockIdx.y * 128;
    const int r0 = tid >> 2;
    const int kg = (tid & 3) << 2;
    const int n0 = bm + r0,      s0 = n0 & 511;
    const int n1 = bm + r0 + 64, s1 = n1 & 511;
    const float* Brow0 = wt + (long long)(bn + r0) * KD + kg;
    const float* Brow1 = wt + (long long)(bn + r0 + 64) * KD + kg;

    float acc[8][8] = {};
    for (int k0 = 0; k0 < KD; k0 += 16) {
        const int t  = k0 >> 9;
        const int ib = (k0 & 511) + kg;
        const int sp0 = s0 + t - PAD;
        const int sp1 = s1 + t - PAD;
        float4 a0 = make_float4(0.f,0.f,0.f,0.f);
        float4 a1 = make_float4(0.f,0.f,0.f,0.f);
        if (sp0 >= 0 && sp0 < 512)
            a0 = *(const float4*)(xp + (long long)(n0 + t - PAD)*512 + ib);
        if (sp1 >= 0 && sp1 < 512)
            a1 = *(const float4*)(xp + (long long)(n1 + t - PAD)*512 + ib);
        float4 b0 = *(const float4*)(Brow0 + k0);
        float4 b1 = *(const float4*)(Brow1 + k0);
        __syncthreads();
        As[kg+0][r0]=a0.x; As[kg+1][r0]=a0.y; As[kg+2][r0]=a0.z; As[kg+3][r0]=a0.w;
        As[kg+0][r0+64]=a1.x; As[kg+1][r0+64]=a1.y; As[kg+2][r0+64]=a1.z; As[kg+3][r0+64]=a1.w;
        Bs[kg+0][r0]=b0.x; Bs[kg+1][r0]=b0.y; Bs[kg+2][r0]=b0.z; Bs[kg+3][r0]=b0.w;
        Bs[kg+0][r0+64]=b1.x; Bs[kg+1][r0+64]=b1.y; Bs[kg+2][r0+64]=b1.z; Bs[kg+3][r0+64]=b1.w;
        __syncthreads();
        #pragma unroll
        for (int kk = 0; kk < 16; ++kk) {
            float a[8], b[8];
            #pragma unroll
            for (int i=0;i<8;i++) a[i] = As[kk][ty*8+i];
            #pragma unroll
            for (int j=0;j<4;j++) b[j]   = Bs[kk][tx*4+j];
            #pragma unroll
            for (int j=0;j<4;j++) b[4+j] = Bs[kk][64+tx*4+j];
            #pragma unroll
            for (int i=0;i<8;i++)
                #pragma unroll
                for (int j=0;j<8;j++)
                    acc[i][j] = fmaf(a[i], b[j], acc[i][j]);
        }
    }
    #pragma unroll
    for (int i=0;i<8;i++){
        const int row = bm + ty*8 + i;
        #pragma unroll
        for (int j=0;j<8;j++){
            const int col = bn + ((j < 4) ? (tx*4 + j) : (64 + tx*4 + (j-4)));
            float v = acc[i][j] + bias[col];
            outp[(long long)row*512 + col] = fmaxf(v, 0.0f);
        }
    }
}

// conv weight transpose: w[o][i][t] -> wt[o][t][i]
template<int KT>
__global__ __launch_bounds__(256)
void conv_w_tr_r14(const float* __restrict__ w, float* __restrict__ wt)
{
    long long i = (long long)blockIdx.x*256 + threadIdx.x;
    int o  = (int)(i / (512*KT));
    int rem= (int)(i % (512*KT));
    int t  = rem >> 9;
    int ii = rem & 511;
    wt[i] = w[(long long)o*512*KT + (long long)ii*KT + t];
}

// ---------------- fused attention (r13 verbatim) -----------------------------
__global__ __launch_bounds__(256)
void attn_fused_r14(const float* __restrict__ proj, const float* __restrict__ inw,
                    const float* __restrict__ inb, const float* __restrict__ Kbuf,
                    const float* __restrict__ Vbuf, float* __restrict__ att)
{
    __shared__ float Qs[64][65];
    __shared__ float Kt[64][65];
    __shared__ float Vt[64][65];
    const int tid = threadIdx.x;
    const int tx = tid & 15, ty = tid >> 4;
    const int bid = blockIdx.x;
    const int qt = bid & 7, h = (bid >> 3) & 7, b = bid >> 6;
    const int row0 = b*512 + qt*64;
    const int lr = tid >> 2, lk = (tid & 3) << 2;

    {
        double qa[4][4] = {};
        const float* Arow = proj + (long long)(row0 + lr)*512 + lk;
        const float* Brow = inw  + (long long)(h*64 + lr)*512 + lk;
        for (int k0 = 0; k0 < 512; k0 += 16) {
            float4 av = *(const float4*)(Arow + k0);
            float4 bv = *(const float4*)(Brow + k0);
            __syncthreads();
            Kt[lk+0][lr]=av.x; Kt[lk+1][lr]=av.y; Kt[lk+2][lr]=av.z; Kt[lk+3][lr]=av.w;
            Vt[lk+0][lr]=bv.x; Vt[lk+1][lr]=bv.y; Vt[lk+2][lr]=bv.z; Vt[lk+3][lr]=bv.w;
            __syncthreads();
            float c[4][4] = {};
            #pragma unroll
            for (int kk = 0; kk < 16; ++kk) {
                float a[4], bb[4];
                #pragma unroll
                for (int i=0;i<4;i++) a[i] = Kt[kk][ty*4+i];
                #pragma unroll
                for (int j=0;j<4;j++) bb[j] = Vt[kk][tx*4+j];
                #pragma unroll
                for (int i=0;i<4;i++)
                    #pragma unroll
                    for (int j=0;j<4;j++)
                        c[i][j] = fmaf(a[i], bb[j], c[i][j]);
            }
            #pragma unroll
            for (int i=0;i<4;i++)
                #pragma unroll
                for (int j=0;j<4;j++)
                    qa[i][j] += (double)c[i][j];
        }
        __syncthreads();
        #pragma unroll
        for (int i=0;i<4;i++)
            #pragma unroll
            for (int j=0;j<4;j++)
                Qs[ty*4+i][tx*4+j] = (float)((qa[i][j] + (double)inb[h*64 + tx*4+j]) * 0.125);
    }

    float m[4];
    double l[4], acc[4][4] = {};
    #pragma unroll
    for (int i=0;i<4;i++){ m[i] = -1e30f; l[i] = 0.0; }

    for (int kv = 0; kv < 512; kv += 64) {
        __syncthreads();
        #pragma unroll
        for (int u = 0; u < 16; ++u) {
            int e = u*256 + tid;
            int r = e >> 6, c = e & 63;
            Kt[r][c] = Kbuf[(long long)(b*512 + kv + r)*512 + h*64 + c];
            Vt[r][c] = Vbuf[(long long)(b*512 + kv + r)*512 + h*64 + c];
        }
        __syncthreads();
        double scd[4][4] = {};
        for (int d0 = 0; d0 < 64; d0 += 16) {
            float c[4][4] = {};
            #pragma unroll
            for (int dd = 0; dd < 16; ++dd) {
                float a[4], bb[4];
                #pragma unroll
                for (int i=0;i<4;i++) a[i] = Qs[ty*4+i][d0+dd];
                #pragma unroll
                for (int j=0;j<4;j++) bb[j] = Kt[tx*4+j][d0+dd];
                #pragma unroll
                for (int i=0;i<4;i++)
                    #pragma unroll
                    for (int j=0;j<4;j++)
                        c[i][j] = fmaf(a[i], bb[j], c[i][j]);
            }
            #pragma unroll
            for (int i=0;i<4;i++)
                #pragma unroll
                for (int j=0;j<4;j++)
                    scd[i][j] += (double)c[i][j];
        }
        float sc[4][4];
        #pragma unroll
        for (int i=0;i<4;i++)
            #pragma unroll
            for (int j=0;j<4;j++)
                sc[i][j] = (float)scd[i][j];
        #pragma unroll
        for (int i=0;i<4;i++){
            float tm = fmaxf(fmaxf(sc[i][0],sc[i][1]), fmaxf(sc[i][2],sc[i][3]));
            #pragma unroll
            for (int msk=1; msk<16; msk<<=1) tm = fmaxf(tm, __shfl_xor(tm, msk, 64));
            float mn = fmaxf(m[i], tm);
            float scale = expf(m[i] - mn);
            double rs = 0.0;
            #pragma unroll
            for (int j=0;j<4;j++){ float p = expf(sc[i][j]-mn); sc[i][j]=p; rs += (double)p; }
            #pragma unroll
            for (int msk=1; msk<16; msk<<=1) rs += __shfl_xor(rs, msk, 64);
            l[i] = l[i]*(double)scale + rs;
            m[i] = mn;
            #pragma unroll
            for (int j=0;j<4;j++) acc[i][j] *= (double)scale;
        }
        __syncthreads();
        #pragma unroll
        for (int i=0;i<4;i++)
            #pragma unroll
            for (int j=0;j<4;j++)
                Kt[ty*4+i][tx*4+j] = sc[i][j];
        __syncthreads();
        for (int d0 = 0; d0 < 64; d0 += 16) {
            float c[4][4] = {};
            #pragma unroll
            for (int dd = 0; dd < 16; ++dd) {
                float p[4], v[4];
                #pragma unroll
                for (int i=0;i<4;i++) p[i] = Kt[ty*4+i][d0+dd];
                #pragma unroll
                for (int j=0;j<4;j++) v[j] = Vt[d0+dd][tx*4+j];
                #pragma unroll
                for (int i=0;i<4;i++)
                    #pragma unroll
                    for (int j=0;j<4;j++)
                        c[i][j] = fmaf(p[i], v[j], c[i][j]);
            }
            #pragma unroll
            for (int i=0;i<4;i++)
                #pragma unroll
                for (int j=0;j<4;j++)
                    acc[i][j] += (double)c[i][j];
        }
    }
    #pragma unroll
    for (int i=0;i<4;i++)
        #pragma unroll
        for (int j=0;j<4;j++)
            att[(long long)(row0 + ty*4+i)*512 + h*64 + tx*4+j] = (float)(acc[i][j] / l[i]);
}

// ---------------- row sum of squares (f64), 512-col rows ---------------------
__global__ __launch_bounds__(256)
void row_sumsq_r14(const float* __restrict__ X, double* __restrict__ outp)
{
    const int row  = blockIdx.x*4 + (threadIdx.x >> 6);
    const int lane = threadIdx.x & 63;
    double s = 0.0;
    #pragma unroll
    for (int u = 0; u < 8; ++u) {
        float v = X[(long long)row*512 + lane + u*64];
        s += (double)v * (double)v;
    }
    #pragma unroll
    for (int msk = 32; msk; msk >>= 1) s += __shfl_xor(s, msk, 64);
    if (lane == 0) outp[row] = s;
}

// ---------------- VQ argmin (r13 verbatim): f64 dots, absorbed compare -------
__global__ __launch_bounds__(256)
void vq_argmin_r14(const float* __restrict__ enc, const float* __restrict__ cb,
                   const double* __restrict__ Asum, const double* __restrict__ cbB,
                   float* __restrict__ pbv, int* __restrict__ pbi)
{
    __shared__ float Es[32][68];
    __shared__ float Cs[32][68];
    __shared__ float bv_s[64][17];
    __shared__ int   bi_s[64][17];
    const int tid = threadIdx.x;
    const int tx = tid & 15, ty = tid >> 4;
    const int lr = tid >> 2, lk = (tid & 3) << 2;
    const int bm  = blockIdx.x * 64;
    const int ct0 = blockIdx.y * 512;
    float bestv[4]; int besti[4];
    #pragma unroll
    for (int i=0;i<4;i++){ bestv[i] = 3.0e38f; besti[i] = 2048; }

    for (int ct = ct0; ct < ct0 + 512; ct += 64) {
        double macc[4][4] = {};
        for (int k0 = 0; k0 < 512; k0 += 32) {
            float4 av0 = *(const float4*)(enc + (long long)(bm + lr)*512 + k0 + lk);
            float4 av1 = *(const float4*)(enc + (long long)(bm + lr)*512 + k0 + 16 + lk);
            float4 bv0 = *(const float4*)(cb  + (long long)(ct + lr)*512 + k0 + lk);
            float4 bv1 = *(const float4*)(cb  + (long long)(ct + lr)*512 + k0 + 16 + lk);
            __syncthreads();
            Es[lk+0][lr]=av0.x; Es[lk+1][lr]=av0.y; Es[lk+2][lr]=av0.z; Es[lk+3][lr]=av0.w;
            Es[lk+16][lr]=av1.x; Es[lk+17][lr]=av1.y; Es[lk+18][lr]=av1.z; Es[lk+19][lr]=av1.w;
            Cs[lk+0][lr]=bv0.x; Cs[lk+1][lr]=bv0.y; Cs[lk+2][lr]=bv0.z; Cs[lk+3][lr]=bv0.w;
            Cs[lk+16][lr]=bv1.x; Cs[lk+17][lr]=bv1.y; Cs[lk+18][lr]=bv1.z; Cs[lk+19][lr]=bv1.w;
            __syncthreads();
            #pragma unroll
            for (int half = 0; half < 2; ++half) {
                float cacc[4][4] = {};
                #pragma unroll
                for (int kk2 = 0; kk2 < 16; ++kk2) {
                    const int kk = half*16 + kk2;
                    float a[4], b[4];
                    #pragma unroll
                    for (int i=0;i<4;i++) a[i] = Es[kk][ty*4+i];
                    #pragma unroll
                    for (int j=0;j<4;j++) b[j] = Cs[kk][tx*4+j];
                    #pragma unroll
                    for (int i=0;i<4;i++)
                        #pragma unroll
                        for (int j=0;j<4;j++)
                            cacc[i][j] = fmaf(a[i], b[j], cacc[i][j]);
                }
                #pragma unroll
                for (int i=0;i<4;i++)
                    #pragma unroll
                    for (int j=0;j<4;j++)
                        macc[i][j] += (double)cacc[i][j];
            }
        }
        #pragma unroll
        for (int i=0;i<4;i++){
            const float anf = (float)Asum[bm + ty*4 + i];
            #pragma unroll
            for (int j=0;j<4;j++){
                const int ci = ct + tx*4 + j;
                const float bf  = (float)cbB[ci];
                const float s1  = anf + bf;
                const float df  = (float)(2.0 * macc[i][j]);
                const float qd  = s1 - df;
                if (qd < bestv[i] || (qd == bestv[i] && ci < besti[i])) {
                    bestv[i] = qd; besti[i] = ci;
                }
            }
        }
    }
    #pragma unroll
    for (int i=0;i<4;i++){ bv_s[ty*4+i][tx] = bestv[i]; bi_s[ty*4+i][tx] = besti[i]; }
    __syncthreads();
    if (tid < 64) {
        float bv = bv_s[tid][0]; int bi = bi_s[tid][0];
        #pragma unroll
        for (int x = 1; x < 16; ++x) {
            float v = bv_s[tid][x]; int ii = bi_s[tid][x];
            if (v < bv || (v == bv && ii < bi)) { bv = v; bi = ii; }
        }
        pbv[(long long)blockIdx.y*16384 + bm + tid] = bv;
        pbi[(long long)blockIdx.y*16384 + bm + tid] = bi;
    }
}

__global__ __launch_bounds__(256)
void vq_reduce_r14(const float* __restrict__ pbv, const int* __restrict__ pbi,
                   int* __restrict__ idxout)
{
    int n = blockIdx.x*256 + threadIdx.x;
    if (n >= 16384) return;
    float bv = pbv[n]; int bi = pbi[n];
    #pragma unroll
    for (int q = 1; q < 4; ++q) {
        float v = pbv[q*16384 + n]; int ii = pbi[q*16384 + n];
        if (v < bv || (v == bv && ii < bi)) { bv = v; bi = ii; }
    }
    idxout[n] = bi & 2047;
}

// ---------------- vq loss: two-stage, atomic-free ----------------------------
__global__ __launch_bounds__(256)
void vq_loss_partial_r14(const float* __restrict__ enc, const float* __restrict__ cb,
                         const int* __restrict__ idxp, double* __restrict__ part)
{
    __shared__ double red[4];
    const int row  = blockIdx.x*4 + (threadIdx.x >> 6);
    const int lane = threadIdx.x & 63;
    const int ci = idxp[row] & 2047;
    double s = 0.0;
    #pragma unroll
    for (int u = 0; u < 8; ++u) {
        int d = lane + u*64;
        double dv = (double)cb[(long long)ci*512 + d] - (double)enc[(long long)row*512 + d];
        s += dv * dv;
    }
    #pragma unroll
    for (int msk = 32; msk; msk >>= 1) s += __shfl_xor(s, msk, 64);
    if (lane == 0) red[threadIdx.x >> 6] = s;
    __syncthreads();
    if (threadIdx.x == 0)
        part[blockIdx.x] = red[0] + red[1] + red[2] + red[3];
}

// ---------------- regime softmax rows (in place) -----------------------------
__global__ __launch_bounds__(256)
void softmax_rows_r14(float* __restrict__ R)
{
    const int row = blockIdx.x;
    const int tid = threadIdx.x;
    __shared__ float  redf[256];
    __shared__ double redd[256];
    float* p = R + (long long)row * 2048;
    float mx = -1e30f;
    for (int c = tid; c < 2048; c += 256) mx = fmaxf(mx, p[c]);
    redf[tid] = mx; __syncthreads();
    for (int s2 = 128; s2; s2 >>= 1) { if (tid < s2) redf[tid] = fmaxf(redf[tid], redf[tid+s2]); __syncthreads(); }
    mx = redf[0];
    double sum = 0.0;
    for (int c = tid; c < 2048; c += 256) { float e = expf(p[c] - mx); p[c] = e; sum += e; }
    redd[tid] = sum; __syncthreads();
    for (int s2 = 128; s2; s2 >>= 1) { if (tid < s2) redd[tid] += redd[tid+s2]; __syncthreads(); }
    double tot = redd[0];
    for (int c = tid; c < 2048; c += 256) p[c] = (float)((double)p[c] / tot);
}

// ---------------- hash table per codebook entry ------------------------------
__global__ __launch_bounds__(256)
void hash_table_r14(const float* __restrict__ cb, const float* __restrict__ hw,
                    float* __restrict__ T)
{
    const int k = blockIdx.x*4 + (threadIdx.x >> 6);
    const int j = threadIdx.x & 63;
    double s = 0.0;
    for (int d = 0; d < 512; ++d)
        s += (double)cb[(long long)k*512 + d] * (double)hw[(long long)j*512 + d];
    T[(long long)k*64 + j] = (s > 0.0) ? 1.0f : 0.0f;
}

// ---------------- output writers (f32 d_out) ---------------------------------
__global__ void write_loss_r14(const double* __restrict__ part,
                               float* __restrict__ out)
{
    __shared__ double red[256];
    double s = 0.0;
    for (int i = threadIdx.x; i < 4096; i += 256) s += part[i];
    red[threadIdx.x] = s; __syncthreads();
    for (int s2 = 128; s2; s2 >>= 1) {
        if (threadIdx.x < s2) red[threadIdx.x] += red[threadIdx.x + s2];
        __syncthreads();
    }
    if (threadIdx.x == 0)
        out[O_LOSS] = (float)(1.25 * red[0] / 8388608.0);
}

__global__ __launch_bounds__(256)
void write_regime_r14(const float* __restrict__ R, const int* __restrict__ idxp,
                      float* __restrict__ out)
{
    long long i = (long long)blockIdx.x*256 + threadIdx.x;
    if (i >= 33554432LL) return;
    int n = (int)(i >> 11), c = (int)(i & 2047);
    int ci = idxp[n] & 2047;
    out[O_REG + i] = R[(long long)ci*2048 + c];
}

__global__ __launch_bounds__(256)
void write_hash_r14(const float* __restrict__ T, const int* __restrict__ idxp,
                    float* __restrict__ out)
{
    long long i = (long long)blockIdx.x*256 + threadIdx.x;
    if (i >= 1048576LL) return;
    int n = (int)(i >> 6), j = (int)(i & 63);
    int ci = idxp[n] & 2047;
    out[O_HASH + i] = T[(long long)ci*64 + j];
}

__global__ __launch_bounds__(256)
void write_idx_r14(const int* __restrict__ idxp, float* __restrict__ out)
{
    int n = blockIdx.x*256 + threadIdx.x;
    if (n >= 16384) return;
    out[O_IDX + n] = (float)(idxp[n] & 2047);
}

__global__ __launch_bounds__(256)
void write_quant_r14(const float* __restrict__ cb, const int* __restrict__ idxp,
                     float* __restrict__ out)
{
    long long i = (long long)blockIdx.x*256 + threadIdx.x;
    if (i >= 8388608LL) return;
    int n = (int)(i >> 9), d = (int)(i & 511);
    int ci = idxp[n] & 2047;
    out[O_QUANT + i] = cb[(long long)ci*512 + d];
}

// ---------------- launcher ----------------------------------------------------
extern "C" void kernel_launch(void* const* d_in, const int* in_sizes, int n_in,
                              void* d_out, int out_size, void* d_ws, size_t ws_size,
                              hipStream_t stream)
{
    (void)in_sizes; (void)n_in; (void)out_size;
    const float* market = (const float*)d_in[0];
    const float* W_in   = (const float*)d_in[1];
    const float* b_in   = (const float*)d_in[2];
    const float* pos    = (const float*)d_in[3];
    const float* c3w = (const float*)d_in[4];  const float* c3b = (const float*)d_in[5];
    const float* c5w = (const float*)d_in[6];  const float* c5b = (const float*)d_in[7];
    const float* c7w = (const float*)d_in[8];  const float* c7b = (const float*)d_in[9];
    const float* c9w = (const float*)d_in[10]; const float* c9b = (const float*)d_in[11];
    const float* msw = (const float*)d_in[12]; const float* msb = (const float*)d_in[13];
    const float* inw = (const float*)d_in[14]; const float* inb = (const float*)d_in[15];
    const float* aow = (const float*)d_in[16]; const float* aob = (const float*)d_in[17];
    const float* cb  = (const float*)d_in[18]; const float* hw  = (const float*)d_in[19];
    const float* r1w = (const float*)d_in[20]; const float* r1b = (const float*)d_in[21];
    const float* r2w = (const float*)d_in[22]; const float* r2b = (const float*)d_in[23];

    if (ws_size < (size_t)W_END * sizeof(float)) return; // insufficient scratch

    float* ws    = (float*)d_ws;
    float* xp    = ws + W_XP;
    float* convt = ws + W_CT;
    float* projp = ws + W_PROJ;
    float* wt3   = ws + W_VW;        // conv weights time-share the V region
    float* wt5   = wt3 + 512*512*3;
    float* wt7   = wt5 + 512*512*5;
    float* wt9   = wt7 + 512*512*7;
    float* Vbufp = ws + W_VW;
    float* hregp = ws + W_HREG;
    float* Tp    = ws + W_T;
    int*    idxp  = (int*)(ws + W_IDX);
    double* asump = (double*)(ws + W_ASUM);
    double* cbbp  = (double*)(ws + W_CBB);
    double* lpart = (double*)(ws + W_LPART);
    float*  pbvp  = ws + W_PBV;
    int*    pbip  = (int*)(ws + W_PBI);

    float* out = (float*)d_out;   // f32 output buffer

    float* attp  = xp;      // xp dead after conv9
    float* Kbufp = convt;   // conv_tmp dead after last ms gemm
    float* encp  = convt;   // K dead after attn
    float* Rp    = projp;   // proj dead after enc gemm

    // conv weight transposes
    conv_w_tr_r14<3><<<3072, 256, 0, stream>>>(c3w, wt3);
    conv_w_tr_r14<5><<<5120, 256, 0, stream>>>(c5w, wt5);
    conv_w_tr_r14<7><<<7168, 256, 0, stream>>>(c7w, wt7);
    conv_w_tr_r14<9><<<9216, 256, 0, stream>>>(c9w, wt9);

    const dim3 gN512(128, 4);     // 128-row x 128-col tiles, N=16384 x 512

    // xp = market @ W_in^T + b_in + pos_enc
    gemm_bt_r14<GF_BIAS|GF_POS><<<gN512, 256, 0, stream>>>(market, W_in, b_in, pos, nullptr, xp, 512, 512, 512, 512);

    // proj = sum_c relu(conv_c(xp)) @ msW_c^T (+ bias on first)
    conv_relu_r14<3><<<gN512, 256, 0, stream>>>(xp, wt3, c3b, convt);
    gemm_bt_r14<GF_BIAS><<<gN512, 256, 0, stream>>>(convt, msw + 0*512, msb, nullptr, nullptr, projp, 512, 512, 2048, 512);
    conv_relu_r14<5><<<gN512, 256, 0, stream>>>(xp, wt5, c5b, convt);
    gemm_bt_r14<GF_ACC><<<gN512, 256, 0, stream>>>(convt, msw + 1*512, nullptr, nullptr, nullptr, projp, 512, 512, 2048, 512);
    conv_relu_r14<7><<<gN512, 256, 0, stream>>>(xp, wt7, c7b, convt);
    gemm_bt_r14<GF_ACC><<<gN512, 256, 0, stream>>>(convt, msw + 2*512, nullptr, nullptr, nullptr, projp, 512, 512, 2048, 512);
    conv_relu_r14<9><<<gN512, 256, 0, stream>>>(xp, wt9, c9b, convt);
    gemm_bt_r14<GF_ACC><<<gN512, 256, 0, stream>>>(convt, msw + 3*512, nullptr, nullptr, nullptr, projp, 512, 512, 2048, 512);

    // K, V projections (Q fused into attention). V overwrites wt (dead).
    gemm_bt_r14<GF_BIAS><<<gN512, 256, 0, stream>>>(projp, inw + 512*512,  inb + 512,  nullptr, nullptr, Kbufp, 512, 512, 512, 512);
    gemm_bt_r14<GF_BIAS><<<gN512, 256, 0, stream>>>(projp, inw + 1024*512, inb + 1024, nullptr, nullptr, Vbufp, 512, 512, 512, 512);

    attn_fused_r14<<<2048, 256, 0, stream>>>(projp, inw, inb, Kbufp, Vbufp, attp);

    // enc = proj + att @ attn_out_w^T + attn_out_b   (enc overwrites K region)
    gemm_bt_r14<GF_BIAS|GF_ADD><<<gN512, 256, 0, stream>>>(attp, aow, aob, nullptr, projp, encp, 512, 512, 512, 512);

    // VQ
    row_sumsq_r14<<<4096, 256, 0, stream>>>(encp, asump);
    row_sumsq_r14<<<512,  256, 0, stream>>>(cb, cbbp);
    vq_argmin_r14<<<dim3(256, 4), 256, 0, stream>>>(encp, cb, asump, cbbp, pbvp, pbip);
    vq_reduce_r14<<<64, 256, 0, stream>>>(pbvp, pbip, idxp);
    vq_loss_partial_r14<<<4096, 256, 0, stream>>>(encp, cb, idxp, lpart);

    // regime tables per codebook entry (R overwrites proj region, now dead)
    gemm_bt_r14<GF_BIAS|GF_RELU><<<dim3(16, 2),  256, 0, stream>>>(cb, r1w, r1b, nullptr, nullptr, hregp, 512, 512, 512, 256);
    gemm_bt_r14<GF_BIAS><<<dim3(16, 16), 256, 0, stream>>>(hregp, r2w, r2b, nullptr, nullptr, Rp, 256, 256, 256, 2048);
    softmax_rows_r14<<<2048, 256, 0, stream>>>(Rp);
    hash_table_r14<<<512, 256, 0, stream>>>(cb, hw, Tp);

    // ---- output writes (f32), every chunk fully covered each call ----
    write_loss_r14<<<1, 256, 0, stream>>>(lpart, out);
    write_regime_r14<<<131072, 256, 0, stream>>>(Rp, idxp, out);
    write_hash_r14<<<4096, 256, 0, stream>>>(Tp, idxp, out);
    write_idx_r14<<<64, 256, 0, stream>>>(idxp, out);
    write_quant_r14<<<32768, 256, 0, stream>>>(cb, idxp, out);
}

// Round 15
// 2886.271 us; speedup vs baseline: 1.9290x; 1.6695x over previous
//
#include <hip/hip_runtime.h>
#include <hip/hip_bf16.h>

// ---------------- problem constants ----------------
// B=32, S=512, D=512, K=2048; N = B*S = 16384. d_out is FLOAT32.
// r15: the four convs use f16x3 split MFMA (hi/lo f16, 3x mfma_f32_16x16x32_f16,
// error class == f32 reorder noise, proven safe in r13/r14). xp and conv
// weights are pre-split into packed (hi,lo) u32 — in-place / same footprint.
// GEMMs, attention, VQ argmin (f64 dots + absorbed compare): r14 verbatim.

#define GF_BIAS 1
#define GF_RELU 2
#define GF_ADD  4
#define GF_POS  8
#define GF_ACC  16

typedef _Float16 f16x8 __attribute__((ext_vector_type(8)));
typedef float    f32x4 __attribute__((ext_vector_type(4)));

// output layout (f32 elements), return order — total 43,008,001
static constexpr long long O_QUANT = 0LL;
static constexpr long long O_LOSS  = 8388608LL;
static constexpr long long O_IDX   = 8388609LL;
static constexpr long long O_HASH  = 8404993LL;
static constexpr long long O_REG   = 9453569LL;
static constexpr long long O_END   = 43008001LL;

// workspace layout (f32 element offsets) — unchanged from r14
static constexpr long long W_XP    = 0LL;         // xp f32 -> packed hi/lo -> attp
static constexpr long long W_CT    = 8388608LL;
static constexpr long long W_PROJ  = 16777216LL;
static constexpr long long W_VW    = 25165824LL;  // packed conv weights -> V
static constexpr long long W_HREG  = 33554432LL;
static constexpr long long W_T     = 34078720LL;
static constexpr long long W_IDX   = 34209792LL;
static constexpr long long W_ASUM  = 34226176LL;
static constexpr long long W_CBB   = 34258944LL;
static constexpr long long W_LPART = 34263040LL;
static constexpr long long W_PBV   = 34271232LL;
static constexpr long long W_PBI   = 34336768LL;
static constexpr long long W_END   = 34402304LL;

__device__ __forceinline__ unsigned int pack_hl(float x)
{
    _Float16 h = (_Float16)x;
    float hf = (float)h;
    _Float16 l = (_Float16)(x - hf);
    unsigned short hb = __builtin_bit_cast(unsigned short, h);
    unsigned short lb = __builtin_bit_cast(unsigned short, l);
    return (unsigned int)hb | ((unsigned int)lb << 16);
}

// ---------------- split xp in place: f32 -> packed (hi,lo) -------------------
__global__ __launch_bounds__(256)
void split_xp_r15(float* __restrict__ xp)
{
    long long i = (long long)blockIdx.x*256 + threadIdx.x;  // 8388608
    float x = xp[i];
    ((unsigned int*)xp)[i] = pack_hl(x);
}

// conv weight transpose+split: w[o][i][t] f32 -> packed [o][t][i]
template<int KT>
__global__ __launch_bounds__(256)
void conv_w_tr_r15(const float* __restrict__ w, unsigned int* __restrict__ wt)
{
    long long i = (long long)blockIdx.x*256 + threadIdx.x;
    int o  = (int)(i / (512*KT));
    int rem= (int)(i % (512*KT));
    int t  = rem >> 9;
    int ii = rem & 511;
    wt[i] = pack_hl(w[(long long)o*512*KT + (long long)ii*KT + t]);
}

// ---------------- conv via f16x3 MFMA: 128x128 tile, 4 waves (2x2) -----------
template<int KT>
__global__ __launch_bounds__(256)
void conv_mfma_r15(const unsigned int* __restrict__ xphl,
                   const unsigned int* __restrict__ wthl,
                   const float* __restrict__ bias, float* __restrict__ outp)
{
    constexpr int PAD = KT / 2;
    __shared__ unsigned short Ah[128][56];
    __shared__ unsigned short Al[128][56];
    __shared__ unsigned short Bh[128][56];
    __shared__ unsigned short Bl[128][56];
    const int tid  = threadIdx.x;
    const int lane = tid & 63;
    const int wave = tid >> 6;
    const int wm = (wave >> 1) * 64, wn = (wave & 1) * 64;
    const int bm = blockIdx.x * 128, bn = blockIdx.y * 128;
    const int l15 = lane & 15;
    const int lk8 = (lane >> 4) * 8;     // f16 units
    const int rbase = (lane >> 4) * 4;

    const int cg   = tid & 7;            // 4-elem chunk within 32-col slice
    const int rw0  = tid >> 3;           // staging row base (0..31), +32 per q

    f32x4 acc[4][4];
    #pragma unroll
    for (int i=0;i<4;i++)
        #pragma unroll
        for (int j=0;j<4;j++)
            acc[i][j] = (f32x4){0.f,0.f,0.f,0.f};

    for (int t = 0; t < KT; ++t) {
        for (int i0 = 0; i0 < 512; i0 += 32) {
            // global loads: A (xp rows, shifted by tap) and B (weights)
            uint4 va[4], vb[4];
            #pragma unroll
            for (int q = 0; q < 4; ++q) {
                const int row = rw0 + q*32;
                const int s   = (bm + row) & 511;
                const int sp  = s + t - PAD;
                if (sp >= 0 && sp < 512)
                    va[q] = *(const uint4*)(xphl + (long long)(bm + row + t - PAD)*512 + i0 + cg*4);
                else
                    va[q] = make_uint4(0u,0u,0u,0u);
                vb[q] = *(const uint4*)(wthl + (long long)(bn + row)*(KT*512) + t*512 + i0 + cg*4);
            }
            __syncthreads();
            #pragma unroll
            for (int q = 0; q < 4; ++q) {
                const int row = rw0 + q*32;
                ushort4 ahi = make_ushort4((unsigned short)(va[q].x & 0xffff),
                                           (unsigned short)(va[q].y & 0xffff),
                                           (unsigned short)(va[q].z & 0xffff),
                                           (unsigned short)(va[q].w & 0xffff));
                ushort4 alo = make_ushort4((unsigned short)(va[q].x >> 16),
                                           (unsigned short)(va[q].y >> 16),
                                           (unsigned short)(va[q].z >> 16),
                                           (unsigned short)(va[q].w >> 16));
                ushort4 bhi = make_ushort4((unsigned short)(vb[q].x & 0xffff),
                                           (unsigned short)(vb[q].y & 0xffff),
                                           (unsigned short)(vb[q].z & 0xffff),
                                           (unsigned short)(vb[q].w & 0xffff));
                ushort4 blo = make_ushort4((unsigned short)(vb[q].x >> 16),
                                           (unsigned short)(vb[q].y >> 16),
                                           (unsigned short)(vb[q].z >> 16),
                                           (unsigned short)(vb[q].w >> 16));
                *(ushort4*)(&Ah[row][cg*4]) = ahi;
                *(ushort4*)(&Al[row][cg*4]) = alo;
                *(ushort4*)(&Bh[row][cg*4]) = bhi;
                *(ushort4*)(&Bl[row][cg*4]) = blo;
            }
            __syncthreads();
            // fragments + 3-pass MFMA
            f16x8 ah[4], al[4], bh[4], bl[4];
            #pragma unroll
            for (int mi = 0; mi < 4; ++mi) {
                ah[mi] = *(const f16x8*)(&Ah[wm + mi*16 + l15][lk8]);
                al[mi] = *(const f16x8*)(&Al[wm + mi*16 + l15][lk8]);
            }
            #pragma unroll
            for (int nj = 0; nj < 4; ++nj) {
                bh[nj] = *(const f16x8*)(&Bh[wn + nj*16 + l15][lk8]);
                bl[nj] = *(const f16x8*)(&Bl[wn + nj*16 + l15][lk8]);
            }
            #pragma unroll
            for (int mi = 0; mi < 4; ++mi)
                #pragma unroll
                for (int nj = 0; nj < 4; ++nj) {
                    acc[mi][nj] = __builtin_amdgcn_mfma_f32_16x16x32_f16(ah[mi], bh[nj], acc[mi][nj], 0, 0, 0);
                    acc[mi][nj] = __builtin_amdgcn_mfma_f32_16x16x32_f16(ah[mi], bl[nj], acc[mi][nj], 0, 0, 0);
                    acc[mi][nj] = __builtin_amdgcn_mfma_f32_16x16x32_f16(al[mi], bh[nj], acc[mi][nj], 0, 0, 0);
                }
        }
    }
    // epilogue: D row=(lane>>4)*4+r, col=lane&15
    #pragma unroll
    for (int mi = 0; mi < 4; ++mi) {
        #pragma unroll
        for (int nj = 0; nj < 4; ++nj) {
            const int col = bn + wn + nj*16 + l15;
            const float bcol = bias[col];
            #pragma unroll
            for (int r = 0; r < 4; ++r) {
                const int row = bm + wm + mi*16 + rbase + r;
                float v = acc[mi][nj][r] + bcol;
                outp[(long long)row*512 + col] = fmaxf(v, 0.0f);
            }
        }
    }
}

// ---------------- generic GEMM (r14 verbatim): 128x128, 8x8, f32 acc ---------
template<int FLAGS>
__global__ __launch_bounds__(256)
void gemm_bt_r15(const float* __restrict__ A, const float* __restrict__ Bm,
                 const float* __restrict__ bias, const float* __restrict__ pos,
                 const float* __restrict__ addsrc, float* __restrict__ C,
                 int Kdim, int lda, int ldb, int ldc)
{
    __shared__ float As[16][132];
    __shared__ float Bs[16][132];
    const int tid = threadIdx.x;
    const int tx = tid & 15, ty = tid >> 4;
    const int bm = blockIdx.x * 128, bn = blockIdx.y * 128;
    const int r0 = tid >> 2;
    const int kg = (tid & 3) << 2;
    const float* Arow0 = A  + (long long)(bm + r0) * lda + kg;
    const float* Arow1 = A  + (long long)(bm + r0 + 64) * lda + kg;
    const float* Brow0 = Bm + (long long)(bn + r0) * ldb + kg;
    const float* Brow1 = Bm + (long long)(bn + r0 + 64) * ldb + kg;

    float acc[8][8] = {};
    for (int k0 = 0; k0 < Kdim; k0 += 16) {
        float4 a0 = *(const float4*)(Arow0 + k0);
        float4 a1 = *(const float4*)(Arow1 + k0);
        float4 b0 = *(const float4*)(Brow0 + k0);
        float4 b1 = *(const float4*)(Brow1 + k0);
        __syncthreads();
        As[kg+0][r0]=a0.x; As[kg+1][r0]=a0.y; As[kg+2][r0]=a0.z; As[kg+3][r0]=a0.w;
        As[kg+0][r0+64]=a1.x; As[kg+1][r0+64]=a1.y; As[kg+2][r0+64]=a1.z; As[kg+3][r0+64]=a1.w;
        Bs[kg+0][r0]=b0.x; Bs[kg+1][r0]=b0.y; Bs[kg+2][r0]=b0.z; Bs[kg+3][r0]=b0.w;
        Bs[kg+0][r0+64]=b1.x; Bs[kg+1][r0+64]=b1.y; Bs[kg+2][r0+64]=b1.z; Bs[kg+3][r0+64]=b1.w;
        __syncthreads();
        #pragma unroll
        for (int kk = 0; kk < 16; ++kk) {
            float a[8], b[8];
            #pragma unroll
            for (int i=0;i<8;i++) a[i] = As[kk][ty*8+i];
            #pragma unroll
            for (int j=0;j<4;j++) b[j]   = Bs[kk][tx*4+j];
            #pragma unroll
            for (int j=0;j<4;j++) b[4+j] = Bs[kk][64+tx*4+j];
            #pragma unroll
            for (int i=0;i<8;i++)
                #pragma unroll
                for (int j=0;j<8;j++)
                    acc[i][j] = fmaf(a[i], b[j], acc[i][j]);
        }
    }
    #pragma unroll
    for (int i=0;i<8;i++){
        const int row = bm + ty*8 + i;
        #pragma unroll
        for (int j=0;j<8;j++){
            const int col = bn + ((j < 4) ? (tx*4 + j) : (64 + tx*4 + (j-4)));
            float v = acc[i][j];
            if constexpr (FLAGS & GF_BIAS) v += bias[col];
            if constexpr (FLAGS & GF_POS)  v += pos[(long long)(row & 511)*512 + col];
            if constexpr (FLAGS & GF_ADD)  v += addsrc[(long long)row*ldc + col];
            if constexpr (FLAGS & GF_ACC)  v += C[(long long)row*ldc + col];
            if constexpr (FLAGS & GF_RELU) v = fmaxf(v, 0.0f);
            C[(long long)row*ldc + col] = v;
        }
    }
}

// ---------------- fused attention (r14 verbatim) -----------------------------
__global__ __launch_bounds__(256)
void attn_fused_r15(const float* __restrict__ proj, const float* __restrict__ inw,
                    const float* __restrict__ inb, const float* __restrict__ Kbuf,
                    const float* __restrict__ Vbuf, float* __restrict__ att)
{
    __shared__ float Qs[64][65];
    __shared__ float Kt[64][65];
    __shared__ float Vt[64][65];
    const int tid = threadIdx.x;
    const int tx = tid & 15, ty = tid >> 4;
    const int bid = blockIdx.x;
    const int qt = bid & 7, h = (bid >> 3) & 7, b = bid >> 6;
    const int row0 = b*512 + qt*64;
    const int lr = tid >> 2, lk = (tid & 3) << 2;

    {
        double qa[4][4] = {};
        const float* Arow = proj + (long long)(row0 + lr)*512 + lk;
        const float* Brow = inw  + (long long)(h*64 + lr)*512 + lk;
        for (int k0 = 0; k0 < 512; k0 += 16) {
            float4 av = *(const float4*)(Arow + k0);
            float4 bv = *(const float4*)(Brow + k0);
            __syncthreads();
            Kt[lk+0][lr]=av.x; Kt[lk+1][lr]=av.y; Kt[lk+2][lr]=av.z; Kt[lk+3][lr]=av.w;
            Vt[lk+0][lr]=bv.x; Vt[lk+1][lr]=bv.y; Vt[lk+2][lr]=bv.z; Vt[lk+3][lr]=bv.w;
            __syncthreads();
            float c[4][4] = {};
            #pragma unroll
            for (int kk = 0; kk < 16; ++kk) {
                float a[4], bb[4];
                #pragma unroll
                for (int i=0;i<4;i++) a[i] = Kt[kk][ty*4+i];
                #pragma unroll
                for (int j=0;j<4;j++) bb[j] = Vt[kk][tx*4+j];
                #pragma unroll
                for (int i=0;i<4;i++)
                    #pragma unroll
                    for (int j=0;j<4;j++)
                        c[i][j] = fmaf(a[i], bb[j], c[i][j]);
            }
            #pragma unroll
            for (int i=0;i<4;i++)
                #pragma unroll
                for (int j=0;j<4;j++)
                    qa[i][j] += (double)c[i][j];
        }
        __syncthreads();
        #pragma unroll
        for (int i=0;i<4;i++)
            #pragma unroll
            for (int j=0;j<4;j++)
                Qs[ty*4+i][tx*4+j] = (float)((qa[i][j] + (double)inb[h*64 + tx*4+j]) * 0.125);
    }

    float m[4];
    double l[4], acc[4][4] = {};
    #pragma unroll
    for (int i=0;i<4;i++){ m[i] = -1e30f; l[i] = 0.0; }

    for (int kv = 0; kv < 512; kv += 64) {
        __syncthreads();
        #pragma unroll
        for (int u = 0; u < 16; ++u) {
            int e = u*256 + tid;
            int r = e >> 6, c = e & 63;
            Kt[r][c] = Kbuf[(long long)(b*512 + kv + r)*512 + h*64 + c];
            Vt[r][c] = Vbuf[(long long)(b*512 + kv + r)*512 + h*64 + c];
        }
        __syncthreads();
        double scd[4][4] = {};
        for (int d0 = 0; d0 < 64; d0 += 16) {
            float c[4][4] = {};
            #pragma unroll
            for (int dd = 0; dd < 16; ++dd) {
                float a[4], bb[4];
                #pragma unroll
                for (int i=0;i<4;i++) a[i] = Qs[ty*4+i][d0+dd];
                #pragma unroll
                for (int j=0;j<4;j++) bb[j] = Kt[tx*4+j][d0+dd];
                #pragma unroll
                for (int i=0;i<4;i++)
                    #pragma unroll
                    for (int j=0;j<4;j++)
                        c[i][j] = fmaf(a[i], bb[j], c[i][j]);
            }
            #pragma unroll
            for (int i=0;i<4;i++)
                #pragma unroll
                for (int j=0;j<4;j++)
                    scd[i][j] += (double)c[i][j];
        }
        float sc[4][4];
        #pragma unroll
        for (int i=0;i<4;i++)
            #pragma unroll
            for (int j=0;j<4;j++)
                sc[i][j] = (float)scd[i][j];
        #pragma unroll
        for (int i=0;i<4;i++){
            float tm = fmaxf(fmaxf(sc[i][0],sc[i][1]), fmaxf(sc[i][2],sc[i][3]));
            #pragma unroll
            for (int msk=1; msk<16; msk<<=1) tm = fmaxf(tm, __shfl_xor(tm, msk, 64));
            float mn = fmaxf(m[i], tm);
            float scale = expf(m[i] - mn);
            double rs = 0.0;
            #pragma unroll
            for (int j=0;j<4;j++){ float p = expf(sc[i][j]-mn); sc[i][j]=p; rs += (double)p; }
            #pragma unroll
            for (int msk=1; msk<16; msk<<=1) rs += __shfl_xor(rs, msk, 64);
            l[i] = l[i]*(double)scale + rs;
            m[i] = mn;
            #pragma unroll
            for (int j=0;j<4;j++) acc[i][j] *= (double)scale;
        }
        __syncthreads();
        #pragma unroll
        for (int i=0;i<4;i++)
            #pragma unroll
            for (int j=0;j<4;j++)
                Kt[ty*4+i][tx*4+j] = sc[i][j];
        __syncthreads();
        for (int d0 = 0; d0 < 64; d0 += 16) {
            float c[4][4] = {};
            #pragma unroll
            for (int dd = 0; dd < 16; ++dd) {
                float p[4], v[4];
                #pragma unroll
                for (int i=0;i<4;i++) p[i] = Kt[ty*4+i][d0+dd];
                #pragma unroll
                for (int j=0;j<4;j++) v[j] = Vt[d0+dd][tx*4+j];
                #pragma unroll
                for (int i=0;i<4;i++)
                    #pragma unroll
                    for (int j=0;j<4;j++)
                        c[i][j] = fmaf(p[i], v[j], c[i][j]);
            }
            #pragma unroll
            for (int i=0;i<4;i++)
                #pragma unroll
                for (int j=0;j<4;j++)
                    acc[i][j] += (double)c[i][j];
        }
    }
    #pragma unroll
    for (int i=0;i<4;i++)
        #pragma unroll
        for (int j=0;j<4;j++)
            att[(long long)(row0 + ty*4+i)*512 + h*64 + tx*4+j] = (float)(acc[i][j] / l[i]);
}

// ---------------- row sum of squares (f64) -----------------------------------
__global__ __launch_bounds__(256)
void row_sumsq_r15(const float* __restrict__ X, double* __restrict__ outp)
{
    const int row  = blockIdx.x*4 + (threadIdx.x >> 6);
    const int lane = threadIdx.x & 63;
    double s = 0.0;
    #pragma unroll
    for (int u = 0; u < 8; ++u) {
        float v = X[(long long)row*512 + lane + u*64];
        s += (double)v * (double)v;
    }
    #pragma unroll
    for (int msk = 32; msk; msk >>= 1) s += __shfl_xor(s, msk, 64);
    if (lane == 0) outp[row] = s;
}

// ---------------- VQ argmin (r14 verbatim) -----------------------------------
__global__ __launch_bounds__(256)
void vq_argmin_r15(const float* __restrict__ enc, const float* __restrict__ cb,
                   const double* __restrict__ Asum, const double* __restrict__ cbB,
                   float* __restrict__ pbv, int* __restrict__ pbi)
{
    __shared__ float Es[32][68];
    __shared__ float Cs[32][68];
    __shared__ float bv_s[64][17];
    __shared__ int   bi_s[64][17];
    const int tid = threadIdx.x;
    const int tx = tid & 15, ty = tid >> 4;
    const int lr = tid >> 2, lk = (tid & 3) << 2;
    const int bm  = blockIdx.x * 64;
    const int ct0 = blockIdx.y * 512;
    float bestv[4]; int besti[4];
    #pragma unroll
    for (int i=0;i<4;i++){ bestv[i] = 3.0e38f; besti[i] = 2048; }

    for (int ct = ct0; ct < ct0 + 512; ct += 64) {
        double macc[4][4] = {};
        for (int k0 = 0; k0 < 512; k0 += 32) {
            float4 av0 = *(const float4*)(enc + (long long)(bm + lr)*512 + k0 + lk);
            float4 av1 = *(const float4*)(enc + (long long)(bm + lr)*512 + k0 + 16 + lk);
            float4 bv0 = *(const float4*)(cb  + (long long)(ct + lr)*512 + k0 + lk);
            float4 bv1 = *(const float4*)(cb  + (long long)(ct + lr)*512 + k0 + 16 + lk);
            __syncthreads();
            Es[lk+0][lr]=av0.x; Es[lk+1][lr]=av0.y; Es[lk+2][lr]=av0.z; Es[lk+3][lr]=av0.w;
            Es[lk+16][lr]=av1.x; Es[lk+17][lr]=av1.y; Es[lk+18][lr]=av1.z; Es[lk+19][lr]=av1.w;
            Cs[lk+0][lr]=bv0.x; Cs[lk+1][lr]=bv0.y; Cs[lk+2][lr]=bv0.z; Cs[lk+3][lr]=bv0.w;
            Cs[lk+16][lr]=bv1.x; Cs[lk+17][lr]=bv1.y; Cs[lk+18][lr]=bv1.z; Cs[lk+19][lr]=bv1.w;
            __syncthreads();
            #pragma unroll
            for (int half = 0; half < 2; ++half) {
                float cacc[4][4] = {};
                #pragma unroll
                for (int kk2 = 0; kk2 < 16; ++kk2) {
                    const int kk = half*16 + kk2;
                    float a[4], b[4];
                    #pragma unroll
                    for (int i=0;i<4;i++) a[i] = Es[kk][ty*4+i];
                    #pragma unroll
                    for (int j=0;j<4;j++) b[j] = Cs[kk][tx*4+j];
                    #pragma unroll
                    for (int i=0;i<4;i++)
                        #pragma unroll
                        for (int j=0;j<4;j++)
                            cacc[i][j] = fmaf(a[i], b[j], cacc[i][j]);
                }
                #pragma unroll
                for (int i=0;i<4;i++)
                    #pragma unroll
                    for (int j=0;j<4;j++)
                        macc[i][j] += (double)cacc[i][j];
            }
        }
        #pragma unroll
        for (int i=0;i<4;i++){
            const float anf = (float)Asum[bm + ty*4 + i];
            #pragma unroll
            for (int j=0;j<4;j++){
                const int ci = ct + tx*4 + j;
                const float bf  = (float)cbB[ci];
                const float s1  = anf + bf;
                const float df  = (float)(2.0 * macc[i][j]);
                const float qd  = s1 - df;
                if (qd < bestv[i] || (qd == bestv[i] && ci < besti[i])) {
                    bestv[i] = qd; besti[i] = ci;
                }
            }
        }
    }
    #pragma unroll
    for (int i=0;i<4;i++){ bv_s[ty*4+i][tx] = bestv[i]; bi_s[ty*4+i][tx] = besti[i]; }
    __syncthreads();
    if (tid < 64) {
        float bv = bv_s[tid][0]; int bi = bi_s[tid][0];
        #pragma unroll
        for (int x = 1; x < 16; ++x) {
            float v = bv_s[tid][x]; int ii = bi_s[tid][x];
            if (v < bv || (v == bv && ii < bi)) { bv = v; bi = ii; }
        }
        pbv[(long long)blockIdx.y*16384 + bm + tid] = bv;
        pbi[(long long)blockIdx.y*16384 + bm + tid] = bi;
    }
}

__global__ __launch_bounds__(256)
void vq_reduce_r15(const float* __restrict__ pbv, const int* __restrict__ pbi,
                   int* __restrict__ idxout)
{
    int n = blockIdx.x*256 + threadIdx.x;
    if (n >= 16384) return;
    float bv = pbv[n]; int bi = pbi[n];
    #pragma unroll
    for (int q = 1; q < 4; ++q) {
        float v = pbv[q*16384 + n]; int ii = pbi[q*16384 + n];
        if (v < bv || (v == bv && ii < bi)) { bv = v; bi = ii; }
    }
    idxout[n] = bi & 2047;
}

// ---------------- vq loss ----------------------------------------------------
__global__ __launch_bounds__(256)
void vq_loss_partial_r15(const float* __restrict__ enc, const float* __restrict__ cb,
                         const int* __restrict__ idxp, double* __restrict__ part)
{
    __shared__ double red[4];
    const int row  = blockIdx.x*4 + (threadIdx.x >> 6);
    const int lane = threadIdx.x & 63;
    const int ci = idxp[row] & 2047;
    double s = 0.0;
    #pragma unroll
    for (int u = 0; u < 8; ++u) {
        int d = lane + u*64;
        double dv = (double)cb[(long long)ci*512 + d] - (double)enc[(long long)row*512 + d];
        s += dv * dv;
    }
    #pragma unroll
    for (int msk = 32; msk; msk >>= 1) s += __shfl_xor(s, msk, 64);
    if (lane == 0) red[threadIdx.x >> 6] = s;
    __syncthreads();
    if (threadIdx.x == 0)
        part[blockIdx.x] = red[0] + red[1] + red[2] + red[3];
}

// ---------------- regime softmax ---------------------------------------------
__global__ __launch_bounds__(256)
void softmax_rows_r15(float* __restrict__ R)
{
    const int row = blockIdx.x;
    const int tid = threadIdx.x;
    __shared__ float  redf[256];
    __shared__ double redd[256];
    float* p = R + (long long)row * 2048;
    float mx = -1e30f;
    for (int c = tid; c < 2048; c += 256) mx = fmaxf(mx, p[c]);
    redf[tid] = mx; __syncthreads();
    for (int s2 = 128; s2; s2 >>= 1) { if (tid < s2) redf[tid] = fmaxf(redf[tid], redf[tid+s2]); __syncthreads(); }
    mx = redf[0];
    double sum = 0.0;
    for (int c = tid; c < 2048; c += 256) { float e = expf(p[c] - mx); p[c] = e; sum += e; }
    redd[tid] = sum; __syncthreads();
    for (int s2 = 128; s2; s2 >>= 1) { if (tid < s2) redd[tid] += redd[tid+s2]; __syncthreads(); }
    double tot = redd[0];
    for (int c = tid; c < 2048; c += 256) p[c] = (float)((double)p[c] / tot);
}

// ---------------- hash table -------------------------------------------------
__global__ __launch_bounds__(256)
void hash_table_r15(const float* __restrict__ cb, const float* __restrict__ hw,
                    float* __restrict__ T)
{
    const int k = blockIdx.x*4 + (threadIdx.x >> 6);
    const int j = threadIdx.x & 63;
    double s = 0.0;
    for (int d = 0; d < 512; ++d)
        s += (double)cb[(long long)k*512 + d] * (double)hw[(long long)j*512 + d];
    T[(long long)k*64 + j] = (s > 0.0) ? 1.0f : 0.0f;
}

// ---------------- output writers ---------------------------------------------
__global__ void write_loss_r15(const double* __restrict__ part,
                               float* __restrict__ out)
{
    __shared__ double red[256];
    double s = 0.0;
    for (int i = threadIdx.x; i < 4096; i += 256) s += part[i];
    red[threadIdx.x] = s; __syncthreads();
    for (int s2 = 128; s2; s2 >>= 1) {
        if (threadIdx.x < s2) red[threadIdx.x] += red[threadIdx.x + s2];
        __syncthreads();
    }
    if (threadIdx.x == 0)
        out[O_LOSS] = (float)(1.25 * red[0] / 8388608.0);
}

__global__ __launch_bounds__(256)
void write_regime_r15(const float* __restrict__ R, const int* __restrict__ idxp,
                      float* __restrict__ out)
{
    long long i = (long long)blockIdx.x*256 + threadIdx.x;
    if (i >= 33554432LL) return;
    int n = (int)(i >> 11), c = (int)(i & 2047);
    int ci = idxp[n] & 2047;
    out[O_REG + i] = R[(long long)ci*2048 + c];
}

__global__ __launch_bounds__(256)
void write_hash_r15(const float* __restrict__ T, const int* __restrict__ idxp,
                    float* __restrict__ out)
{
    long long i = (long long)blockIdx.x*256 + threadIdx.x;
    if (i >= 1048576LL) return;
    int n = (int)(i >> 6), j = (int)(i & 63);
    int ci = idxp[n] & 2047;
    out[O_HASH + i] = T[(long long)ci*64 + j];
}

__global__ __launch_bounds__(256)
void write_idx_r15(const int* __restrict__ idxp, float* __restrict__ out)
{
    int n = blockIdx.x*256 + threadIdx.x;
    if (n >= 16384) return;
    out[O_IDX + n] = (float)(idxp[n] & 2047);
}

__global__ __launch_bounds__(256)
void write_quant_r15(const float* __restrict__ cb, const int* __restrict__ idxp,
                     float* __restrict__ out)
{
    long long i = (long long)blockIdx.x*256 + threadIdx.x;
    if (i >= 8388608LL) return;
    int n = (int)(i >> 9), d = (int)(i & 511);
    int ci = idxp[n] & 2047;
    out[O_QUANT + i] = cb[(long long)ci*512 + d];
}

// ---------------- launcher ----------------------------------------------------
extern "C" void kernel_launch(void* const* d_in, const int* in_sizes, int n_in,
                              void* d_out, int out_size, void* d_ws, size_t ws_size,
                              hipStream_t stream)
{
    (void)in_sizes; (void)n_in; (void)out_size;
    const float* market = (const float*)d_in[0];
    const float* W_in   = (const float*)d_in[1];
    const float* b_in   = (const float*)d_in[2];
    const float* pos    = (const float*)d_in[3];
    const float* c3w = (const float*)d_in[4];  const float* c3b = (const float*)d_in[5];
    const float* c5w = (const float*)d_in[6];  const float* c5b = (const float*)d_in[7];
    const float* c7w = (const float*)d_in[8];  const float* c7b = (const float*)d_in[9];
    const float* c9w = (const float*)d_in[10]; const float* c9b = (const float*)d_in[11];
    const float* msw = (const float*)d_in[12]; const float* msb = (const float*)d_in[13];
    const float* inw = (const float*)d_in[14]; const float* inb = (const float*)d_in[15];
    const float* aow = (const float*)d_in[16]; const float* aob = (const float*)d_in[17];
    const float* cb  = (const float*)d_in[18]; const float* hw  = (const float*)d_in[19];
    const float* r1w = (const float*)d_in[20]; const float* r1b = (const float*)d_in[21];
    const float* r2w = (const float*)d_in[22]; const float* r2b = (const float*)d_in[23];

    if (ws_size < (size_t)W_END * sizeof(float)) return;

    float* ws    = (float*)d_ws;
    float* xp    = ws + W_XP;            // f32 -> packed hi/lo -> attp
    float* convt = ws + W_CT;
    float* projp = ws + W_PROJ;
    unsigned int* wt3 = (unsigned int*)(ws + W_VW);   // packed conv weights
    unsigned int* wt5 = wt3 + 512*512*3;
    unsigned int* wt7 = wt5 + 512*512*5;
    unsigned int* wt9 = wt7 + 512*512*7;
    float* Vbufp = ws + W_VW;            // overwrites packed wt after convs
    float* hregp = ws + W_HREG;
    float* Tp    = ws + W_T;
    int*    idxp  = (int*)(ws + W_IDX);
    double* asump = (double*)(ws + W_ASUM);
    double* cbbp  = (double*)(ws + W_CBB);
    double* lpart = (double*)(ws + W_LPART);
    float*  pbvp  = ws + W_PBV;
    int*    pbip  = (int*)(ws + W_PBI);

    float* out = (float*)d_out;

    float* attp  = xp;
    float* Kbufp = convt;
    float* encp  = convt;
    float* Rp    = projp;

    const unsigned int* xpu = (const unsigned int*)xp;

    // conv weight transpose+split (packed hi/lo)
    conv_w_tr_r15<3><<<3072, 256, 0, stream>>>(c3w, wt3);
    conv_w_tr_r15<5><<<5120, 256, 0, stream>>>(c5w, wt5);
    conv_w_tr_r15<7><<<7168, 256, 0, stream>>>(c7w, wt7);
    conv_w_tr_r15<9><<<9216, 256, 0, stream>>>(c9w, wt9);

    const dim3 gT(128, 4);    // 128x128 tiles over 16384x512

    // xp = market @ W_in^T + b_in + pos_enc, then split in place
    gemm_bt_r15<GF_BIAS|GF_POS><<<gT, 256, 0, stream>>>(market, W_in, b_in, pos, nullptr, xp, 512, 512, 512, 512);
    split_xp_r15<<<32768, 256, 0, stream>>>(xp);

    // proj = sum_c relu(conv_c(xp)) @ msW_c^T
    conv_mfma_r15<3><<<gT, 256, 0, stream>>>(xpu, wt3, c3b, convt);
    gemm_bt_r15<GF_BIAS><<<gT, 256, 0, stream>>>(convt, msw + 0*512, msb, nullptr, nullptr, projp, 512, 512, 2048, 512);
    conv_mfma_r15<5><<<gT, 256, 0, stream>>>(xpu, wt5, c5b, convt);
    gemm_bt_r15<GF_ACC><<<gT, 256, 0, stream>>>(convt, msw + 1*512, nullptr, nullptr, nullptr, projp, 512, 512, 2048, 512);
    conv_mfma_r15<7><<<gT, 256, 0, stream>>>(xpu, wt7, c7b, convt);
    gemm_bt_r15<GF_ACC><<<gT, 256, 0, stream>>>(convt, msw + 2*512, nullptr, nullptr, nullptr, projp, 512, 512, 2048, 512);
    conv_mfma_r15<9><<<gT, 256, 0, stream>>>(xpu, wt9, c9b, convt);
    gemm_bt_r15<GF_ACC><<<gT, 256, 0, stream>>>(convt, msw + 3*512, nullptr, nullptr, nullptr, projp, 512, 512, 2048, 512);

    // K, V projections (V overwrites packed wt, now dead)
    gemm_bt_r15<GF_BIAS><<<gT, 256, 0, stream>>>(projp, inw + 512*512,  inb + 512,  nullptr, nullptr, Kbufp, 512, 512, 512, 512);
    gemm_bt_r15<GF_BIAS><<<gT, 256, 0, stream>>>(projp, inw + 1024*512, inb + 1024, nullptr, nullptr, Vbufp, 512, 512, 512, 512);

    attn_fused_r15<<<2048, 256, 0, stream>>>(projp, inw, inb, Kbufp, Vbufp, attp);

    // enc = proj + att @ attn_out_w^T + attn_out_b
    gemm_bt_r15<GF_BIAS|GF_ADD><<<gT, 256, 0, stream>>>(attp, aow, aob, nullptr, projp, encp, 512, 512, 512, 512);

    // VQ
    row_sumsq_r15<<<4096, 256, 0, stream>>>(encp, asump);
    row_sumsq_r15<<<512,  256, 0, stream>>>(cb, cbbp);
    vq_argmin_r15<<<dim3(256, 4), 256, 0, stream>>>(encp, cb, asump, cbbp, pbvp, pbip);
    vq_reduce_r15<<<64, 256, 0, stream>>>(pbvp, pbip, idxp);
    vq_loss_partial_r15<<<4096, 256, 0, stream>>>(encp, cb, idxp, lpart);

    // regime tables
    gemm_bt_r15<GF_BIAS|GF_RELU><<<dim3(16, 2),  256, 0, stream>>>(cb, r1w, r1b, nullptr, nullptr, hregp, 512, 512, 512, 256);
    gemm_bt_r15<GF_BIAS><<<dim3(16, 16), 256, 0, stream>>>(hregp, r2w, r2b, nullptr, nullptr, Rp, 256, 256, 256, 2048);
    softmax_rows_r15<<<2048, 256, 0, stream>>>(Rp);
    hash_table_r15<<<512, 256, 0, stream>>>(cb, hw, Tp);

    // outputs
    write_loss_r15<<<1, 256, 0, stream>>>(lpart, out);
    write_regime_r15<<<131072, 256, 0, stream>>>(Rp, idxp, out);
    write_hash_r15<<<4096, 256, 0, stream>>>(Tp, idxp, out);
    write_idx_r15<<<64, 256, 0, stream>>>(idxp, out);
    write_quant_r15<<<32768, 256, 0, stream>>>(cb, idxp, out);
}

// Round 16
// 2153.805 us; speedup vs baseline: 2.5851x; 1.3401x over previous
//
#include <hip/hip_runtime.h>
#include <hip/hip_bf16.h>

// ---------------- problem constants ----------------
// B=32, S=512, D=512, K=2048; N = B*S = 16384. d_out is FLOAT32.
// r16: all 8 big GEMMs + 4 convs use f16x3 split MFMA (noise class proven in
// r15). Q-projection hoisted out of attention (block-private in-place reuse of
// the xp region). Attention QK/PV in plain f32. VQ argmin verbatim.

#define GF_BIAS 1
#define GF_RELU 2
#define GF_ADD  4
#define GF_POS  8
#define GF_ACC  16

typedef _Float16 f16x8 __attribute__((ext_vector_type(8)));
typedef float    f32x4 __attribute__((ext_vector_type(4)));

// output layout (f32 elements), return order — total 43,008,001
static constexpr long long O_QUANT = 0LL;
static constexpr long long O_LOSS  = 8388608LL;
static constexpr long long O_IDX   = 8388609LL;
static constexpr long long O_HASH  = 8404993LL;
static constexpr long long O_REG   = 9453569LL;
static constexpr long long O_END   = 43008001LL;

// workspace layout (f32 element offsets)
static constexpr long long W_XP    = 0LL;         // xp -> packed -> Qbuf -> att
static constexpr long long W_CT    = 8388608LL;   // convt -> Kbuf -> enc
static constexpr long long W_PROJ  = 16777216LL;  // proj -> R
static constexpr long long W_VW    = 25165824LL;  // packed conv w -> V
static constexpr long long W_HREG  = 33554432LL;
static constexpr long long W_T     = 34078720LL;
static constexpr long long W_IDX   = 34209792LL;
static constexpr long long W_ASUM  = 34226176LL;
static constexpr long long W_CBB   = 34258944LL;
static constexpr long long W_LPART = 34263040LL;
static constexpr long long W_PBV   = 34271232LL;
static constexpr long long W_PBI   = 34336768LL;
static constexpr long long W_END   = 34402304LL;

__device__ __forceinline__ unsigned int pack_hl(float x)
{
    _Float16 h = (_Float16)x;
    float hf = (float)h;
    _Float16 l = (_Float16)(x - hf);
    unsigned short hb = __builtin_bit_cast(unsigned short, h);
    unsigned short lb = __builtin_bit_cast(unsigned short, l);
    return (unsigned int)hb | ((unsigned int)lb << 16);
}

__device__ __forceinline__ void split2(float x, unsigned short& h, unsigned short& l)
{
    _Float16 hf = (_Float16)x;
    _Float16 lf = (_Float16)(x - (float)hf);
    h = __builtin_bit_cast(unsigned short, hf);
    l = __builtin_bit_cast(unsigned short, lf);
}

// ---------------- split xp in place: f32 -> packed (hi,lo) -------------------
__global__ __launch_bounds__(256)
void split_xp_r16(float* __restrict__ xp)
{
    long long i = (long long)blockIdx.x*256 + threadIdx.x;  // 8388608
    float x = xp[i];
    ((unsigned int*)xp)[i] = pack_hl(x);
}

// conv weight transpose+split: w[o][i][t] f32 -> packed [o][t][i]
template<int KT>
__global__ __launch_bounds__(256)
void conv_w_tr_r16(const float* __restrict__ w, unsigned int* __restrict__ wt)
{
    long long i = (long long)blockIdx.x*256 + threadIdx.x;
    int o  = (int)(i / (512*KT));
    int rem= (int)(i % (512*KT));
    int t  = rem >> 9;
    int ii = rem & 511;
    wt[i] = pack_hl(w[(long long)o*512*KT + (long long)ii*KT + t]);
}

// ---------------- conv via f16x3 MFMA (r15 verbatim) -------------------------
template<int KT>
__global__ __launch_bounds__(256)
void conv_mfma_r16(const unsigned int* __restrict__ xphl,
                   const unsigned int* __restrict__ wthl,
                   const float* __restrict__ bias, float* __restrict__ outp)
{
    constexpr int PAD = KT / 2;
    __shared__ unsigned short Ah[128][56];
    __shared__ unsigned short Al[128][56];
    __shared__ unsigned short Bh[128][56];
    __shared__ unsigned short Bl[128][56];
    const int tid  = threadIdx.x;
    const int lane = tid & 63;
    const int wave = tid >> 6;
    const int wm = (wave >> 1) * 64, wn = (wave & 1) * 64;
    const int bm = blockIdx.x * 128, bn = blockIdx.y * 128;
    const int l15 = lane & 15;
    const int lk8 = (lane >> 4) * 8;
    const int rbase = (lane >> 4) * 4;
    const int cg   = tid & 7;
    const int rw0  = tid >> 3;

    f32x4 acc[4][4];
    #pragma unroll
    for (int i=0;i<4;i++)
        #pragma unroll
        for (int j=0;j<4;j++)
            acc[i][j] = (f32x4){0.f,0.f,0.f,0.f};

    for (int t = 0; t < KT; ++t) {
        for (int i0 = 0; i0 < 512; i0 += 32) {
            uint4 va[4], vb[4];
            #pragma unroll
            for (int q = 0; q < 4; ++q) {
                const int row = rw0 + q*32;
                const int s   = (bm + row) & 511;
                const int sp  = s + t - PAD;
                if (sp >= 0 && sp < 512)
                    va[q] = *(const uint4*)(xphl + (long long)(bm + row + t - PAD)*512 + i0 + cg*4);
                else
                    va[q] = make_uint4(0u,0u,0u,0u);
                vb[q] = *(const uint4*)(wthl + (long long)(bn + row)*(KT*512) + t*512 + i0 + cg*4);
            }
            __syncthreads();
            #pragma unroll
            for (int q = 0; q < 4; ++q) {
                const int row = rw0 + q*32;
                ushort4 ahi = make_ushort4((unsigned short)(va[q].x & 0xffff),
                                           (unsigned short)(va[q].y & 0xffff),
                                           (unsigned short)(va[q].z & 0xffff),
                                           (unsigned short)(va[q].w & 0xffff));
                ushort4 alo = make_ushort4((unsigned short)(va[q].x >> 16),
                                           (unsigned short)(va[q].y >> 16),
                                           (unsigned short)(va[q].z >> 16),
                                           (unsigned short)(va[q].w >> 16));
                ushort4 bhi = make_ushort4((unsigned short)(vb[q].x & 0xffff),
                                           (unsigned short)(vb[q].y & 0xffff),
                                           (unsigned short)(vb[q].z & 0xffff),
                                           (unsigned short)(vb[q].w & 0xffff));
                ushort4 blo = make_ushort4((unsigned short)(vb[q].x >> 16),
                                           (unsigned short)(vb[q].y >> 16),
                                           (unsigned short)(vb[q].z >> 16),
                                           (unsigned short)(vb[q].w >> 16));
                *(ushort4*)(&Ah[row][cg*4]) = ahi;
                *(ushort4*)(&Al[row][cg*4]) = alo;
                *(ushort4*)(&Bh[row][cg*4]) = bhi;
                *(ushort4*)(&Bl[row][cg*4]) = blo;
            }
            __syncthreads();
            f16x8 ah[4], al[4], bh[4], bl[4];
            #pragma unroll
            for (int mi = 0; mi < 4; ++mi) {
                ah[mi] = *(const f16x8*)(&Ah[wm + mi*16 + l15][lk8]);
                al[mi] = *(const f16x8*)(&Al[wm + mi*16 + l15][lk8]);
            }
            #pragma unroll
            for (int nj = 0; nj < 4; ++nj) {
                bh[nj] = *(const f16x8*)(&Bh[wn + nj*16 + l15][lk8]);
                bl[nj] = *(const f16x8*)(&Bl[wn + nj*16 + l15][lk8]);
            }
            #pragma unroll
            for (int mi = 0; mi < 4; ++mi)
                #pragma unroll
                for (int nj = 0; nj < 4; ++nj) {
                    acc[mi][nj] = __builtin_amdgcn_mfma_f32_16x16x32_f16(ah[mi], bh[nj], acc[mi][nj], 0, 0, 0);
                    acc[mi][nj] = __builtin_amdgcn_mfma_f32_16x16x32_f16(ah[mi], bl[nj], acc[mi][nj], 0, 0, 0);
                    acc[mi][nj] = __builtin_amdgcn_mfma_f32_16x16x32_f16(al[mi], bh[nj], acc[mi][nj], 0, 0, 0);
                }
        }
    }
    #pragma unroll
    for (int mi = 0; mi < 4; ++mi) {
        #pragma unroll
        for (int nj = 0; nj < 4; ++nj) {
            const int col = bn + wn + nj*16 + l15;
            const float bcol = bias[col];
            #pragma unroll
            for (int r = 0; r < 4; ++r) {
                const int row = bm + wm + mi*16 + rbase + r;
                float v = acc[mi][nj][r] + bcol;
                outp[(long long)row*512 + col] = fmaxf(v, 0.0f);
            }
        }
    }
}

// ---------------- generic GEMM via f16x3 MFMA (on-the-fly split) -------------
template<int FLAGS>
__global__ __launch_bounds__(256)
void gemm_mfma_r16(const float* __restrict__ A, const float* __restrict__ Bm,
                   const float* __restrict__ bias, const float* __restrict__ pos,
                   const float* __restrict__ addsrc, float* __restrict__ C,
                   int Kdim, int lda, int ldb, int ldc)
{
    __shared__ unsigned short Ah[128][56];
    __shared__ unsigned short Al[128][56];
    __shared__ unsigned short Bh[128][56];
    __shared__ unsigned short Bl[128][56];
    const int tid  = threadIdx.x;
    const int lane = tid & 63;
    const int wave = tid >> 6;
    const int wm = (wave >> 1) * 64, wn = (wave & 1) * 64;
    const int bm = blockIdx.x * 128, bn = blockIdx.y * 128;
    const int l15 = lane & 15;
    const int lk8 = (lane >> 4) * 8;
    const int rbase = (lane >> 4) * 4;
    const int cg   = tid & 7;
    const int rw0  = tid >> 3;

    f32x4 acc[4][4];
    #pragma unroll
    for (int i=0;i<4;i++)
        #pragma unroll
        for (int j=0;j<4;j++)
            acc[i][j] = (f32x4){0.f,0.f,0.f,0.f};

    for (int k0 = 0; k0 < Kdim; k0 += 32) {
        float4 fa[4], fb[4];
        #pragma unroll
        for (int q = 0; q < 4; ++q) {
            const int row = rw0 + q*32;
            fa[q] = *(const float4*)(A  + (long long)(bm + row)*lda + k0 + cg*4);
            fb[q] = *(const float4*)(Bm + (long long)(bn + row)*ldb + k0 + cg*4);
        }
        __syncthreads();
        #pragma unroll
        for (int q = 0; q < 4; ++q) {
            const int row = rw0 + q*32;
            ushort4 ah_, al_, bh_, bl_;
            split2(fa[q].x, ah_.x, al_.x);
            split2(fa[q].y, ah_.y, al_.y);
            split2(fa[q].z, ah_.z, al_.z);
            split2(fa[q].w, ah_.w, al_.w);
            split2(fb[q].x, bh_.x, bl_.x);
            split2(fb[q].y, bh_.y, bl_.y);
            split2(fb[q].z, bh_.z, bl_.z);
            split2(fb[q].w, bh_.w, bl_.w);
            *(ushort4*)(&Ah[row][cg*4]) = ah_;
            *(ushort4*)(&Al[row][cg*4]) = al_;
            *(ushort4*)(&Bh[row][cg*4]) = bh_;
            *(ushort4*)(&Bl[row][cg*4]) = bl_;
        }
        __syncthreads();
        f16x8 ah[4], al[4], bh[4], bl[4];
        #pragma unroll
        for (int mi = 0; mi < 4; ++mi) {
            ah[mi] = *(const f16x8*)(&Ah[wm + mi*16 + l15][lk8]);
            al[mi] = *(const f16x8*)(&Al[wm + mi*16 + l15][lk8]);
        }
        #pragma unroll
        for (int nj = 0; nj < 4; ++nj) {
            bh[nj] = *(const f16x8*)(&Bh[wn + nj*16 + l15][lk8]);
            bl[nj] = *(const f16x8*)(&Bl[wn + nj*16 + l15][lk8]);
        }
        #pragma unroll
        for (int mi = 0; mi < 4; ++mi)
            #pragma unroll
            for (int nj = 0; nj < 4; ++nj) {
                acc[mi][nj] = __builtin_amdgcn_mfma_f32_16x16x32_f16(ah[mi], bh[nj], acc[mi][nj], 0, 0, 0);
                acc[mi][nj] = __builtin_amdgcn_mfma_f32_16x16x32_f16(ah[mi], bl[nj], acc[mi][nj], 0, 0, 0);
                acc[mi][nj] = __builtin_amdgcn_mfma_f32_16x16x32_f16(al[mi], bh[nj], acc[mi][nj], 0, 0, 0);
            }
    }
    #pragma unroll
    for (int mi = 0; mi < 4; ++mi) {
        #pragma unroll
        for (int nj = 0; nj < 4; ++nj) {
            const int col = bn + wn + nj*16 + l15;
            #pragma unroll
            for (int r = 0; r < 4; ++r) {
                const int row = bm + wm + mi*16 + rbase + r;
                float v = acc[mi][nj][r];
                if constexpr (FLAGS & GF_BIAS) v += bias[col];
                if constexpr (FLAGS & GF_POS)  v += pos[(long long)(row & 511)*512 + col];
                if constexpr (FLAGS & GF_ADD)  v += addsrc[(long long)row*ldc + col];
                if constexpr (FLAGS & GF_ACC)  v += C[(long long)row*ldc + col];
                if constexpr (FLAGS & GF_RELU) v = fmaxf(v, 0.0f);
                C[(long long)row*ldc + col] = v;
            }
        }
    }
}

// ---------------- fused attention: Q precomputed, f32 math -------------------
// Qbuf region == att region (block-private row x col range: safe in-place).
__global__ __launch_bounds__(256)
void attn_fused_r16(const float* __restrict__ Qbuf, const float* __restrict__ Kbuf,
                    const float* __restrict__ Vbuf, float* __restrict__ att)
{
    __shared__ float Qs[64][65];
    __shared__ float Kt[64][65];
    __shared__ float Vt[64][65];
    const int tid = threadIdx.x;
    const int tx = tid & 15, ty = tid >> 4;
    const int bid = blockIdx.x;
    const int qt = bid & 7, h = (bid >> 3) & 7, b = bid >> 6;
    const int row0 = b*512 + qt*64;

    #pragma unroll
    for (int u = 0; u < 16; ++u) {
        int e = u*256 + tid;
        int r = e >> 6, c = e & 63;
        Qs[r][c] = Qbuf[(long long)(row0 + r)*512 + h*64 + c] * 0.125f;
    }

    float m[4], l[4], acc[4][4] = {};
    #pragma unroll
    for (int i=0;i<4;i++){ m[i] = -1e30f; l[i] = 0.f; }

    for (int kv = 0; kv < 512; kv += 64) {
        __syncthreads();
        #pragma unroll
        for (int u = 0; u < 16; ++u) {
            int e = u*256 + tid;
            int r = e >> 6, c = e & 63;
            Kt[r][c] = Kbuf[(long long)(b*512 + kv + r)*512 + h*64 + c];
            Vt[r][c] = Vbuf[(long long)(b*512 + kv + r)*512 + h*64 + c];
        }
        __syncthreads();
        float sc[4][4] = {};
        for (int d = 0; d < 64; ++d) {
            float a[4], bb[4];
            #pragma unroll
            for (int i=0;i<4;i++) a[i] = Qs[ty*4+i][d];
            #pragma unroll
            for (int j=0;j<4;j++) bb[j] = Kt[tx*4+j][d];
            #pragma unroll
            for (int i=0;i<4;i++)
                #pragma unroll
                for (int j=0;j<4;j++)
                    sc[i][j] = fmaf(a[i], bb[j], sc[i][j]);
        }
        #pragma unroll
        for (int i=0;i<4;i++){
            float tm = fmaxf(fmaxf(sc[i][0],sc[i][1]), fmaxf(sc[i][2],sc[i][3]));
            #pragma unroll
            for (int msk=1; msk<16; msk<<=1) tm = fmaxf(tm, __shfl_xor(tm, msk, 64));
            float mn = fmaxf(m[i], tm);
            float scale = expf(m[i] - mn);
            float rs = 0.f;
            #pragma unroll
            for (int j=0;j<4;j++){ float p = expf(sc[i][j]-mn); sc[i][j]=p; rs += p; }
            #pragma unroll
            for (int msk=1; msk<16; msk<<=1) rs += __shfl_xor(rs, msk, 64);
            l[i] = l[i]*scale + rs;
            m[i] = mn;
            #pragma unroll
            for (int j=0;j<4;j++) acc[i][j] *= scale;
        }
        __syncthreads();
        #pragma unroll
        for (int i=0;i<4;i++)
            #pragma unroll
            for (int j=0;j<4;j++)
                Kt[ty*4+i][tx*4+j] = sc[i][j];
        __syncthreads();
        for (int d = 0; d < 64; ++d) {
            float p[4], v[4];
            #pragma unroll
            for (int i=0;i<4;i++) p[i] = Kt[ty*4+i][d];
            #pragma unroll
            for (int j=0;j<4;j++) v[j] = Vt[d][tx*4+j];
            #pragma unroll
            for (int i=0;i<4;i++)
                #pragma unroll
                for (int j=0;j<4;j++)
                    acc[i][j] = fmaf(p[i], v[j], acc[i][j]);
        }
    }
    #pragma unroll
    for (int i=0;i<4;i++)
        #pragma unroll
        for (int j=0;j<4;j++)
            att[(long long)(row0 + ty*4+i)*512 + h*64 + tx*4+j] = acc[i][j] / l[i];
}

// ---------------- row sum of squares (f64) -----------------------------------
__global__ __launch_bounds__(256)
void row_sumsq_r16(const float* __restrict__ X, double* __restrict__ outp)
{
    const int row  = blockIdx.x*4 + (threadIdx.x >> 6);
    const int lane = threadIdx.x & 63;
    double s = 0.0;
    #pragma unroll
    for (int u = 0; u < 8; ++u) {
        float v = X[(long long)row*512 + lane + u*64];
        s += (double)v * (double)v;
    }
    #pragma unroll
    for (int msk = 32; msk; msk >>= 1) s += __shfl_xor(s, msk, 64);
    if (lane == 0) outp[row] = s;
}

// ---------------- VQ argmin (verbatim) ---------------------------------------
__global__ __launch_bounds__(256)
void vq_argmin_r16(const float* __restrict__ enc, const float* __restrict__ cb,
                   const double* __restrict__ Asum, const double* __restrict__ cbB,
                   float* __restrict__ pbv, int* __restrict__ pbi)
{
    __shared__ float Es[32][68];
    __shared__ float Cs[32][68];
    __shared__ float bv_s[64][17];
    __shared__ int   bi_s[64][17];
    const int tid = threadIdx.x;
    const int tx = tid & 15, ty = tid >> 4;
    const int lr = tid >> 2, lk = (tid & 3) << 2;
    const int bm  = blockIdx.x * 64;
    const int ct0 = blockIdx.y * 512;
    float bestv[4]; int besti[4];
    #pragma unroll
    for (int i=0;i<4;i++){ bestv[i] = 3.0e38f; besti[i] = 2048; }

    for (int ct = ct0; ct < ct0 + 512; ct += 64) {
        double macc[4][4] = {};
        for (int k0 = 0; k0 < 512; k0 += 32) {
            float4 av0 = *(const float4*)(enc + (long long)(bm + lr)*512 + k0 + lk);
            float4 av1 = *(const float4*)(enc + (long long)(bm + lr)*512 + k0 + 16 + lk);
            float4 bv0 = *(const float4*)(cb  + (long long)(ct + lr)*512 + k0 + lk);
            float4 bv1 = *(const float4*)(cb  + (long long)(ct + lr)*512 + k0 + 16 + lk);
            __syncthreads();
            Es[lk+0][lr]=av0.x; Es[lk+1][lr]=av0.y; Es[lk+2][lr]=av0.z; Es[lk+3][lr]=av0.w;
            Es[lk+16][lr]=av1.x; Es[lk+17][lr]=av1.y; Es[lk+18][lr]=av1.z; Es[lk+19][lr]=av1.w;
            Cs[lk+0][lr]=bv0.x; Cs[lk+1][lr]=bv0.y; Cs[lk+2][lr]=bv0.z; Cs[lk+3][lr]=bv0.w;
            Cs[lk+16][lr]=bv1.x; Cs[lk+17][lr]=bv1.y; Cs[lk+18][lr]=bv1.z; Cs[lk+19][lr]=bv1.w;
            __syncthreads();
            #pragma unroll
            for (int half = 0; half < 2; ++half) {
                float cacc[4][4] = {};
                #pragma unroll
                for (int kk2 = 0; kk2 < 16; ++kk2) {
                    const int kk = half*16 + kk2;
                    float a[4], b[4];
                    #pragma unroll
                    for (int i=0;i<4;i++) a[i] = Es[kk][ty*4+i];
                    #pragma unroll
                    for (int j=0;j<4;j++) b[j] = Cs[kk][tx*4+j];
                    #pragma unroll
                    for (int i=0;i<4;i++)
                        #pragma unroll
                        for (int j=0;j<4;j++)
                            cacc[i][j] = fmaf(a[i], b[j], cacc[i][j]);
                }
                #pragma unroll
                for (int i=0;i<4;i++)
                    #pragma unroll
                    for (int j=0;j<4;j++)
                        macc[i][j] += (double)cacc[i][j];
            }
        }
        #pragma unroll
        for (int i=0;i<4;i++){
            const float anf = (float)Asum[bm + ty*4 + i];
            #pragma unroll
            for (int j=0;j<4;j++){
                const int ci = ct + tx*4 + j;
                const float bf  = (float)cbB[ci];
                const float s1  = anf + bf;
                const float df  = (float)(2.0 * macc[i][j]);
                const float qd  = s1 - df;
                if (qd < bestv[i] || (qd == bestv[i] && ci < besti[i])) {
                    bestv[i] = qd; besti[i] = ci;
                }
            }
        }
    }
    #pragma unroll
    for (int i=0;i<4;i++){ bv_s[ty*4+i][tx] = bestv[i]; bi_s[ty*4+i][tx] = besti[i]; }
    __syncthreads();
    if (tid < 64) {
        float bv = bv_s[tid][0]; int bi = bi_s[tid][0];
        #pragma unroll
        for (int x = 1; x < 16; ++x) {
            float v = bv_s[tid][x]; int ii = bi_s[tid][x];
            if (v < bv || (v == bv && ii < bi)) { bv = v; bi = ii; }
        }
        pbv[(long long)blockIdx.y*16384 + bm + tid] = bv;
        pbi[(long long)blockIdx.y*16384 + bm + tid] = bi;
    }
}

__global__ __launch_bounds__(256)
void vq_reduce_r16(const float* __restrict__ pbv, const int* __restrict__ pbi,
                   int* __restrict__ idxout)
{
    int n = blockIdx.x*256 + threadIdx.x;
    if (n >= 16384) return;
    float bv = pbv[n]; int bi = pbi[n];
    #pragma unroll
    for (int q = 1; q < 4; ++q) {
        float v = pbv[q*16384 + n]; int ii = pbi[q*16384 + n];
        if (v < bv || (v == bv && ii < bi)) { bv = v; bi = ii; }
    }
    idxout[n] = bi & 2047;
}

// ---------------- vq loss ----------------------------------------------------
__global__ __launch_bounds__(256)
void vq_loss_partial_r16(const float* __restrict__ enc, const float* __restrict__ cb,
                         const int* __restrict__ idxp, double* __restrict__ part)
{
    __shared__ double red[4];
    const int row  = blockIdx.x*4 + (threadIdx.x >> 6);
    const int lane = threadIdx.x & 63;
    const int ci = idxp[row] & 2047;
    double s = 0.0;
    #pragma unroll
    for (int u = 0; u < 8; ++u) {
        int d = lane + u*64;
        double dv = (double)cb[(long long)ci*512 + d] - (double)enc[(long long)row*512 + d];
        s += dv * dv;
    }
    #pragma unroll
    for (int msk = 32; msk; msk >>= 1) s += __shfl_xor(s, msk, 64);
    if (lane == 0) red[threadIdx.x >> 6] = s;
    __syncthreads();
    if (threadIdx.x == 0)
        part[blockIdx.x] = red[0] + red[1] + red[2] + red[3];
}

// ---------------- regime f32 GEMM (small, r14 structure) ---------------------
template<int FLAGS>
__global__ __launch_bounds__(256)
void gemm_bt_r16(const float* __restrict__ A, const float* __restrict__ Bm,
                 const float* __restrict__ bias, const float* __restrict__ pos,
                 const float* __restrict__ addsrc, float* __restrict__ C,
                 int Kdim, int lda, int ldb, int ldc)
{
    __shared__ float As[16][132];
    __shared__ float Bs[16][132];
    const int tid = threadIdx.x;
    const int tx = tid & 15, ty = tid >> 4;
    const int bm = blockIdx.x * 128, bn = blockIdx.y * 128;
    const int r0 = tid >> 2;
    const int kg = (tid & 3) << 2;
    const float* Arow0 = A  + (long long)(bm + r0) * lda + kg;
    const float* Arow1 = A  + (long long)(bm + r0 + 64) * lda + kg;
    const float* Brow0 = Bm + (long long)(bn + r0) * ldb + kg;
    const float* Brow1 = Bm + (long long)(bn + r0 + 64) * ldb + kg;

    float acc[8][8] = {};
    for (int k0 = 0; k0 < Kdim; k0 += 16) {
        float4 a0 = *(const float4*)(Arow0 + k0);
        float4 a1 = *(const float4*)(Arow1 + k0);
        float4 b0 = *(const float4*)(Brow0 + k0);
        float4 b1 = *(const float4*)(Brow1 + k0);
        __syncthreads();
        As[kg+0][r0]=a0.x; As[kg+1][r0]=a0.y; As[kg+2][r0]=a0.z; As[kg+3][r0]=a0.w;
        As[kg+0][r0+64]=a1.x; As[kg+1][r0+64]=a1.y; As[kg+2][r0+64]=a1.z; As[kg+3][r0+64]=a1.w;
        Bs[kg+0][r0]=b0.x; Bs[kg+1][r0]=b0.y; Bs[kg+2][r0]=b0.z; Bs[kg+3][r0]=b0.w;
        Bs[kg+0][r0+64]=b1.x; Bs[kg+1][r0+64]=b1.y; Bs[kg+2][r0+64]=b1.z; Bs[kg+3][r0+64]=b1.w;
        __syncthreads();
        #pragma unroll
        for (int kk = 0; kk < 16; ++kk) {
            float a[8], b[8];
            #pragma unroll
            for (int i=0;i<8;i++) a[i] = As[kk][ty*8+i];
            #pragma unroll
            for (int j=0;j<4;j++) b[j]   = Bs[kk][tx*4+j];
            #pragma unroll
            for (int j=0;j<4;j++) b[4+j] = Bs[kk][64+tx*4+j];
            #pragma unroll
            for (int i=0;i<8;i++)
                #pragma unroll
                for (int j=0;j<8;j++)
                    acc[i][j] = fmaf(a[i], b[j], acc[i][j]);
        }
    }
    #pragma unroll
    for (int i=0;i<8;i++){
        const int row = bm + ty*8 + i;
        #pragma unroll
        for (int j=0;j<8;j++){
            const int col = bn + ((j < 4) ? (tx*4 + j) : (64 + tx*4 + (j-4)));
            float v = acc[i][j];
            if constexpr (FLAGS & GF_BIAS) v += bias[col];
            if constexpr (FLAGS & GF_POS)  v += pos[(long long)(row & 511)*512 + col];
            if constexpr (FLAGS & GF_ADD)  v += addsrc[(long long)row*ldc + col];
            if constexpr (FLAGS & GF_ACC)  v += C[(long long)row*ldc + col];
            if constexpr (FLAGS & GF_RELU) v = fmaxf(v, 0.0f);
            C[(long long)row*ldc + col] = v;
        }
    }
}

// ---------------- regime softmax ---------------------------------------------
__global__ __launch_bounds__(256)
void softmax_rows_r16(float* __restrict__ R)
{
    const int row = blockIdx.x;
    const int tid = threadIdx.x;
    __shared__ float  redf[256];
    __shared__ double redd[256];
    float* p = R + (long long)row * 2048;
    float mx = -1e30f;
    for (int c = tid; c < 2048; c += 256) mx = fmaxf(mx, p[c]);
    redf[tid] = mx; __syncthreads();
    for (int s2 = 128; s2; s2 >>= 1) { if (tid < s2) redf[tid] = fmaxf(redf[tid], redf[tid+s2]); __syncthreads(); }
    mx = redf[0];
    double sum = 0.0;
    for (int c = tid; c < 2048; c += 256) { float e = expf(p[c] - mx); p[c] = e; sum += e; }
    redd[tid] = sum; __syncthreads();
    for (int s2 = 128; s2; s2 >>= 1) { if (tid < s2) redd[tid] += redd[tid+s2]; __syncthreads(); }
    double tot = redd[0];
    for (int c = tid; c < 2048; c += 256) p[c] = (float)((double)p[c] / tot);
}

// ---------------- hash table -------------------------------------------------
__global__ __launch_bounds__(256)
void hash_table_r16(const float* __restrict__ cb, const float* __restrict__ hw,
                    float* __restrict__ T)
{
    const int k = blockIdx.x*4 + (threadIdx.x >> 6);
    const int j = threadIdx.x & 63;
    double s = 0.0;
    for (int d = 0; d < 512; ++d)
        s += (double)cb[(long long)k*512 + d] * (double)hw[(long long)j*512 + d];
    T[(long long)k*64 + j] = (s > 0.0) ? 1.0f : 0.0f;
}

// ---------------- output writers ---------------------------------------------
__global__ void write_loss_r16(const double* __restrict__ part,
                               float* __restrict__ out)
{
    __shared__ double red[256];
    double s = 0.0;
    for (int i = threadIdx.x; i < 4096; i += 256) s += part[i];
    red[threadIdx.x] = s; __syncthreads();
    for (int s2 = 128; s2; s2 >>= 1) {
        if (threadIdx.x < s2) red[threadIdx.x] += red[threadIdx.x + s2];
        __syncthreads();
    }
    if (threadIdx.x == 0)
        out[O_LOSS] = (float)(1.25 * red[0] / 8388608.0);
}

__global__ __launch_bounds__(256)
void write_regime_r16(const float* __restrict__ R, const int* __restrict__ idxp,
                      float* __restrict__ out)
{
    long long i = (long long)blockIdx.x*256 + threadIdx.x;
    if (i >= 33554432LL) return;
    int n = (int)(i >> 11), c = (int)(i & 2047);
    int ci = idxp[n] & 2047;
    out[O_REG + i] = R[(long long)ci*2048 + c];
}

__global__ __launch_bounds__(256)
void write_hash_r16(const float* __restrict__ T, const int* __restrict__ idxp,
                    float* __restrict__ out)
{
    long long i = (long long)blockIdx.x*256 + threadIdx.x;
    if (i >= 1048576LL) return;
    int n = (int)(i >> 6), j = (int)(i & 63);
    int ci = idxp[n] & 2047;
    out[O_HASH + i] = T[(long long)ci*64 + j];
}

__global__ __launch_bounds__(256)
void write_idx_r16(const int* __restrict__ idxp, float* __restrict__ out)
{
    int n = blockIdx.x*256 + threadIdx.x;
    if (n >= 16384) return;
    out[O_IDX + n] = (float)(idxp[n] & 2047);
}

__global__ __launch_bounds__(256)
void write_quant_r16(const float* __restrict__ cb, const int* __restrict__ idxp,
                     float* __restrict__ out)
{
    long long i = (long long)blockIdx.x*256 + threadIdx.x;
    if (i >= 8388608LL) return;
    int n = (int)(i >> 9), d = (int)(i & 511);
    int ci = idxp[n] & 2047;
    out[O_QUANT + i] = cb[(long long)ci*512 + d];
}

// ---------------- launcher ----------------------------------------------------
extern "C" void kernel_launch(void* const* d_in, const int* in_sizes, int n_in,
                              void* d_out, int out_size, void* d_ws, size_t ws_size,
                              hipStream_t stream)
{
    (void)in_sizes; (void)n_in; (void)out_size;
    const float* market = (const float*)d_in[0];
    const float* W_in   = (const float*)d_in[1];
    const float* b_in   = (const float*)d_in[2];
    const float* pos    = (const float*)d_in[3];
    const float* c3w = (const float*)d_in[4];  const float* c3b = (const float*)d_in[5];
    const float* c5w = (const float*)d_in[6];  const float* c5b = (const float*)d_in[7];
    const float* c7w = (const float*)d_in[8];  const float* c7b = (const float*)d_in[9];
    const float* c9w = (const float*)d_in[10]; const float* c9b = (const float*)d_in[11];
    const float* msw = (const float*)d_in[12]; const float* msb = (const float*)d_in[13];
    const float* inw = (const float*)d_in[14]; const float* inb = (const float*)d_in[15];
    const float* aow = (const float*)d_in[16]; const float* aob = (const float*)d_in[17];
    const float* cb  = (const float*)d_in[18]; const float* hw  = (const float*)d_in[19];
    const float* r1w = (const float*)d_in[20]; const float* r1b = (const float*)d_in[21];
    const float* r2w = (const float*)d_in[22]; const float* r2b = (const float*)d_in[23];

    if (ws_size < (size_t)W_END * sizeof(float)) return;

    float* ws    = (float*)d_ws;
    float* xp    = ws + W_XP;
    float* convt = ws + W_CT;
    float* projp = ws + W_PROJ;
    unsigned int* wt3 = (unsigned int*)(ws + W_VW);
    unsigned int* wt5 = wt3 + 512*512*3;
    unsigned int* wt7 = wt5 + 512*512*5;
    unsigned int* wt9 = wt7 + 512*512*7;
    float* Vbufp = ws + W_VW;
    float* hregp = ws + W_HREG;
    float* Tp    = ws + W_T;
    int*    idxp  = (int*)(ws + W_IDX);
    double* asump = (double*)(ws + W_ASUM);
    double* cbbp  = (double*)(ws + W_CBB);
    double* lpart = (double*)(ws + W_LPART);
    float*  pbvp  = ws + W_PBV;
    int*    pbip  = (int*)(ws + W_PBI);

    float* out = (float*)d_out;

    float* Qbufp = xp;      // packed xp dead after conv9; Q then att in place
    float* attp  = xp;
    float* Kbufp = convt;
    float* encp  = convt;
    float* Rp    = projp;

    const unsigned int* xpu = (const unsigned int*)xp;

    conv_w_tr_r16<3><<<3072, 256, 0, stream>>>(c3w, wt3);
    conv_w_tr_r16<5><<<5120, 256, 0, stream>>>(c5w, wt5);
    conv_w_tr_r16<7><<<7168, 256, 0, stream>>>(c7w, wt7);
    conv_w_tr_r16<9><<<9216, 256, 0, stream>>>(c9w, wt9);

    const dim3 gT(128, 4);

    // xp = market @ W_in^T + b_in + pos_enc, then split in place
    gemm_mfma_r16<GF_BIAS|GF_POS><<<gT, 256, 0, stream>>>(market, W_in, b_in, pos, nullptr, xp, 512, 512, 512, 512);
    split_xp_r16<<<32768, 256, 0, stream>>>(xp);

    // proj = sum_c relu(conv_c(xp)) @ msW_c^T
    conv_mfma_r16<3><<<gT, 256, 0, stream>>>(xpu, wt3, c3b, convt);
    gemm_mfma_r16<GF_BIAS><<<gT, 256, 0, stream>>>(convt, msw + 0*512, msb, nullptr, nullptr, projp, 512, 512, 2048, 512);
    conv_mfma_r16<5><<<gT, 256, 0, stream>>>(xpu, wt5, c5b, convt);
    gemm_mfma_r16<GF_ACC><<<gT, 256, 0, stream>>>(convt, msw + 1*512, nullptr, nullptr, nullptr, projp, 512, 512, 2048, 512);
    conv_mfma_r16<7><<<gT, 256, 0, stream>>>(xpu, wt7, c7b, convt);
    gemm_mfma_r16<GF_ACC><<<gT, 256, 0, stream>>>(convt, msw + 2*512, nullptr, nullptr, nullptr, projp, 512, 512, 2048, 512);
    conv_mfma_r16<9><<<gT, 256, 0, stream>>>(xpu, wt9, c9b, convt);
    gemm_mfma_r16<GF_ACC><<<gT, 256, 0, stream>>>(convt, msw + 3*512, nullptr, nullptr, nullptr, projp, 512, 512, 2048, 512);

    // K, V, Q projections (Q overwrites dead packed xp region)
    gemm_mfma_r16<GF_BIAS><<<gT, 256, 0, stream>>>(projp, inw + 512*512,  inb + 512,  nullptr, nullptr, Kbufp, 512, 512, 512, 512);
    gemm_mfma_r16<GF_BIAS><<<gT, 256, 0, stream>>>(projp, inw + 1024*512, inb + 1024, nullptr, nullptr, Vbufp, 512, 512, 512, 512);
    gemm_mfma_r16<GF_BIAS><<<gT, 256, 0, stream>>>(projp, inw,            inb,        nullptr, nullptr, Qbufp, 512, 512, 512, 512);

    attn_fused_r16<<<2048, 256, 0, stream>>>(Qbufp, Kbufp, Vbufp, attp);

    // enc = proj + att @ attn_out_w^T + attn_out_b
    gemm_mfma_r16<GF_BIAS|GF_ADD><<<gT, 256, 0, stream>>>(attp, aow, aob, nullptr, projp, encp, 512, 512, 512, 512);

    // VQ
    row_sumsq_r16<<<4096, 256, 0, stream>>>(encp, asump);
    row_sumsq_r16<<<512,  256, 0, stream>>>(cb, cbbp);
    vq_argmin_r16<<<dim3(256, 4), 256, 0, stream>>>(encp, cb, asump, cbbp, pbvp, pbip);
    vq_reduce_r16<<<64, 256, 0, stream>>>(pbvp, pbip, idxp);
    vq_loss_partial_r16<<<4096, 256, 0, stream>>>(encp, cb, idxp, lpart);

    // regime tables (small, f32)
    gemm_bt_r16<GF_BIAS|GF_RELU><<<dim3(16, 2),  256, 0, stream>>>(cb, r1w, r1b, nullptr, nullptr, hregp, 512, 512, 512, 256);
    gemm_bt_r16<GF_BIAS><<<dim3(16, 16), 256, 0, stream>>>(hregp, r2w, r2b, nullptr, nullptr, Rp, 256, 256, 256, 2048);
    softmax_rows_r16<<<2048, 256, 0, stream>>>(Rp);
    hash_table_r16<<<512, 256, 0, stream>>>(cb, hw, Tp);

    // outputs
    write_loss_r16<<<1, 256, 0, stream>>>(lpart, out);
    write_regime_r16<<<131072, 256, 0, stream>>>(Rp, idxp, out);
    write_hash_r16<<<4096, 256, 0, stream>>>(Tp, idxp, out);
    write_idx_r16<<<64, 256, 0, stream>>>(idxp, out);
    write_quant_r16<<<32768, 256, 0, stream>>>(cb, idxp, out);
}

// Round 17
// 1829.074 us; speedup vs baseline: 3.0440x; 1.1775x over previous
//
#include <hip/hip_runtime.h>
#include <hip/hip_bf16.h>

// ---------------- problem constants ----------------
// B=32, S=512, D=512, K=2048; N = B*S = 16384. d_out is FLOAT32.
// r17 = r16 + vq_argmin dist matrix via f16x3 split MFMA (cb pre-scaled x2048
// so lo-parts stay normal f16; dot rescaled by exact 2^-11). Absorbed compare
// + first-index tie-break verbatim. All else r16-verbatim.

#define GF_BIAS 1
#define GF_RELU 2
#define GF_ADD  4
#define GF_POS  8
#define GF_ACC  16

typedef _Float16 f16x8 __attribute__((ext_vector_type(8)));
typedef float    f32x4 __attribute__((ext_vector_type(4)));

// output layout (f32 elements), return order — total 43,008,001
static constexpr long long O_QUANT = 0LL;
static constexpr long long O_LOSS  = 8388608LL;
static constexpr long long O_IDX   = 8388609LL;
static constexpr long long O_HASH  = 8404993LL;
static constexpr long long O_REG   = 9453569LL;
static constexpr long long O_END   = 43008001LL;

// workspace layout (f32 element offsets)
static constexpr long long W_XP    = 0LL;
static constexpr long long W_CT    = 8388608LL;
static constexpr long long W_PROJ  = 16777216LL;
static constexpr long long W_VW    = 25165824LL;
static constexpr long long W_HREG  = 33554432LL;
static constexpr long long W_T     = 34078720LL;
static constexpr long long W_IDX   = 34209792LL;
static constexpr long long W_ASUM  = 34226176LL;
static constexpr long long W_CBB   = 34258944LL;
static constexpr long long W_LPART = 34263040LL;
static constexpr long long W_PBV   = 34271232LL;  // 4*16384 f32
static constexpr long long W_PBI   = 34336768LL;  // 4*16384 int
static constexpr long long W_END   = 34402304LL;

__device__ __forceinline__ unsigned int pack_hl(float x)
{
    _Float16 h = (_Float16)x;
    float hf = (float)h;
    _Float16 l = (_Float16)(x - hf);
    unsigned short hb = __builtin_bit_cast(unsigned short, h);
    unsigned short lb = __builtin_bit_cast(unsigned short, l);
    return (unsigned int)hb | ((unsigned int)lb << 16);
}

__device__ __forceinline__ void split2(float x, unsigned short& h, unsigned short& l)
{
    _Float16 hf = (_Float16)x;
    _Float16 lf = (_Float16)(x - (float)hf);
    h = __builtin_bit_cast(unsigned short, hf);
    l = __builtin_bit_cast(unsigned short, lf);
}

// ---------------- split xp in place ------------------------------------------
__global__ __launch_bounds__(256)
void split_xp_r17(float* __restrict__ xp)
{
    long long i = (long long)blockIdx.x*256 + threadIdx.x;
    float x = xp[i];
    ((unsigned int*)xp)[i] = pack_hl(x);
}

// conv weight transpose+split
template<int KT>
__global__ __launch_bounds__(256)
void conv_w_tr_r17(const float* __restrict__ w, unsigned int* __restrict__ wt)
{
    long long i = (long long)blockIdx.x*256 + threadIdx.x;
    int o  = (int)(i / (512*KT));
    int rem= (int)(i % (512*KT));
    int t  = rem >> 9;
    int ii = rem & 511;
    wt[i] = pack_hl(w[(long long)o*512*KT + (long long)ii*KT + t]);
}

// ---------------- conv via f16x3 MFMA ----------------------------------------
template<int KT>
__global__ __launch_bounds__(256)
void conv_mfma_r17(const unsigned int* __restrict__ xphl,
                   const unsigned int* __restrict__ wthl,
                   const float* __restrict__ bias, float* __restrict__ outp)
{
    constexpr int PAD = KT / 2;
    __shared__ unsigned short Ah[128][56];
    __shared__ unsigned short Al[128][56];
    __shared__ unsigned short Bh[128][56];
    __shared__ unsigned short Bl[128][56];
    const int tid  = threadIdx.x;
    const int lane = tid & 63;
    const int wave = tid >> 6;
    const int wm = (wave >> 1) * 64, wn = (wave & 1) * 64;
    const int bm = blockIdx.x * 128, bn = blockIdx.y * 128;
    const int l15 = lane & 15;
    const int lk8 = (lane >> 4) * 8;
    const int rbase = (lane >> 4) * 4;
    const int cg   = tid & 7;
    const int rw0  = tid >> 3;

    f32x4 acc[4][4];
    #pragma unroll
    for (int i=0;i<4;i++)
        #pragma unroll
        for (int j=0;j<4;j++)
            acc[i][j] = (f32x4){0.f,0.f,0.f,0.f};

    for (int t = 0; t < KT; ++t) {
        for (int i0 = 0; i0 < 512; i0 += 32) {
            uint4 va[4], vb[4];
            #pragma unroll
            for (int q = 0; q < 4; ++q) {
                const int row = rw0 + q*32;
                const int s   = (bm + row) & 511;
                const int sp  = s + t - PAD;
                if (sp >= 0 && sp < 512)
                    va[q] = *(const uint4*)(xphl + (long long)(bm + row + t - PAD)*512 + i0 + cg*4);
                else
                    va[q] = make_uint4(0u,0u,0u,0u);
                vb[q] = *(const uint4*)(wthl + (long long)(bn + row)*(KT*512) + t*512 + i0 + cg*4);
            }
            __syncthreads();
            #pragma unroll
            for (int q = 0; q < 4; ++q) {
                const int row = rw0 + q*32;
                ushort4 ahi = make_ushort4((unsigned short)(va[q].x & 0xffff),
                                           (unsigned short)(va[q].y & 0xffff),
                                           (unsigned short)(va[q].z & 0xffff),
                                           (unsigned short)(va[q].w & 0xffff));
                ushort4 alo = make_ushort4((unsigned short)(va[q].x >> 16),
                                           (unsigned short)(va[q].y >> 16),
                                           (unsigned short)(va[q].z >> 16),
                                           (unsigned short)(va[q].w >> 16));
                ushort4 bhi = make_ushort4((unsigned short)(vb[q].x & 0xffff),
                                           (unsigned short)(vb[q].y & 0xffff),
                                           (unsigned short)(vb[q].z & 0xffff),
                                           (unsigned short)(vb[q].w & 0xffff));
                ushort4 blo = make_ushort4((unsigned short)(vb[q].x >> 16),
                                           (unsigned short)(vb[q].y >> 16),
                                           (unsigned short)(vb[q].z >> 16),
                                           (unsigned short)(vb[q].w >> 16));
                *(ushort4*)(&Ah[row][cg*4]) = ahi;
                *(ushort4*)(&Al[row][cg*4]) = alo;
                *(ushort4*)(&Bh[row][cg*4]) = bhi;
                *(ushort4*)(&Bl[row][cg*4]) = blo;
            }
            __syncthreads();
            f16x8 ah[4], al[4], bh[4], bl[4];
            #pragma unroll
            for (int mi = 0; mi < 4; ++mi) {
                ah[mi] = *(const f16x8*)(&Ah[wm + mi*16 + l15][lk8]);
                al[mi] = *(const f16x8*)(&Al[wm + mi*16 + l15][lk8]);
            }
            #pragma unroll
            for (int nj = 0; nj < 4; ++nj) {
                bh[nj] = *(const f16x8*)(&Bh[wn + nj*16 + l15][lk8]);
                bl[nj] = *(const f16x8*)(&Bl[wn + nj*16 + l15][lk8]);
            }
            #pragma unroll
            for (int mi = 0; mi < 4; ++mi)
                #pragma unroll
                for (int nj = 0; nj < 4; ++nj) {
                    acc[mi][nj] = __builtin_amdgcn_mfma_f32_16x16x32_f16(ah[mi], bh[nj], acc[mi][nj], 0, 0, 0);
                    acc[mi][nj] = __builtin_amdgcn_mfma_f32_16x16x32_f16(ah[mi], bl[nj], acc[mi][nj], 0, 0, 0);
                    acc[mi][nj] = __builtin_amdgcn_mfma_f32_16x16x32_f16(al[mi], bh[nj], acc[mi][nj], 0, 0, 0);
                }
        }
    }
    #pragma unroll
    for (int mi = 0; mi < 4; ++mi) {
        #pragma unroll
        for (int nj = 0; nj < 4; ++nj) {
            const int col = bn + wn + nj*16 + l15;
            const float bcol = bias[col];
            #pragma unroll
            for (int r = 0; r < 4; ++r) {
                const int row = bm + wm + mi*16 + rbase + r;
                float v = acc[mi][nj][r] + bcol;
                outp[(long long)row*512 + col] = fmaxf(v, 0.0f);
            }
        }
    }
}

// ---------------- generic GEMM via f16x3 MFMA --------------------------------
template<int FLAGS>
__global__ __launch_bounds__(256)
void gemm_mfma_r17(const float* __restrict__ A, const float* __restrict__ Bm,
                   const float* __restrict__ bias, const float* __restrict__ pos,
                   const float* __restrict__ addsrc, float* __restrict__ C,
                   int Kdim, int lda, int ldb, int ldc)
{
    __shared__ unsigned short Ah[128][56];
    __shared__ unsigned short Al[128][56];
    __shared__ unsigned short Bh[128][56];
    __shared__ unsigned short Bl[128][56];
    const int tid  = threadIdx.x;
    const int lane = tid & 63;
    const int wave = tid >> 6;
    const int wm = (wave >> 1) * 64, wn = (wave & 1) * 64;
    const int bm = blockIdx.x * 128, bn = blockIdx.y * 128;
    const int l15 = lane & 15;
    const int lk8 = (lane >> 4) * 8;
    const int rbase = (lane >> 4) * 4;
    const int cg   = tid & 7;
    const int rw0  = tid >> 3;

    f32x4 acc[4][4];
    #pragma unroll
    for (int i=0;i<4;i++)
        #pragma unroll
        for (int j=0;j<4;j++)
            acc[i][j] = (f32x4){0.f,0.f,0.f,0.f};

    for (int k0 = 0; k0 < Kdim; k0 += 32) {
        float4 fa[4], fb[4];
        #pragma unroll
        for (int q = 0; q < 4; ++q) {
            const int row = rw0 + q*32;
            fa[q] = *(const float4*)(A  + (long long)(bm + row)*lda + k0 + cg*4);
            fb[q] = *(const float4*)(Bm + (long long)(bn + row)*ldb + k0 + cg*4);
        }
        __syncthreads();
        #pragma unroll
        for (int q = 0; q < 4; ++q) {
            const int row = rw0 + q*32;
            ushort4 ah_, al_, bh_, bl_;
            split2(fa[q].x, ah_.x, al_.x);
            split2(fa[q].y, ah_.y, al_.y);
            split2(fa[q].z, ah_.z, al_.z);
            split2(fa[q].w, ah_.w, al_.w);
            split2(fb[q].x, bh_.x, bl_.x);
            split2(fb[q].y, bh_.y, bl_.y);
            split2(fb[q].z, bh_.z, bl_.z);
            split2(fb[q].w, bh_.w, bl_.w);
            *(ushort4*)(&Ah[row][cg*4]) = ah_;
            *(ushort4*)(&Al[row][cg*4]) = al_;
            *(ushort4*)(&Bh[row][cg*4]) = bh_;
            *(ushort4*)(&Bl[row][cg*4]) = bl_;
        }
        __syncthreads();
        f16x8 ah[4], al[4], bh[4], bl[4];
        #pragma unroll
        for (int mi = 0; mi < 4; ++mi) {
            ah[mi] = *(const f16x8*)(&Ah[wm + mi*16 + l15][lk8]);
            al[mi] = *(const f16x8*)(&Al[wm + mi*16 + l15][lk8]);
        }
        #pragma unroll
        for (int nj = 0; nj < 4; ++nj) {
            bh[nj] = *(const f16x8*)(&Bh[wn + nj*16 + l15][lk8]);
            bl[nj] = *(const f16x8*)(&Bl[wn + nj*16 + l15][lk8]);
        }
        #pragma unroll
        for (int mi = 0; mi < 4; ++mi)
            #pragma unroll
            for (int nj = 0; nj < 4; ++nj) {
                acc[mi][nj] = __builtin_amdgcn_mfma_f32_16x16x32_f16(ah[mi], bh[nj], acc[mi][nj], 0, 0, 0);
                acc[mi][nj] = __builtin_amdgcn_mfma_f32_16x16x32_f16(ah[mi], bl[nj], acc[mi][nj], 0, 0, 0);
                acc[mi][nj] = __builtin_amdgcn_mfma_f32_16x16x32_f16(al[mi], bh[nj], acc[mi][nj], 0, 0, 0);
            }
    }
    #pragma unroll
    for (int mi = 0; mi < 4; ++mi) {
        #pragma unroll
        for (int nj = 0; nj < 4; ++nj) {
            const int col = bn + wn + nj*16 + l15;
            #pragma unroll
            for (int r = 0; r < 4; ++r) {
                const int row = bm + wm + mi*16 + rbase + r;
                float v = acc[mi][nj][r];
                if constexpr (FLAGS & GF_BIAS) v += bias[col];
                if constexpr (FLAGS & GF_POS)  v += pos[(long long)(row & 511)*512 + col];
                if constexpr (FLAGS & GF_ADD)  v += addsrc[(long long)row*ldc + col];
                if constexpr (FLAGS & GF_ACC)  v += C[(long long)row*ldc + col];
                if constexpr (FLAGS & GF_RELU) v = fmaxf(v, 0.0f);
                C[(long long)row*ldc + col] = v;
            }
        }
    }
}

// ---------------- fused attention (r16 verbatim) -----------------------------
__global__ __launch_bounds__(256)
void attn_fused_r17(const float* __restrict__ Qbuf, const float* __restrict__ Kbuf,
                    const float* __restrict__ Vbuf, float* __restrict__ att)
{
    __shared__ float Qs[64][65];
    __shared__ float Kt[64][65];
    __shared__ float Vt[64][65];
    const int tid = threadIdx.x;
    const int tx = tid & 15, ty = tid >> 4;
    const int bid = blockIdx.x;
    const int qt = bid & 7, h = (bid >> 3) & 7, b = bid >> 6;
    const int row0 = b*512 + qt*64;

    #pragma unroll
    for (int u = 0; u < 16; ++u) {
        int e = u*256 + tid;
        int r = e >> 6, c = e & 63;
        Qs[r][c] = Qbuf[(long long)(row0 + r)*512 + h*64 + c] * 0.125f;
    }

    float m[4], l[4], acc[4][4] = {};
    #pragma unroll
    for (int i=0;i<4;i++){ m[i] = -1e30f; l[i] = 0.f; }

    for (int kv = 0; kv < 512; kv += 64) {
        __syncthreads();
        #pragma unroll
        for (int u = 0; u < 16; ++u) {
            int e = u*256 + tid;
            int r = e >> 6, c = e & 63;
            Kt[r][c] = Kbuf[(long long)(b*512 + kv + r)*512 + h*64 + c];
            Vt[r][c] = Vbuf[(long long)(b*512 + kv + r)*512 + h*64 + c];
        }
        __syncthreads();
        float sc[4][4] = {};
        for (int d = 0; d < 64; ++d) {
            float a[4], bb[4];
            #pragma unroll
            for (int i=0;i<4;i++) a[i] = Qs[ty*4+i][d];
            #pragma unroll
            for (int j=0;j<4;j++) bb[j] = Kt[tx*4+j][d];
            #pragma unroll
            for (int i=0;i<4;i++)
                #pragma unroll
                for (int j=0;j<4;j++)
                    sc[i][j] = fmaf(a[i], bb[j], sc[i][j]);
        }
        #pragma unroll
        for (int i=0;i<4;i++){
            float tm = fmaxf(fmaxf(sc[i][0],sc[i][1]), fmaxf(sc[i][2],sc[i][3]));
            #pragma unroll
            for (int msk=1; msk<16; msk<<=1) tm = fmaxf(tm, __shfl_xor(tm, msk, 64));
            float mn = fmaxf(m[i], tm);
            float scale = expf(m[i] - mn);
            float rs = 0.f;
            #pragma unroll
            for (int j=0;j<4;j++){ float p = expf(sc[i][j]-mn); sc[i][j]=p; rs += p; }
            #pragma unroll
            for (int msk=1; msk<16; msk<<=1) rs += __shfl_xor(rs, msk, 64);
            l[i] = l[i]*scale + rs;
            m[i] = mn;
            #pragma unroll
            for (int j=0;j<4;j++) acc[i][j] *= scale;
        }
        __syncthreads();
        #pragma unroll
        for (int i=0;i<4;i++)
            #pragma unroll
            for (int j=0;j<4;j++)
                Kt[ty*4+i][tx*4+j] = sc[i][j];
        __syncthreads();
        for (int d = 0; d < 64; ++d) {
            float p[4], v[4];
            #pragma unroll
            for (int i=0;i<4;i++) p[i] = Kt[ty*4+i][d];
            #pragma unroll
            for (int j=0;j<4;j++) v[j] = Vt[d][tx*4+j];
            #pragma unroll
            for (int i=0;i<4;i++)
                #pragma unroll
                for (int j=0;j<4;j++)
                    acc[i][j] = fmaf(p[i], v[j], acc[i][j]);
        }
    }
    #pragma unroll
    for (int i=0;i<4;i++)
        #pragma unroll
        for (int j=0;j<4;j++)
            att[(long long)(row0 + ty*4+i)*512 + h*64 + tx*4+j] = acc[i][j] / l[i];
}

// ---------------- row sum of squares (f64) -----------------------------------
__global__ __launch_bounds__(256)
void row_sumsq_r17(const float* __restrict__ X, double* __restrict__ outp)
{
    const int row  = blockIdx.x*4 + (threadIdx.x >> 6);
    const int lane = threadIdx.x & 63;
    double s = 0.0;
    #pragma unroll
    for (int u = 0; u < 8; ++u) {
        float v = X[(long long)row*512 + lane + u*64];
        s += (double)v * (double)v;
    }
    #pragma unroll
    for (int msk = 32; msk; msk >>= 1) s += __shfl_xor(s, msk, 64);
    if (lane == 0) outp[row] = s;
}

// ---------------- VQ argmin via f16x3 MFMA -----------------------------------
// 128 tokens x 512 cb-entries per block (4 sub-chunks of 128 cols).
// cb pre-scaled x2048 at split (lo-parts normal f16); dot = acc * 2^-11 exact.
// Compare: qd = fl32(fl32(A+B) - fl32(2*dot)), first-index ties (verbatim).
__global__ __launch_bounds__(256)
void vq_argmin_mfma_r17(const float* __restrict__ enc, const float* __restrict__ cb,
                        const double* __restrict__ Asum, const double* __restrict__ cbB,
                        float* __restrict__ pbv, int* __restrict__ pbi)
{
    __shared__ unsigned int smem[14336];   // 57344 B union
    unsigned short* AhP = (unsigned short*)smem;           // [128][56]
    unsigned short* AlP = AhP + 128*56;
    unsigned short* BhP = AlP + 128*56;
    unsigned short* BlP = BhP + 128*56;
    float* bvsP = (float*)smem;                            // [128][32]
    int*   bisP = (int*)(smem + 4096);                     // [128][32]

    const int tid  = threadIdx.x;
    const int lane = tid & 63;
    const int wave = tid >> 6;
    const int wm = (wave >> 1) * 64, wn = (wave & 1) * 64;
    const int bm = blockIdx.x * 128;
    const int l15 = lane & 15;
    const int lk8 = (lane >> 4) * 8;
    const int rbase = (lane >> 4) * 4;
    const int cg   = tid & 7;
    const int rw0  = tid >> 3;

    float bestv[16]; int besti[16];
    #pragma unroll
    for (int g = 0; g < 16; ++g) { bestv[g] = 3.0e38f; besti[g] = 2048; }

    for (int nb = 0; nb < 4; ++nb) {
        const int ct0 = blockIdx.y * 512 + nb * 128;
        f32x4 acc[4][4];
        #pragma unroll
        for (int i=0;i<4;i++)
            #pragma unroll
            for (int j=0;j<4;j++)
                acc[i][j] = (f32x4){0.f,0.f,0.f,0.f};

        for (int k0 = 0; k0 < 512; k0 += 32) {
            float4 fa[4], fb[4];
            #pragma unroll
            for (int q = 0; q < 4; ++q) {
                const int row = rw0 + q*32;
                fa[q] = *(const float4*)(enc + (long long)(bm + row)*512 + k0 + cg*4);
                fb[q] = *(const float4*)(cb  + (long long)(ct0 + row)*512 + k0 + cg*4);
            }
            __syncthreads();
            #pragma unroll
            for (int q = 0; q < 4; ++q) {
                const int row = rw0 + q*32;
                ushort4 ah_, al_, bh_, bl_;
                split2(fa[q].x, ah_.x, al_.x);
                split2(fa[q].y, ah_.y, al_.y);
                split2(fa[q].z, ah_.z, al_.z);
                split2(fa[q].w, ah_.w, al_.w);
                split2(fb[q].x * 2048.0f, bh_.x, bl_.x);
                split2(fb[q].y * 2048.0f, bh_.y, bl_.y);
                split2(fb[q].z * 2048.0f, bh_.z, bl_.z);
                split2(fb[q].w * 2048.0f, bh_.w, bl_.w);
                *(ushort4*)(&AhP[row*56 + cg*4]) = ah_;
                *(ushort4*)(&AlP[row*56 + cg*4]) = al_;
                *(ushort4*)(&BhP[row*56 + cg*4]) = bh_;
                *(ushort4*)(&BlP[row*56 + cg*4]) = bl_;
            }
            __syncthreads();
            f16x8 ah[4], al[4], bh[4], bl[4];
            #pragma unroll
            for (int mi = 0; mi < 4; ++mi) {
                ah[mi] = *(const f16x8*)(&AhP[(wm + mi*16 + l15)*56 + lk8]);
                al[mi] = *(const f16x8*)(&AlP[(wm + mi*16 + l15)*56 + lk8]);
            }
            #pragma unroll
            for (int nj = 0; nj < 4; ++nj) {
                bh[nj] = *(const f16x8*)(&BhP[(wn + nj*16 + l15)*56 + lk8]);
                bl[nj] = *(const f16x8*)(&BlP[(wn + nj*16 + l15)*56 + lk8]);
            }
            #pragma unroll
            for (int mi = 0; mi < 4; ++mi)
                #pragma unroll
                for (int nj = 0; nj < 4; ++nj) {
                    acc[mi][nj] = __builtin_amdgcn_mfma_f32_16x16x32_f16(ah[mi], bh[nj], acc[mi][nj], 0, 0, 0);
                    acc[mi][nj] = __builtin_amdgcn_mfma_f32_16x16x32_f16(ah[mi], bl[nj], acc[mi][nj], 0, 0, 0);
                    acc[mi][nj] = __builtin_amdgcn_mfma_f32_16x16x32_f16(al[mi], bh[nj], acc[mi][nj], 0, 0, 0);
                }
        }
        // epilogue for this 128-col chunk (registers only)
        #pragma unroll
        for (int mi = 0; mi < 4; ++mi) {
            #pragma unroll
            for (int r = 0; r < 4; ++r) {
                const int g = mi*4 + r;
                const float anf = (float)Asum[bm + wm + mi*16 + rbase + r];
                #pragma unroll
                for (int nj = 0; nj < 4; ++nj) {
                    const int col = ct0 + wn + nj*16 + l15;
                    const float bf = (float)cbB[col];
                    const float s1 = anf + bf;
                    const float dot = acc[mi][nj][r] * (1.0f/2048.0f);  // exact scale
                    const float df  = 2.0f * dot;                        // exact scale
                    const float qd  = s1 - df;
                    if (qd < bestv[g] || (qd == bestv[g] && col < besti[g])) {
                        bestv[g] = qd; besti[g] = col;
                    }
                }
            }
        }
    }
    __syncthreads();   // tile LDS dead; reuse as reduce arrays
    #pragma unroll
    for (int mi = 0; mi < 4; ++mi)
        #pragma unroll
        for (int r = 0; r < 4; ++r) {
            const int row  = wm + mi*16 + rbase + r;
            const int slot = (wave & 1)*16 + l15;
            bvsP[row*32 + slot] = bestv[mi*4 + r];
            bisP[row*32 + slot] = besti[mi*4 + r];
        }
    __syncthreads();
    if (tid < 128) {
        float bv = bvsP[tid*32]; int bi = bisP[tid*32];
        #pragma unroll
        for (int s = 1; s < 32; ++s) {
            float v = bvsP[tid*32 + s]; int ii = bisP[tid*32 + s];
            if (v < bv || (v == bv && ii < bi)) { bv = v; bi = ii; }
        }
        pbv[(long long)blockIdx.y*16384 + bm + tid] = bv;
        pbi[(long long)blockIdx.y*16384 + bm + tid] = bi;
    }
}

__global__ __launch_bounds__(256)
void vq_reduce_r17(const float* __restrict__ pbv, const int* __restrict__ pbi,
                   int* __restrict__ idxout)
{
    int n = blockIdx.x*256 + threadIdx.x;
    if (n >= 16384) return;
    float bv = pbv[n]; int bi = pbi[n];
    #pragma unroll
    for (int q = 1; q < 4; ++q) {
        float v = pbv[q*16384 + n]; int ii = pbi[q*16384 + n];
        if (v < bv || (v == bv && ii < bi)) { bv = v; bi = ii; }
    }
    idxout[n] = bi & 2047;
}

// ---------------- vq loss ----------------------------------------------------
__global__ __launch_bounds__(256)
void vq_loss_partial_r17(const float* __restrict__ enc, const float* __restrict__ cb,
                         const int* __restrict__ idxp, double* __restrict__ part)
{
    __shared__ double red[4];
    const int row  = blockIdx.x*4 + (threadIdx.x >> 6);
    const int lane = threadIdx.x & 63;
    const int ci = idxp[row] & 2047;
    double s = 0.0;
    #pragma unroll
    for (int u = 0; u < 8; ++u) {
        int d = lane + u*64;
        double dv = (double)cb[(long long)ci*512 + d] - (double)enc[(long long)row*512 + d];
        s += dv * dv;
    }
    #pragma unroll
    for (int msk = 32; msk; msk >>= 1) s += __shfl_xor(s, msk, 64);
    if (lane == 0) red[threadIdx.x >> 6] = s;
    __syncthreads();
    if (threadIdx.x == 0)
        part[blockIdx.x] = red[0] + red[1] + red[2] + red[3];
}

// ---------------- regime f32 GEMM (small) ------------------------------------
template<int FLAGS>
__global__ __launch_bounds__(256)
void gemm_bt_r17(const float* __restrict__ A, const float* __restrict__ Bm,
                 const float* __restrict__ bias, const float* __restrict__ pos,
                 const float* __restrict__ addsrc, float* __restrict__ C,
                 int Kdim, int lda, int ldb, int ldc)
{
    __shared__ float As[16][132];
    __shared__ float Bs[16][132];
    const int tid = threadIdx.x;
    const int tx = tid & 15, ty = tid >> 4;
    const int bm = blockIdx.x * 128, bn = blockIdx.y * 128;
    const int r0 = tid >> 2;
    const int kg = (tid & 3) << 2;
    const float* Arow0 = A  + (long long)(bm + r0) * lda + kg;
    const float* Arow1 = A  + (long long)(bm + r0 + 64) * lda + kg;
    const float* Brow0 = Bm + (long long)(bn + r0) * ldb + kg;
    const float* Brow1 = Bm + (long long)(bn + r0 + 64) * ldb + kg;

    float acc[8][8] = {};
    for (int k0 = 0; k0 < Kdim; k0 += 16) {
        float4 a0 = *(const float4*)(Arow0 + k0);
        float4 a1 = *(const float4*)(Arow1 + k0);
        float4 b0 = *(const float4*)(Brow0 + k0);
        float4 b1 = *(const float4*)(Brow1 + k0);
        __syncthreads();
        As[kg+0][r0]=a0.x; As[kg+1][r0]=a0.y; As[kg+2][r0]=a0.z; As[kg+3][r0]=a0.w;
        As[kg+0][r0+64]=a1.x; As[kg+1][r0+64]=a1.y; As[kg+2][r0+64]=a1.z; As[kg+3][r0+64]=a1.w;
        Bs[kg+0][r0]=b0.x; Bs[kg+1][r0]=b0.y; Bs[kg+2][r0]=b0.z; Bs[kg+3][r0]=b0.w;
        Bs[kg+0][r0+64]=b1.x; Bs[kg+1][r0+64]=b1.y; Bs[kg+2][r0+64]=b1.z; Bs[kg+3][r0+64]=b1.w;
        __syncthreads();
        #pragma unroll
        for (int kk = 0; kk < 16; ++kk) {
            float a[8], b[8];
            #pragma unroll
            for (int i=0;i<8;i++) a[i] = As[kk][ty*8+i];
            #pragma unroll
            for (int j=0;j<4;j++) b[j]   = Bs[kk][tx*4+j];
            #pragma unroll
            for (int j=0;j<4;j++) b[4+j] = Bs[kk][64+tx*4+j];
            #pragma unroll
            for (int i=0;i<8;i++)
                #pragma unroll
                for (int j=0;j<8;j++)
                    acc[i][j] = fmaf(a[i], b[j], acc[i][j]);
        }
    }
    #pragma unroll
    for (int i=0;i<8;i++){
        const int row = bm + ty*8 + i;
        #pragma unroll
        for (int j=0;j<8;j++){
            const int col = bn + ((j < 4) ? (tx*4 + j) : (64 + tx*4 + (j-4)));
            float v = acc[i][j];
            if constexpr (FLAGS & GF_BIAS) v += bias[col];
            if constexpr (FLAGS & GF_POS)  v += pos[(long long)(row & 511)*512 + col];
            if constexpr (FLAGS & GF_ADD)  v += addsrc[(long long)row*ldc + col];
            if constexpr (FLAGS & GF_ACC)  v += C[(long long)row*ldc + col];
            if constexpr (FLAGS & GF_RELU) v = fmaxf(v, 0.0f);
            C[(long long)row*ldc + col] = v;
        }
    }
}

// ---------------- regime softmax ---------------------------------------------
__global__ __launch_bounds__(256)
void softmax_rows_r17(float* __restrict__ R)
{
    const int row = blockIdx.x;
    const int tid = threadIdx.x;
    __shared__ float  redf[256];
    __shared__ double redd[256];
    float* p = R + (long long)row * 2048;
    float mx = -1e30f;
    for (int c = tid; c < 2048; c += 256) mx = fmaxf(mx, p[c]);
    redf[tid] = mx; __syncthreads();
    for (int s2 = 128; s2; s2 >>= 1) { if (tid < s2) redf[tid] = fmaxf(redf[tid], redf[tid+s2]); __syncthreads(); }
    mx = redf[0];
    double sum = 0.0;
    for (int c = tid; c < 2048; c += 256) { float e = expf(p[c] - mx); p[c] = e; sum += e; }
    redd[tid] = sum; __syncthreads();
    for (int s2 = 128; s2; s2 >>= 1) { if (tid < s2) redd[tid] += redd[tid+s2]; __syncthreads(); }
    double tot = redd[0];
    for (int c = tid; c < 2048; c += 256) p[c] = (float)((double)p[c] / tot);
}

// ---------------- hash table -------------------------------------------------
__global__ __launch_bounds__(256)
void hash_table_r17(const float* __restrict__ cb, const float* __restrict__ hw,
                    float* __restrict__ T)
{
    const int k = blockIdx.x*4 + (threadIdx.x >> 6);
    const int j = threadIdx.x & 63;
    double s = 0.0;
    for (int d = 0; d < 512; ++d)
        s += (double)cb[(long long)k*512 + d] * (double)hw[(long long)j*512 + d];
    T[(long long)k*64 + j] = (s > 0.0) ? 1.0f : 0.0f;
}

// ---------------- output writers ---------------------------------------------
__global__ void write_loss_r17(const double* __restrict__ part,
                               float* __restrict__ out)
{
    __shared__ double red[256];
    double s = 0.0;
    for (int i = threadIdx.x; i < 4096; i += 256) s += part[i];
    red[threadIdx.x] = s; __syncthreads();
    for (int s2 = 128; s2; s2 >>= 1) {
        if (threadIdx.x < s2) red[threadIdx.x] += red[threadIdx.x + s2];
        __syncthreads();
    }
    if (threadIdx.x == 0)
        out[O_LOSS] = (float)(1.25 * red[0] / 8388608.0);
}

__global__ __launch_bounds__(256)
void write_regime_r17(const float* __restrict__ R, const int* __restrict__ idxp,
                      float* __restrict__ out)
{
    long long i = (long long)blockIdx.x*256 + threadIdx.x;
    if (i >= 33554432LL) return;
    int n = (int)(i >> 11), c = (int)(i & 2047);
    int ci = idxp[n] & 2047;
    out[O_REG + i] = R[(long long)ci*2048 + c];
}

__global__ __launch_bounds__(256)
void write_hash_r17(const float* __restrict__ T, const int* __restrict__ idxp,
                    float* __restrict__ out)
{
    long long i = (long long)blockIdx.x*256 + threadIdx.x;
    if (i >= 1048576LL) return;
    int n = (int)(i >> 6), j = (int)(i & 63);
    int ci = idxp[n] & 2047;
    out[O_HASH + i] = T[(long long)ci*64 + j];
}

__global__ __launch_bounds__(256)
void write_idx_r17(const int* __restrict__ idxp, float* __restrict__ out)
{
    int n = blockIdx.x*256 + threadIdx.x;
    if (n >= 16384) return;
    out[O_IDX + n] = (float)(idxp[n] & 2047);
}

__global__ __launch_bounds__(256)
void write_quant_r17(const float* __restrict__ cb, const int* __restrict__ idxp,
                     float* __restrict__ out)
{
    long long i = (long long)blockIdx.x*256 + threadIdx.x;
    if (i >= 8388608LL) return;
    int n = (int)(i >> 9), d = (int)(i & 511);
    int ci = idxp[n] & 2047;
    out[O_QUANT + i] = cb[(long long)ci*512 + d];
}

// ---------------- launcher ----------------------------------------------------
extern "C" void kernel_launch(void* const* d_in, const int* in_sizes, int n_in,
                              void* d_out, int out_size, void* d_ws, size_t ws_size,
                              hipStream_t stream)
{
    (void)in_sizes; (void)n_in; (void)out_size;
    const float* market = (const float*)d_in[0];
    const float* W_in   = (const float*)d_in[1];
    const float* b_in   = (const float*)d_in[2];
    const float* pos    = (const float*)d_in[3];
    const float* c3w = (const float*)d_in[4];  const float* c3b = (const float*)d_in[5];
    const float* c5w = (const float*)d_in[6];  const float* c5b = (const float*)d_in[7];
    const float* c7w = (const float*)d_in[8];  const float* c7b = (const float*)d_in[9];
    const float* c9w = (const float*)d_in[10]; const float* c9b = (const float*)d_in[11];
    const float* msw = (const float*)d_in[12]; const float* msb = (const float*)d_in[13];
    const float* inw = (const float*)d_in[14]; const float* inb = (const float*)d_in[15];
    const float* aow = (const float*)d_in[16]; const float* aob = (const float*)d_in[17];
    const float* cb  = (const float*)d_in[18]; const float* hw  = (const float*)d_in[19];
    const float* r1w = (const float*)d_in[20]; const float* r1b = (const float*)d_in[21];
    const float* r2w = (const float*)d_in[22]; const float* r2b = (const float*)d_in[23];

    if (ws_size < (size_t)W_END * sizeof(float)) return;

    float* ws    = (float*)d_ws;
    float* xp    = ws + W_XP;
    float* convt = ws + W_CT;
    float* projp = ws + W_PROJ;
    unsigned int* wt3 = (unsigned int*)(ws + W_VW);
    unsigned int* wt5 = wt3 + 512*512*3;
    unsigned int* wt7 = wt5 + 512*512*5;
    unsigned int* wt9 = wt7 + 512*512*7;
    float* Vbufp = ws + W_VW;
    float* hregp = ws + W_HREG;
    float* Tp    = ws + W_T;
    int*    idxp  = (int*)(ws + W_IDX);
    double* asump = (double*)(ws + W_ASUM);
    double* cbbp  = (double*)(ws + W_CBB);
    double* lpart = (double*)(ws + W_LPART);
    float*  pbvp  = ws + W_PBV;
    int*    pbip  = (int*)(ws + W_PBI);

    float* out = (float*)d_out;

    float* Qbufp = xp;
    float* attp  = xp;
    float* Kbufp = convt;
    float* encp  = convt;
    float* Rp    = projp;

    const unsigned int* xpu = (const unsigned int*)xp;

    conv_w_tr_r17<3><<<3072, 256, 0, stream>>>(c3w, wt3);
    conv_w_tr_r17<5><<<5120, 256, 0, stream>>>(c5w, wt5);
    conv_w_tr_r17<7><<<7168, 256, 0, stream>>>(c7w, wt7);
    conv_w_tr_r17<9><<<9216, 256, 0, stream>>>(c9w, wt9);

    const dim3 gT(128, 4);

    gemm_mfma_r17<GF_BIAS|GF_POS><<<gT, 256, 0, stream>>>(market, W_in, b_in, pos, nullptr, xp, 512, 512, 512, 512);
    split_xp_r17<<<32768, 256, 0, stream>>>(xp);

    conv_mfma_r17<3><<<gT, 256, 0, stream>>>(xpu, wt3, c3b, convt);
    gemm_mfma_r17<GF_BIAS><<<gT, 256, 0, stream>>>(convt, msw + 0*512, msb, nullptr, nullptr, projp, 512, 512, 2048, 512);
    conv_mfma_r17<5><<<gT, 256, 0, stream>>>(xpu, wt5, c5b, convt);
    gemm_mfma_r17<GF_ACC><<<gT, 256, 0, stream>>>(convt, msw + 1*512, nullptr, nullptr, nullptr, projp, 512, 512, 2048, 512);
    conv_mfma_r17<7><<<gT, 256, 0, stream>>>(xpu, wt7, c7b, convt);
    gemm_mfma_r17<GF_ACC><<<gT, 256, 0, stream>>>(convt, msw + 2*512, nullptr, nullptr, nullptr, projp, 512, 512, 2048, 512);
    conv_mfma_r17<9><<<gT, 256, 0, stream>>>(xpu, wt9, c9b, convt);
    gemm_mfma_r17<GF_ACC><<<gT, 256, 0, stream>>>(convt, msw + 3*512, nullptr, nullptr, nullptr, projp, 512, 512, 2048, 512);

    gemm_mfma_r17<GF_BIAS><<<gT, 256, 0, stream>>>(projp, inw + 512*512,  inb + 512,  nullptr, nullptr, Kbufp, 512, 512, 512, 512);
    gemm_mfma_r17<GF_BIAS><<<gT, 256, 0, stream>>>(projp, inw + 1024*512, inb + 1024, nullptr, nullptr, Vbufp, 512, 512, 512, 512);
    gemm_mfma_r17<GF_BIAS><<<gT, 256, 0, stream>>>(projp, inw,            inb,        nullptr, nullptr, Qbufp, 512, 512, 512, 512);

    attn_fused_r17<<<2048, 256, 0, stream>>>(Qbufp, Kbufp, Vbufp, attp);

    gemm_mfma_r17<GF_BIAS|GF_ADD><<<gT, 256, 0, stream>>>(attp, aow, aob, nullptr, projp, encp, 512, 512, 512, 512);

    // VQ
    row_sumsq_r17<<<4096, 256, 0, stream>>>(encp, asump);
    row_sumsq_r17<<<512,  256, 0, stream>>>(cb, cbbp);
    vq_argmin_mfma_r17<<<dim3(128, 4), 256, 0, stream>>>(encp, cb, asump, cbbp, pbvp, pbip);
    vq_reduce_r17<<<64, 256, 0, stream>>>(pbvp, pbip, idxp);
    vq_loss_partial_r17<<<4096, 256, 0, stream>>>(encp, cb, idxp, lpart);

    // regime tables
    gemm_bt_r17<GF_BIAS|GF_RELU><<<dim3(16, 2),  256, 0, stream>>>(cb, r1w, r1b, nullptr, nullptr, hregp, 512, 512, 512, 256);
    gemm_bt_r17<GF_BIAS><<<dim3(16, 16), 256, 0, stream>>>(hregp, r2w, r2b, nullptr, nullptr, Rp, 256, 256, 256, 2048);
    softmax_rows_r17<<<2048, 256, 0, stream>>>(Rp);
    hash_table_r17<<<512, 256, 0, stream>>>(cb, hw, Tp);

    // outputs
    write_loss_r17<<<1, 256, 0, stream>>>(lpart, out);
    write_regime_r17<<<131072, 256, 0, stream>>>(Rp, idxp, out);
    write_hash_r17<<<4096, 256, 0, stream>>>(Tp, idxp, out);
    write_idx_r17<<<64, 256, 0, stream>>>(idxp, out);
    write_quant_r17<<<32768, 256, 0, stream>>>(cb, idxp, out);
}

// Round 18
// 1631.168 us; speedup vs baseline: 3.4133x; 1.1213x over previous
//
#include <hip/hip_runtime.h>
#include <hip/hip_bf16.h>

// ---------------- problem constants ----------------
// B=32, S=512, D=512, K=2048; N = B*S = 16384. d_out is FLOAT32.
// r18 = r17 + attention QK^T/PV via f16x3 split MFMA (same proven template).
// Softmax f32 online (structure unchanged). All else r17-verbatim.

#define GF_BIAS 1
#define GF_RELU 2
#define GF_ADD  4
#define GF_POS  8
#define GF_ACC  16

typedef _Float16 f16x8 __attribute__((ext_vector_type(8)));
typedef float    f32x4 __attribute__((ext_vector_type(4)));

static constexpr long long O_QUANT = 0LL;
static constexpr long long O_LOSS  = 8388608LL;
static constexpr long long O_IDX   = 8388609LL;
static constexpr long long O_HASH  = 8404993LL;
static constexpr long long O_REG   = 9453569LL;
static constexpr long long O_END   = 43008001LL;

static constexpr long long W_XP    = 0LL;
static constexpr long long W_CT    = 8388608LL;
static constexpr long long W_PROJ  = 16777216LL;
static constexpr long long W_VW    = 25165824LL;
static constexpr long long W_HREG  = 33554432LL;
static constexpr long long W_T     = 34078720LL;
static constexpr long long W_IDX   = 34209792LL;
static constexpr long long W_ASUM  = 34226176LL;
static constexpr long long W_CBB   = 34258944LL;
static constexpr long long W_LPART = 34263040LL;
static constexpr long long W_PBV   = 34271232LL;
static constexpr long long W_PBI   = 34336768LL;
static constexpr long long W_END   = 34402304LL;

__device__ __forceinline__ unsigned int pack_hl(float x)
{
    _Float16 h = (_Float16)x;
    float hf = (float)h;
    _Float16 l = (_Float16)(x - hf);
    unsigned short hb = __builtin_bit_cast(unsigned short, h);
    unsigned short lb = __builtin_bit_cast(unsigned short, l);
    return (unsigned int)hb | ((unsigned int)lb << 16);
}

__device__ __forceinline__ void split2(float x, unsigned short& h, unsigned short& l)
{
    _Float16 hf = (_Float16)x;
    _Float16 lf = (_Float16)(x - (float)hf);
    h = __builtin_bit_cast(unsigned short, hf);
    l = __builtin_bit_cast(unsigned short, lf);
}

// ---------------- split xp in place ------------------------------------------
__global__ __launch_bounds__(256)
void split_xp_r18(float* __restrict__ xp)
{
    long long i = (long long)blockIdx.x*256 + threadIdx.x;
    float x = xp[i];
    ((unsigned int*)xp)[i] = pack_hl(x);
}

template<int KT>
__global__ __launch_bounds__(256)
void conv_w_tr_r18(const float* __restrict__ w, unsigned int* __restrict__ wt)
{
    long long i = (long long)blockIdx.x*256 + threadIdx.x;
    int o  = (int)(i / (512*KT));
    int rem= (int)(i % (512*KT));
    int t  = rem >> 9;
    int ii = rem & 511;
    wt[i] = pack_hl(w[(long long)o*512*KT + (long long)ii*KT + t]);
}

// ---------------- conv via f16x3 MFMA (r17 verbatim) -------------------------
template<int KT>
__global__ __launch_bounds__(256)
void conv_mfma_r18(const unsigned int* __restrict__ xphl,
                   const unsigned int* __restrict__ wthl,
                   const float* __restrict__ bias, float* __restrict__ outp)
{
    constexpr int PAD = KT / 2;
    __shared__ unsigned short Ah[128][56];
    __shared__ unsigned short Al[128][56];
    __shared__ unsigned short Bh[128][56];
    __shared__ unsigned short Bl[128][56];
    const int tid  = threadIdx.x;
    const int lane = tid & 63;
    const int wave = tid >> 6;
    const int wm = (wave >> 1) * 64, wn = (wave & 1) * 64;
    const int bm = blockIdx.x * 128, bn = blockIdx.y * 128;
    const int l15 = lane & 15;
    const int lk8 = (lane >> 4) * 8;
    const int rbase = (lane >> 4) * 4;
    const int cg   = tid & 7;
    const int rw0  = tid >> 3;

    f32x4 acc[4][4];
    #pragma unroll
    for (int i=0;i<4;i++)
        #pragma unroll
        for (int j=0;j<4;j++)
            acc[i][j] = (f32x4){0.f,0.f,0.f,0.f};

    for (int t = 0; t < KT; ++t) {
        for (int i0 = 0; i0 < 512; i0 += 32) {
            uint4 va[4], vb[4];
            #pragma unroll
            for (int q = 0; q < 4; ++q) {
                const int row = rw0 + q*32;
                const int s   = (bm + row) & 511;
                const int sp  = s + t - PAD;
                if (sp >= 0 && sp < 512)
                    va[q] = *(const uint4*)(xphl + (long long)(bm + row + t - PAD)*512 + i0 + cg*4);
                else
                    va[q] = make_uint4(0u,0u,0u,0u);
                vb[q] = *(const uint4*)(wthl + (long long)(bn + row)*(KT*512) + t*512 + i0 + cg*4);
            }
            __syncthreads();
            #pragma unroll
            for (int q = 0; q < 4; ++q) {
                const int row = rw0 + q*32;
                ushort4 ahi = make_ushort4((unsigned short)(va[q].x & 0xffff),
                                           (unsigned short)(va[q].y & 0xffff),
                                           (unsigned short)(va[q].z & 0xffff),
                                           (unsigned short)(va[q].w & 0xffff));
                ushort4 alo = make_ushort4((unsigned short)(va[q].x >> 16),
                                           (unsigned short)(va[q].y >> 16),
                                           (unsigned short)(va[q].z >> 16),
                                           (unsigned short)(va[q].w >> 16));
                ushort4 bhi = make_ushort4((unsigned short)(vb[q].x & 0xffff),
                                           (unsigned short)(vb[q].y & 0xffff),
                                           (unsigned short)(vb[q].z & 0xffff),
                                           (unsigned short)(vb[q].w & 0xffff));
                ushort4 blo = make_ushort4((unsigned short)(vb[q].x >> 16),
                                           (unsigned short)(vb[q].y >> 16),
                                           (unsigned short)(vb[q].z >> 16),
                                           (unsigned short)(vb[q].w >> 16));
                *(ushort4*)(&Ah[row][cg*4]) = ahi;
                *(ushort4*)(&Al[row][cg*4]) = alo;
                *(ushort4*)(&Bh[row][cg*4]) = bhi;
                *(ushort4*)(&Bl[row][cg*4]) = blo;
            }
            __syncthreads();
            f16x8 ah[4], al[4], bh[4], bl[4];
            #pragma unroll
            for (int mi = 0; mi < 4; ++mi) {
                ah[mi] = *(const f16x8*)(&Ah[wm + mi*16 + l15][lk8]);
                al[mi] = *(const f16x8*)(&Al[wm + mi*16 + l15][lk8]);
            }
            #pragma unroll
            for (int nj = 0; nj < 4; ++nj) {
                bh[nj] = *(const f16x8*)(&Bh[wn + nj*16 + l15][lk8]);
                bl[nj] = *(const f16x8*)(&Bl[wn + nj*16 + l15][lk8]);
            }
            #pragma unroll
            for (int mi = 0; mi < 4; ++mi)
                #pragma unroll
                for (int nj = 0; nj < 4; ++nj) {
                    acc[mi][nj] = __builtin_amdgcn_mfma_f32_16x16x32_f16(ah[mi], bh[nj], acc[mi][nj], 0, 0, 0);
                    acc[mi][nj] = __builtin_amdgcn_mfma_f32_16x16x32_f16(ah[mi], bl[nj], acc[mi][nj], 0, 0, 0);
                    acc[mi][nj] = __builtin_amdgcn_mfma_f32_16x16x32_f16(al[mi], bh[nj], acc[mi][nj], 0, 0, 0);
                }
        }
    }
    #pragma unroll
    for (int mi = 0; mi < 4; ++mi) {
        #pragma unroll
        for (int nj = 0; nj < 4; ++nj) {
            const int col = bn + wn + nj*16 + l15;
            const float bcol = bias[col];
            #pragma unroll
            for (int r = 0; r < 4; ++r) {
                const int row = bm + wm + mi*16 + rbase + r;
                float v = acc[mi][nj][r] + bcol;
                outp[(long long)row*512 + col] = fmaxf(v, 0.0f);
            }
        }
    }
}

// ---------------- generic GEMM via f16x3 MFMA (r17 verbatim) -----------------
template<int FLAGS>
__global__ __launch_bounds__(256)
void gemm_mfma_r18(const float* __restrict__ A, const float* __restrict__ Bm,
                   const float* __restrict__ bias, const float* __restrict__ pos,
                   const float* __restrict__ addsrc, float* __restrict__ C,
                   int Kdim, int lda, int ldb, int ldc)
{
    __shared__ unsigned short Ah[128][56];
    __shared__ unsigned short Al[128][56];
    __shared__ unsigned short Bh[128][56];
    __shared__ unsigned short Bl[128][56];
    const int tid  = threadIdx.x;
    const int lane = tid & 63;
    const int wave = tid >> 6;
    const int wm = (wave >> 1) * 64, wn = (wave & 1) * 64;
    const int bm = blockIdx.x * 128, bn = blockIdx.y * 128;
    const int l15 = lane & 15;
    const int lk8 = (lane >> 4) * 8;
    const int rbase = (lane >> 4) * 4;
    const int cg   = tid & 7;
    const int rw0  = tid >> 3;

    f32x4 acc[4][4];
    #pragma unroll
    for (int i=0;i<4;i++)
        #pragma unroll
        for (int j=0;j<4;j++)
            acc[i][j] = (f32x4){0.f,0.f,0.f,0.f};

    for (int k0 = 0; k0 < Kdim; k0 += 32) {
        float4 fa[4], fb[4];
        #pragma unroll
        for (int q = 0; q < 4; ++q) {
            const int row = rw0 + q*32;
            fa[q] = *(const float4*)(A  + (long long)(bm + row)*lda + k0 + cg*4);
            fb[q] = *(const float4*)(Bm + (long long)(bn + row)*ldb + k0 + cg*4);
        }
        __syncthreads();
        #pragma unroll
        for (int q = 0; q < 4; ++q) {
            const int row = rw0 + q*32;
            ushort4 ah_, al_, bh_, bl_;
            split2(fa[q].x, ah_.x, al_.x);
            split2(fa[q].y, ah_.y, al_.y);
            split2(fa[q].z, ah_.z, al_.z);
            split2(fa[q].w, ah_.w, al_.w);
            split2(fb[q].x, bh_.x, bl_.x);
            split2(fb[q].y, bh_.y, bl_.y);
            split2(fb[q].z, bh_.z, bl_.z);
            split2(fb[q].w, bh_.w, bl_.w);
            *(ushort4*)(&Ah[row][cg*4]) = ah_;
            *(ushort4*)(&Al[row][cg*4]) = al_;
            *(ushort4*)(&Bh[row][cg*4]) = bh_;
            *(ushort4*)(&Bl[row][cg*4]) = bl_;
        }
        __syncthreads();
        f16x8 ah[4], al[4], bh[4], bl[4];
        #pragma unroll
        for (int mi = 0; mi < 4; ++mi) {
            ah[mi] = *(const f16x8*)(&Ah[wm + mi*16 + l15][lk8]);
            al[mi] = *(const f16x8*)(&Al[wm + mi*16 + l15][lk8]);
        }
        #pragma unroll
        for (int nj = 0; nj < 4; ++nj) {
            bh[nj] = *(const f16x8*)(&Bh[wn + nj*16 + l15][lk8]);
            bl[nj] = *(const f16x8*)(&Bl[wn + nj*16 + l15][lk8]);
        }
        #pragma unroll
        for (int mi = 0; mi < 4; ++mi)
            #pragma unroll
            for (int nj = 0; nj < 4; ++nj) {
                acc[mi][nj] = __builtin_amdgcn_mfma_f32_16x16x32_f16(ah[mi], bh[nj], acc[mi][nj], 0, 0, 0);
                acc[mi][nj] = __builtin_amdgcn_mfma_f32_16x16x32_f16(ah[mi], bl[nj], acc[mi][nj], 0, 0, 0);
                acc[mi][nj] = __builtin_amdgcn_mfma_f32_16x16x32_f16(al[mi], bh[nj], acc[mi][nj], 0, 0, 0);
            }
    }
    #pragma unroll
    for (int mi = 0; mi < 4; ++mi) {
        #pragma unroll
        for (int nj = 0; nj < 4; ++nj) {
            const int col = bn + wn + nj*16 + l15;
            #pragma unroll
            for (int r = 0; r < 4; ++r) {
                const int row = bm + wm + mi*16 + rbase + r;
                float v = acc[mi][nj][r];
                if constexpr (FLAGS & GF_BIAS) v += bias[col];
                if constexpr (FLAGS & GF_POS)  v += pos[(long long)(row & 511)*512 + col];
                if constexpr (FLAGS & GF_ADD)  v += addsrc[(long long)row*ldc + col];
                if constexpr (FLAGS & GF_ACC)  v += C[(long long)row*ldc + col];
                if constexpr (FLAGS & GF_RELU) v = fmaxf(v, 0.0f);
                C[(long long)row*ldc + col] = v;
            }
        }
    }
}

// ---------------- fused attention via f16x3 MFMA -----------------------------
// Per block: (b,h,qt); 4 waves x 16 q-rows. K tile overlaid by P after scores.
__global__ __launch_bounds__(256)
void attn_mfma_r18(const float* __restrict__ Qbuf, const float* __restrict__ Kbuf,
                   const float* __restrict__ Vbuf, float* __restrict__ att)
{
    __shared__ unsigned short Qh[64][68];
    __shared__ unsigned short Ql[64][68];
    __shared__ unsigned short Kh[64][68];   // K tile, then P tile
    __shared__ unsigned short Kl[64][68];
    __shared__ unsigned short Vh[64][68];   // transposed: [d][k]
    __shared__ unsigned short Vl[64][68];
    const int tid  = threadIdx.x;
    const int lane = tid & 63;
    const int wave = tid >> 6;
    const int l15  = lane & 15;
    const int lq   = lane >> 4;         // 0..3
    const int lq8  = lq * 8;
    const int bid = blockIdx.x;
    const int qt = bid & 7, h = (bid >> 3) & 7, b = bid >> 6;
    const int row0 = b*512 + qt*64;

    // stage Q (scaled by exact 2^-3), split hi/lo
    #pragma unroll
    for (int u = 0; u < 16; ++u) {
        int e = u*256 + tid;
        int r = e >> 6, c = e & 63;
        float q = Qbuf[(long long)(row0 + r)*512 + h*64 + c] * 0.125f;
        unsigned short hs, ls;
        split2(q, hs, ls);
        Qh[r][c] = hs; Ql[r][c] = ls;
    }

    float m[4], l[4];
    f32x4 accO[4];
    #pragma unroll
    for (int r=0;r<4;r++){ m[r] = -1e30f; l[r] = 0.f; }
    #pragma unroll
    for (int j=0;j<4;j++) accO[j] = (f32x4){0.f,0.f,0.f,0.f};

    for (int kv = 0; kv < 512; kv += 64) {
        __syncthreads();   // prior-iter P/V readers done
        // stage K (linear) and V (transposed), split hi/lo
        #pragma unroll
        for (int u = 0; u < 16; ++u) {
            int e = u*256 + tid;
            int r = e >> 6, c = e & 63;
            float kvf = Kbuf[(long long)(b*512 + kv + r)*512 + h*64 + c];
            float vvf = Vbuf[(long long)(b*512 + kv + r)*512 + h*64 + c];
            unsigned short hs, ls;
            split2(kvf, hs, ls);
            Kh[r][c] = hs; Kl[r][c] = ls;
            split2(vvf, hs, ls);
            Vh[c][r] = hs; Vl[c][r] = ls;
        }
        __syncthreads();
        // QK^T: scores for this wave's 16 q-rows x 64 keys
        f32x4 accS[4];
        #pragma unroll
        for (int j=0;j<4;j++) accS[j] = (f32x4){0.f,0.f,0.f,0.f};
        #pragma unroll
        for (int ks = 0; ks < 2; ++ks) {
            f16x8 qh = *(const f16x8*)(&Qh[wave*16 + l15][ks*32 + lq8]);
            f16x8 ql = *(const f16x8*)(&Ql[wave*16 + l15][ks*32 + lq8]);
            #pragma unroll
            for (int nj = 0; nj < 4; ++nj) {
                f16x8 kh = *(const f16x8*)(&Kh[nj*16 + l15][ks*32 + lq8]);
                f16x8 kl = *(const f16x8*)(&Kl[nj*16 + l15][ks*32 + lq8]);
                accS[nj] = __builtin_amdgcn_mfma_f32_16x16x32_f16(qh, kh, accS[nj], 0, 0, 0);
                accS[nj] = __builtin_amdgcn_mfma_f32_16x16x32_f16(qh, kl, accS[nj], 0, 0, 0);
                accS[nj] = __builtin_amdgcn_mfma_f32_16x16x32_f16(ql, kh, accS[nj], 0, 0, 0);
            }
        }
        // online softmax (rows rbase+r, value cols nj*16+l15)
        #pragma unroll
        for (int r = 0; r < 4; ++r) {
            float tm = fmaxf(fmaxf(accS[0][r], accS[1][r]), fmaxf(accS[2][r], accS[3][r]));
            #pragma unroll
            for (int msk = 1; msk < 16; msk <<= 1) tm = fmaxf(tm, __shfl_xor(tm, msk, 64));
            float mn = fmaxf(m[r], tm);
            float scale = expf(m[r] - mn);
            float rs = 0.f;
            #pragma unroll
            for (int nj = 0; nj < 4; ++nj) {
                float p = expf(accS[nj][r] - mn);
                accS[nj][r] = p;
                rs += p;
            }
            #pragma unroll
            for (int msk = 1; msk < 16; msk <<= 1) rs += __shfl_xor(rs, msk, 64);
            l[r] = l[r]*scale + rs;
            m[r] = mn;
            #pragma unroll
            for (int nj = 0; nj < 4; ++nj) accO[nj][r] *= scale;
        }
        __syncthreads();   // all waves done reading K; overlay P
        #pragma unroll
        for (int r = 0; r < 4; ++r)
            #pragma unroll
            for (int nj = 0; nj < 4; ++nj) {
                unsigned short hs, ls;
                split2(accS[nj][r], hs, ls);
                Kh[wave*16 + lq*4 + r][nj*16 + l15] = hs;
                Kl[wave*16 + lq*4 + r][nj*16 + l15] = ls;
            }
        __syncthreads();
        // PV: out[16 q][64 d] += P[16][64] x V[64][64]
        #pragma unroll
        for (int ks = 0; ks < 2; ++ks) {
            f16x8 ph = *(const f16x8*)(&Kh[wave*16 + l15][ks*32 + lq8]);
            f16x8 pl = *(const f16x8*)(&Kl[wave*16 + l15][ks*32 + lq8]);
            #pragma unroll
            for (int nj = 0; nj < 4; ++nj) {
                f16x8 vh = *(const f16x8*)(&Vh[nj*16 + l15][ks*32 + lq8]);
                f16x8 vl = *(const f16x8*)(&Vl[nj*16 + l15][ks*32 + lq8]);
                accO[nj] = __builtin_amdgcn_mfma_f32_16x16x32_f16(ph, vh, accO[nj], 0, 0, 0);
                accO[nj] = __builtin_amdgcn_mfma_f32_16x16x32_f16(ph, vl, accO[nj], 0, 0, 0);
                accO[nj] = __builtin_amdgcn_mfma_f32_16x16x32_f16(pl, vh, accO[nj], 0, 0, 0);
            }
        }
    }
    // epilogue: rows wave*16 + lq*4 + r, cols h*64 + nj*16 + l15
    #pragma unroll
    for (int nj = 0; nj < 4; ++nj)
        #pragma unroll
        for (int r = 0; r < 4; ++r) {
            const int row = row0 + wave*16 + lq*4 + r;
            att[(long long)row*512 + h*64 + nj*16 + l15] = accO[nj][r] / l[r];
        }
}

// ---------------- row sum of squares (f64) -----------------------------------
__global__ __launch_bounds__(256)
void row_sumsq_r18(const float* __restrict__ X, double* __restrict__ outp)
{
    const int row  = blockIdx.x*4 + (threadIdx.x >> 6);
    const int lane = threadIdx.x & 63;
    double s = 0.0;
    #pragma unroll
    for (int u = 0; u < 8; ++u) {
        float v = X[(long long)row*512 + lane + u*64];
        s += (double)v * (double)v;
    }
    #pragma unroll
    for (int msk = 32; msk; msk >>= 1) s += __shfl_xor(s, msk, 64);
    if (lane == 0) outp[row] = s;
}

// ---------------- VQ argmin via f16x3 MFMA (r17 verbatim) --------------------
__global__ __launch_bounds__(256)
void vq_argmin_mfma_r18(const float* __restrict__ enc, const float* __restrict__ cb,
                        const double* __restrict__ Asum, const double* __restrict__ cbB,
                        float* __restrict__ pbv, int* __restrict__ pbi)
{
    __shared__ unsigned int smem[14336];
    unsigned short* AhP = (unsigned short*)smem;
    unsigned short* AlP = AhP + 128*56;
    unsigned short* BhP = AlP + 128*56;
    unsigned short* BlP = BhP + 128*56;
    float* bvsP = (float*)smem;
    int*   bisP = (int*)(smem + 4096);

    const int tid  = threadIdx.x;
    const int lane = tid & 63;
    const int wave = tid >> 6;
    const int wm = (wave >> 1) * 64, wn = (wave & 1) * 64;
    const int bm = blockIdx.x * 128;
    const int l15 = lane & 15;
    const int lk8 = (lane >> 4) * 8;
    const int rbase = (lane >> 4) * 4;
    const int cg   = tid & 7;
    const int rw0  = tid >> 3;

    float bestv[16]; int besti[16];
    #pragma unroll
    for (int g = 0; g < 16; ++g) { bestv[g] = 3.0e38f; besti[g] = 2048; }

    for (int nb = 0; nb < 4; ++nb) {
        const int ct0 = blockIdx.y * 512 + nb * 128;
        f32x4 acc[4][4];
        #pragma unroll
        for (int i=0;i<4;i++)
            #pragma unroll
            for (int j=0;j<4;j++)
                acc[i][j] = (f32x4){0.f,0.f,0.f,0.f};

        for (int k0 = 0; k0 < 512; k0 += 32) {
            float4 fa[4], fb[4];
            #pragma unroll
            for (int q = 0; q < 4; ++q) {
                const int row = rw0 + q*32;
                fa[q] = *(const float4*)(enc + (long long)(bm + row)*512 + k0 + cg*4);
                fb[q] = *(const float4*)(cb  + (long long)(ct0 + row)*512 + k0 + cg*4);
            }
            __syncthreads();
            #pragma unroll
            for (int q = 0; q < 4; ++q) {
                const int row = rw0 + q*32;
                ushort4 ah_, al_, bh_, bl_;
                split2(fa[q].x, ah_.x, al_.x);
                split2(fa[q].y, ah_.y, al_.y);
                split2(fa[q].z, ah_.z, al_.z);
                split2(fa[q].w, ah_.w, al_.w);
                split2(fb[q].x * 2048.0f, bh_.x, bl_.x);
                split2(fb[q].y * 2048.0f, bh_.y, bl_.y);
                split2(fb[q].z * 2048.0f, bh_.z, bl_.z);
                split2(fb[q].w * 2048.0f, bh_.w, bl_.w);
                *(ushort4*)(&AhP[row*56 + cg*4]) = ah_;
                *(ushort4*)(&AlP[row*56 + cg*4]) = al_;
                *(ushort4*)(&BhP[row*56 + cg*4]) = bh_;
                *(ushort4*)(&BlP[row*56 + cg*4]) = bl_;
            }
            __syncthreads();
            f16x8 ah[4], al[4], bh[4], bl[4];
            #pragma unroll
            for (int mi = 0; mi < 4; ++mi) {
                ah[mi] = *(const f16x8*)(&AhP[(wm + mi*16 + l15)*56 + lk8]);
                al[mi] = *(const f16x8*)(&AlP[(wm + mi*16 + l15)*56 + lk8]);
            }
            #pragma unroll
            for (int nj = 0; nj < 4; ++nj) {
                bh[nj] = *(const f16x8*)(&BhP[(wn + nj*16 + l15)*56 + lk8]);
                bl[nj] = *(const f16x8*)(&BlP[(wn + nj*16 + l15)*56 + lk8]);
            }
            #pragma unroll
            for (int mi = 0; mi < 4; ++mi)
                #pragma unroll
                for (int nj = 0; nj < 4; ++nj) {
                    acc[mi][nj] = __builtin_amdgcn_mfma_f32_16x16x32_f16(ah[mi], bh[nj], acc[mi][nj], 0, 0, 0);
                    acc[mi][nj] = __builtin_amdgcn_mfma_f32_16x16x32_f16(ah[mi], bl[nj], acc[mi][nj], 0, 0, 0);
                    acc[mi][nj] = __builtin_amdgcn_mfma_f32_16x16x32_f16(al[mi], bh[nj], acc[mi][nj], 0, 0, 0);
                }
        }
        #pragma unroll
        for (int mi = 0; mi < 4; ++mi) {
            #pragma unroll
            for (int r = 0; r < 4; ++r) {
                const int g = mi*4 + r;
                const float anf = (float)Asum[bm + wm + mi*16 + rbase + r];
                #pragma unroll
                for (int nj = 0; nj < 4; ++nj) {
                    const int col = ct0 + wn + nj*16 + l15;
                    const float bf = (float)cbB[col];
                    const float s1 = anf + bf;
                    const float dot = acc[mi][nj][r] * (1.0f/2048.0f);
                    const float df  = 2.0f * dot;
                    const float qd  = s1 - df;
                    if (qd < bestv[g] || (qd == bestv[g] && col < besti[g])) {
                        bestv[g] = qd; besti[g] = col;
                    }
                }
            }
        }
    }
    __syncthreads();
    #pragma unroll
    for (int mi = 0; mi < 4; ++mi)
        #pragma unroll
        for (int r = 0; r < 4; ++r) {
            const int row  = wm + mi*16 + rbase + r;
            const int slot = (wave & 1)*16 + l15;
            bvsP[row*32 + slot] = bestv[mi*4 + r];
            bisP[row*32 + slot] = besti[mi*4 + r];
        }
    __syncthreads();
    if (tid < 128) {
        float bv = bvsP[tid*32]; int bi = bisP[tid*32];
        #pragma unroll
        for (int s = 1; s < 32; ++s) {
            float v = bvsP[tid*32 + s]; int ii = bisP[tid*32 + s];
            if (v < bv || (v == bv && ii < bi)) { bv = v; bi = ii; }
        }
        pbv[(long long)blockIdx.y*16384 + bm + tid] = bv;
        pbi[(long long)blockIdx.y*16384 + bm + tid] = bi;
    }
}

__global__ __launch_bounds__(256)
void vq_reduce_r18(const float* __restrict__ pbv, const int* __restrict__ pbi,
                   int* __restrict__ idxout)
{
    int n = blockIdx.x*256 + threadIdx.x;
    if (n >= 16384) return;
    float bv = pbv[n]; int bi = pbi[n];
    #pragma unroll
    for (int q = 1; q < 4; ++q) {
        float v = pbv[q*16384 + n]; int ii = pbi[q*16384 + n];
        if (v < bv || (v == bv && ii < bi)) { bv = v; bi = ii; }
    }
    idxout[n] = bi & 2047;
}

// ---------------- vq loss ----------------------------------------------------
__global__ __launch_bounds__(256)
void vq_loss_partial_r18(const float* __restrict__ enc, const float* __restrict__ cb,
                         const int* __restrict__ idxp, double* __restrict__ part)
{
    __shared__ double red[4];
    const int row  = blockIdx.x*4 + (threadIdx.x >> 6);
    const int lane = threadIdx.x & 63;
    const int ci = idxp[row] & 2047;
    double s = 0.0;
    #pragma unroll
    for (int u = 0; u < 8; ++u) {
        int d = lane + u*64;
        double dv = (double)cb[(long long)ci*512 + d] - (double)enc[(long long)row*512 + d];
        s += dv * dv;
    }
    #pragma unroll
    for (int msk = 32; msk; msk >>= 1) s += __shfl_xor(s, msk, 64);
    if (lane == 0) red[threadIdx.x >> 6] = s;
    __syncthreads();
    if (threadIdx.x == 0)
        part[blockIdx.x] = red[0] + red[1] + red[2] + red[3];
}

// ---------------- regime f32 GEMM (small) ------------------------------------
template<int FLAGS>
__global__ __launch_bounds__(256)
void gemm_bt_r18(const float* __restrict__ A, const float* __restrict__ Bm,
                 const float* __restrict__ bias, const float* __restrict__ pos,
                 const float* __restrict__ addsrc, float* __restrict__ C,
                 int Kdim, int lda, int ldb, int ldc)
{
    __shared__ float As[16][132];
    __shared__ float Bs[16][132];
    const int tid = threadIdx.x;
    const int tx = tid & 15, ty = tid >> 4;
    const int bm = blockIdx.x * 128, bn = blockIdx.y * 128;
    const int r0 = tid >> 2;
    const int kg = (tid & 3) << 2;
    const float* Arow0 = A  + (long long)(bm + r0) * lda + kg;
    const float* Arow1 = A  + (long long)(bm + r0 + 64) * lda + kg;
    const float* Brow0 = Bm + (long long)(bn + r0) * ldb + kg;
    const float* Brow1 = Bm + (long long)(bn + r0 + 64) * ldb + kg;

    float acc[8][8] = {};
    for (int k0 = 0; k0 < Kdim; k0 += 16) {
        float4 a0 = *(const float4*)(Arow0 + k0);
        float4 a1 = *(const float4*)(Arow1 + k0);
        float4 b0 = *(const float4*)(Brow0 + k0);
        float4 b1 = *(const float4*)(Brow1 + k0);
        __syncthreads();
        As[kg+0][r0]=a0.x; As[kg+1][r0]=a0.y; As[kg+2][r0]=a0.z; As[kg+3][r0]=a0.w;
        As[kg+0][r0+64]=a1.x; As[kg+1][r0+64]=a1.y; As[kg+2][r0+64]=a1.z; As[kg+3][r0+64]=a1.w;
        Bs[kg+0][r0]=b0.x; Bs[kg+1][r0]=b0.y; Bs[kg+2][r0]=b0.z; Bs[kg+3][r0]=b0.w;
        Bs[kg+0][r0+64]=b1.x; Bs[kg+1][r0+64]=b1.y; Bs[kg+2][r0+64]=b1.z; Bs[kg+3][r0+64]=b1.w;
        __syncthreads();
        #pragma unroll
        for (int kk = 0; kk < 16; ++kk) {
            float a[8], b[8];
            #pragma unroll
            for (int i=0;i<8;i++) a[i] = As[kk][ty*8+i];
            #pragma unroll
            for (int j=0;j<4;j++) b[j]   = Bs[kk][tx*4+j];
            #pragma unroll
            for (int j=0;j<4;j++) b[4+j] = Bs[kk][64+tx*4+j];
            #pragma unroll
            for (int i=0;i<8;i++)
                #pragma unroll
                for (int j=0;j<8;j++)
                    acc[i][j] = fmaf(a[i], b[j], acc[i][j]);
        }
    }
    #pragma unroll
    for (int i=0;i<8;i++){
        const int row = bm + ty*8 + i;
        #pragma unroll
        for (int j=0;j<8;j++){
            const int col = bn + ((j < 4) ? (tx*4 + j) : (64 + tx*4 + (j-4)));
            float v = acc[i][j];
            if constexpr (FLAGS & GF_BIAS) v += bias[col];
            if constexpr (FLAGS & GF_POS)  v += pos[(long long)(row & 511)*512 + col];
            if constexpr (FLAGS & GF_ADD)  v += addsrc[(long long)row*ldc + col];
            if constexpr (FLAGS & GF_ACC)  v += C[(long long)row*ldc + col];
            if constexpr (FLAGS & GF_RELU) v = fmaxf(v, 0.0f);
            C[(long long)row*ldc + col] = v;
        }
    }
}

// ---------------- regime softmax ---------------------------------------------
__global__ __launch_bounds__(256)
void softmax_rows_r18(float* __restrict__ R)
{
    const int row = blockIdx.x;
    const int tid = threadIdx.x;
    __shared__ float  redf[256];
    __shared__ double redd[256];
    float* p = R + (long long)row * 2048;
    float mx = -1e30f;
    for (int c = tid; c < 2048; c += 256) mx = fmaxf(mx, p[c]);
    redf[tid] = mx; __syncthreads();
    for (int s2 = 128; s2; s2 >>= 1) { if (tid < s2) redf[tid] = fmaxf(redf[tid], redf[tid+s2]); __syncthreads(); }
    mx = redf[0];
    double sum = 0.0;
    for (int c = tid; c < 2048; c += 256) { float e = expf(p[c] - mx); p[c] = e; sum += e; }
    redd[tid] = sum; __syncthreads();
    for (int s2 = 128; s2; s2 >>= 1) { if (tid < s2) redd[tid] += redd[tid+s2]; __syncthreads(); }
    double tot = redd[0];
    for (int c = tid; c < 2048; c += 256) p[c] = (float)((double)p[c] / tot);
}

// ---------------- hash table -------------------------------------------------
__global__ __launch_bounds__(256)
void hash_table_r18(const float* __restrict__ cb, const float* __restrict__ hw,
                    float* __restrict__ T)
{
    const int k = blockIdx.x*4 + (threadIdx.x >> 6);
    const int j = threadIdx.x & 63;
    double s = 0.0;
    for (int d = 0; d < 512; ++d)
        s += (double)cb[(long long)k*512 + d] * (double)hw[(long long)j*512 + d];
    T[(long long)k*64 + j] = (s > 0.0) ? 1.0f : 0.0f;
}

// ---------------- output writers ---------------------------------------------
__global__ void write_loss_r18(const double* __restrict__ part,
                               float* __restrict__ out)
{
    __shared__ double red[256];
    double s = 0.0;
    for (int i = threadIdx.x; i < 4096; i += 256) s += part[i];
    red[threadIdx.x] = s; __syncthreads();
    for (int s2 = 128; s2; s2 >>= 1) {
        if (threadIdx.x < s2) red[threadIdx.x] += red[threadIdx.x + s2];
        __syncthreads();
    }
    if (threadIdx.x == 0)
        out[O_LOSS] = (float)(1.25 * red[0] / 8388608.0);
}

__global__ __launch_bounds__(256)
void write_regime_r18(const float* __restrict__ R, const int* __restrict__ idxp,
                      float* __restrict__ out)
{
    long long i = (long long)blockIdx.x*256 + threadIdx.x;
    if (i >= 33554432LL) return;
    int n = (int)(i >> 11), c = (int)(i & 2047);
    int ci = idxp[n] & 2047;
    out[O_REG + i] = R[(long long)ci*2048 + c];
}

__global__ __launch_bounds__(256)
void write_hash_r18(const float* __restrict__ T, const int* __restrict__ idxp,
                    float* __restrict__ out)
{
    long long i = (long long)blockIdx.x*256 + threadIdx.x;
    if (i >= 1048576LL) return;
    int n = (int)(i >> 6), j = (int)(i & 63);
    int ci = idxp[n] & 2047;
    out[O_HASH + i] = T[(long long)ci*64 + j];
}

__global__ __launch_bounds__(256)
void write_idx_r18(const int* __restrict__ idxp, float* __restrict__ out)
{
    int n = blockIdx.x*256 + threadIdx.x;
    if (n >= 16384) return;
    out[O_IDX + n] = (float)(idxp[n] & 2047);
}

__global__ __launch_bounds__(256)
void write_quant_r18(const float* __restrict__ cb, const int* __restrict__ idxp,
                     float* __restrict__ out)
{
    long long i = (long long)blockIdx.x*256 + threadIdx.x;
    if (i >= 8388608LL) return;
    int n = (int)(i >> 9), d = (int)(i & 511);
    int ci = idxp[n] & 2047;
    out[O_QUANT + i] = cb[(long long)ci*512 + d];
}

// ---------------- launcher ----------------------------------------------------
extern "C" void kernel_launch(void* const* d_in, const int* in_sizes, int n_in,
                              void* d_out, int out_size, void* d_ws, size_t ws_size,
                              hipStream_t stream)
{
    (void)in_sizes; (void)n_in; (void)out_size;
    const float* market = (const float*)d_in[0];
    const float* W_in   = (const float*)d_in[1];
    const float* b_in   = (const float*)d_in[2];
    const float* pos    = (const float*)d_in[3];
    const float* c3w = (const float*)d_in[4];  const float* c3b = (const float*)d_in[5];
    const float* c5w = (const float*)d_in[6];  const float* c5b = (const float*)d_in[7];
    const float* c7w = (const float*)d_in[8];  const float* c7b = (const float*)d_in[9];
    const float* c9w = (const float*)d_in[10]; const float* c9b = (const float*)d_in[11];
    const float* msw = (const float*)d_in[12]; const float* msb = (const float*)d_in[13];
    const float* inw = (const float*)d_in[14]; const float* inb = (const float*)d_in[15];
    const float* aow = (const float*)d_in[16]; const float* aob = (const float*)d_in[17];
    const float* cb  = (const float*)d_in[18]; const float* hw  = (const float*)d_in[19];
    const float* r1w = (const float*)d_in[20]; const float* r1b = (const float*)d_in[21];
    const float* r2w = (const float*)d_in[22]; const float* r2b = (const float*)d_in[23];

    if (ws_size < (size_t)W_END * sizeof(float)) return;

    float* ws    = (float*)d_ws;
    float* xp    = ws + W_XP;
    float* convt = ws + W_CT;
    float* projp = ws + W_PROJ;
    unsigned int* wt3 = (unsigned int*)(ws + W_VW);
    unsigned int* wt5 = wt3 + 512*512*3;
    unsigned int* wt7 = wt5 + 512*512*5;
    unsigned int* wt9 = wt7 + 512*512*7;
    float* Vbufp = ws + W_VW;
    float* hregp = ws + W_HREG;
    float* Tp    = ws + W_T;
    int*    idxp  = (int*)(ws + W_IDX);
    double* asump = (double*)(ws + W_ASUM);
    double* cbbp  = (double*)(ws + W_CBB);
    double* lpart = (double*)(ws + W_LPART);
    float*  pbvp  = ws + W_PBV;
    int*    pbip  = (int*)(ws + W_PBI);

    float* out = (float*)d_out;

    float* Qbufp = xp;
    float* attp  = xp;
    float* Kbufp = convt;
    float* encp  = convt;
    float* Rp    = projp;

    const unsigned int* xpu = (const unsigned int*)xp;

    conv_w_tr_r18<3><<<3072, 256, 0, stream>>>(c3w, wt3);
    conv_w_tr_r18<5><<<5120, 256, 0, stream>>>(c5w, wt5);
    conv_w_tr_r18<7><<<7168, 256, 0, stream>>>(c7w, wt7);
    conv_w_tr_r18<9><<<9216, 256, 0, stream>>>(c9w, wt9);

    const dim3 gT(128, 4);

    gemm_mfma_r18<GF_BIAS|GF_POS><<<gT, 256, 0, stream>>>(market, W_in, b_in, pos, nullptr, xp, 512, 512, 512, 512);
    split_xp_r18<<<32768, 256, 0, stream>>>(xp);

    conv_mfma_r18<3><<<gT, 256, 0, stream>>>(xpu, wt3, c3b, convt);
    gemm_mfma_r18<GF_BIAS><<<gT, 256, 0, stream>>>(convt, msw + 0*512, msb, nullptr, nullptr, projp, 512, 512, 2048, 512);
    conv_mfma_r18<5><<<gT, 256, 0, stream>>>(xpu, wt5, c5b, convt);
    gemm_mfma_r18<GF_ACC><<<gT, 256, 0, stream>>>(convt, msw + 1*512, nullptr, nullptr, nullptr, projp, 512, 512, 2048, 512);
    conv_mfma_r18<7><<<gT, 256, 0, stream>>>(xpu, wt7, c7b, convt);
    gemm_mfma_r18<GF_ACC><<<gT, 256, 0, stream>>>(convt, msw + 2*512, nullptr, nullptr, nullptr, projp, 512, 512, 2048, 512);
    conv_mfma_r18<9><<<gT, 256, 0, stream>>>(xpu, wt9, c9b, convt);
    gemm_mfma_r18<GF_ACC><<<gT, 256, 0, stream>>>(convt, msw + 3*512, nullptr, nullptr, nullptr, projp, 512, 512, 2048, 512);

    gemm_mfma_r18<GF_BIAS><<<gT, 256, 0, stream>>>(projp, inw + 512*512,  inb + 512,  nullptr, nullptr, Kbufp, 512, 512, 512, 512);
    gemm_mfma_r18<GF_BIAS><<<gT, 256, 0, stream>>>(projp, inw + 1024*512, inb + 1024, nullptr, nullptr, Vbufp, 512, 512, 512, 512);
    gemm_mfma_r18<GF_BIAS><<<gT, 256, 0, stream>>>(projp, inw,            inb,        nullptr, nullptr, Qbufp, 512, 512, 512, 512);

    attn_mfma_r18<<<2048, 256, 0, stream>>>(Qbufp, Kbufp, Vbufp, attp);

    gemm_mfma_r18<GF_BIAS|GF_ADD><<<gT, 256, 0, stream>>>(attp, aow, aob, nullptr, projp, encp, 512, 512, 512, 512);

    // VQ
    row_sumsq_r18<<<4096, 256, 0, stream>>>(encp, asump);
    row_sumsq_r18<<<512,  256, 0, stream>>>(cb, cbbp);
    vq_argmin_mfma_r18<<<dim3(128, 4), 256, 0, stream>>>(encp, cb, asump, cbbp, pbvp, pbip);
    vq_reduce_r18<<<64, 256, 0, stream>>>(pbvp, pbip, idxp);
    vq_loss_partial_r18<<<4096, 256, 0, stream>>>(encp, cb, idxp, lpart);

    // regime tables
    gemm_bt_r18<GF_BIAS|GF_RELU><<<dim3(16, 2),  256, 0, stream>>>(cb, r1w, r1b, nullptr, nullptr, hregp, 512, 512, 512, 256);
    gemm_bt_r18<GF_BIAS><<<dim3(16, 16), 256, 0, stream>>>(hregp, r2w, r2b, nullptr, nullptr, Rp, 256, 256, 256, 2048);
    softmax_rows_r18<<<2048, 256, 0, stream>>>(Rp);
    hash_table_r18<<<512, 256, 0, stream>>>(cb, hw, Tp);

    // outputs
    write_loss_r18<<<1, 256, 0, stream>>>(lpart, out);
    write_regime_r18<<<131072, 256, 0, stream>>>(Rp, idxp, out);
    write_hash_r18<<<4096, 256, 0, stream>>>(Tp, idxp, out);
    write_idx_r18<<<64, 256, 0, stream>>>(idxp, out);
    write_quant_r18<<<32768, 256, 0, stream>>>(cb, idxp, out);
}